// Round 15
// baseline (1404.393 us; speedup 1.0000x reference)
//
#include <hip/hip_runtime.h>
#include <hip/hip_bf16.h>
#include <math.h>

// ---------------- constants ----------------
#define C_DIM 128
#define HGT 192
#define WID 192
#define NB 4
#define WFD 97   // 192/2+1

// TAB float region
#define T_BIAS  0                // 4*64*64 fp32
#define T_QKVB  16384            // 384 fp32 (q_b | kv_b)
#define TF_SZ   16896
// TAB bf16 region (ushort offsets, base = TAB + TF_SZ floats)
#define UT_MW    0               // [256][192]
#define UT_MHF   49152           // [384][384]
#define UT_MHI   196608          // [384][384]
#define UT_MWI   344064          // [192][224]
#define UT_QKVW  387072          // [384][128]
#define UT_PROJW 436224          // [128][128]
#define UT_FFT1W 452608          // [256][256]
#define UT_FFT2W 518144          // [256][256]
#define UT_L1W   583680          // [512][128]
#define UT_L2W   649216          // [128][512]
#define UT_TOT   714752
#define TAB_SZ   374272          // floats: TF_SZ + UT_TOT/2

typedef __attribute__((ext_vector_type(8))) short bf16x8;
typedef __attribute__((ext_vector_type(4))) float f32x4;

__device__ __forceinline__ float gelu_f(float v){
  return 0.5f*v*(1.0f + erff(v*0.70710678118654752440f));
}
__device__ __forceinline__ unsigned short f2bf(float f){
  __hip_bfloat16 h = __float2bfloat16(f);
  return *reinterpret_cast<unsigned short*>(&h);
}
__device__ __forceinline__ float bf2f(unsigned short u){
  unsigned int x = ((unsigned int)u)<<16;
  return __uint_as_float(x);
}
__device__ __forceinline__ void st8u(unsigned short* d, bf16x8 v){
  unsigned int* wp = (unsigned int*)&v;
  unsigned int* dp = (unsigned int*)d;
  dp[0]=wp[0]; dp[1]=wp[1]; dp[2]=wp[2]; dp[3]=wp[3];
}

// ---------------- table build (exact int mod-192 + float trig) ----------------
__global__ __launch_bounds__(256) void build_tables(float* __restrict__ tab,
        const float* __restrict__ rpb, const float* __restrict__ q_b, const float* __restrict__ kv_b,
        const float* __restrict__ q_w, const float* __restrict__ kv_w, const float* __restrict__ proj_w,
        const float* __restrict__ fft1_w, const float* __restrict__ fft2_w,
        const float* __restrict__ l1_w, const float* __restrict__ l2_w){
  int idx = blockIdx.x*256 + threadIdx.x;
  const float STEP = (float)(6.283185307179586476925286766559/192.0);
  if (idx < 16384){ // attn bias fp32: [head][n][m]
    int head = idx>>12, n = (idx>>6)&63, m = idx&63;
    int dh = n/16 - m/16 + 3;
    int dw = (n&15) - (m&15) + 15;
    tab[T_BIAS+idx] = rpb[(dh*31+dw)*4 + head];
    return;
  }
  idx -= 16384;
  if (idx < 384){ // QKV bias concat fp32
    tab[T_QKVB+idx] = (idx < 128) ? q_b[idx] : kv_b[idx-128];
    return;
  }
  idx -= 384;
  unsigned short* ut = (unsigned short*)(tab + TF_SZ);
  if (idx < 49152){ // MW [256][192]
    int r = idx/192, w = idx%192;
    float v = 0.f;
    if (r < 97){ int a = (r*w)%192; v = cosf(a*STEP); }
    else if (r < 194){ int a = ((r-97)*w)%192; v = -sinf(a*STEP); }
    ut[UT_MW+idx] = f2bf(v);
    return;
  }
  idx -= 49152;
  if (idx < 147456){ // MHF [384][384]
    int r = idx/384, j = idx%384;
    int hf = (r < 192) ? r : r-192;
    int h  = (j < 192) ? j : j-192;
    int a = (hf*h)%192;
    float c = cosf(a*STEP), s = sinf(a*STEP);
    float v;
    if (r < 192) v = (j < 192) ? c : s;
    else         v = (j < 192) ? -s : c;
    ut[UT_MHF+idx] = f2bf(v);
    return;
  }
  idx -= 147456;
  if (idx < 147456){ // MHI [384][384]
    int r = idx/384, j = idx%384;
    int h  = (r < 192) ? r : r-192;
    int hf = (j < 192) ? j : j-192;
    int a = (h*hf)%192;
    float c = cosf(a*STEP), s = sinf(a*STEP);
    float v;
    if (r < 192) v = (j < 192) ? c : -s;
    else         v = (j < 192) ? s : c;
    ut[UT_MHI+idx] = f2bf(v);
    return;
  }
  idx -= 147456;
  if (idx < 43008){ // MWI [192][224]
    int w = idx/224, j = idx%224;
    float v = 0.f;
    if (j < 97){
      int a = (j*w)%192;
      float sc = ((j==0 || j==96) ? 1.f : 2.f) / 36864.f;
      v = sc*cosf(a*STEP);
    } else if (j >= 112 && j < 209){
      int k = j-112;
      int a = (k*w)%192;
      float sc = ((k==0 || k==96) ? 1.f : 2.f) / 36864.f;
      v = -sc*sinf(a*STEP);
    }
    ut[UT_MWI+idx] = f2bf(v);
    return;
  }
  idx -= 43008;
  if (idx < 49152){ // QKVW [384][128]
    int n = idx/128, k = idx%128;
    float v = (n < 128) ? q_w[(size_t)k*128 + n] : kv_w[(size_t)k*256 + (n-128)];
    ut[UT_QKVW+idx] = f2bf(v);
    return;
  }
  idx -= 49152;
  if (idx < 16384){ // PROJW [128][128]
    int n = idx/128, k = idx%128;
    ut[UT_PROJW+idx] = f2bf(proj_w[(size_t)k*128 + n]);
    return;
  }
  idx -= 16384;
  if (idx < 65536){ // FFT1W [256][256]
    int n = idx/256, k = idx%256;
    ut[UT_FFT1W+idx] = f2bf(fft1_w[(size_t)k*256 + n]);
    return;
  }
  idx -= 65536;
  if (idx < 65536){ // FFT2W [256][256]
    int n = idx/256, k = idx%256;
    ut[UT_FFT2W+idx] = f2bf(fft2_w[(size_t)k*256 + n]);
    return;
  }
  idx -= 65536;
  if (idx < 65536){ // L1W [512][128]
    int n = idx/128, k = idx%128;
    ut[UT_L1W+idx] = f2bf(l1_w[(size_t)k*512 + n]);
    return;
  }
  idx -= 65536;
  if (idx < 65536){ // L2W [128][512]
    int n = idx/512, k = idx%512;
    ut[UT_L2W+idx] = f2bf(l2_w[(size_t)k*128 + n]);
  }
}

// ---------------- pos depthwise conv: 8h x 32w x 16c ----------------
__global__ __launch_bounds__(256) void posconv3_kernel(const float* __restrict__ x, const float* __restrict__ pw,
                               const float* __restrict__ pb, float* __restrict__ xt){
  __shared__ float rows_s[16*340];
  int w0 = blockIdx.x*32, h0 = blockIdx.y*8;
  int b = blockIdx.z >> 3, cb = (blockIdx.z & 7)*16;
  int tid = threadIdx.x;
  int hl = tid >> 5, wl = tid & 31;
  for (int e = tid; e < 16*340; e += 256){
    int c = e / 340; int rem = e - c*340;
    int r = rem / 34; int wc = rem - r*34;
    int gh = h0 - 1 + r, gw = w0 - 1 + wc;
    float v = 0.f;
    if (gh >= 0 && gh < HGT && gw >= 0 && gw < WID)
      v = x[((size_t)(b*C_DIM + cb + c))*(HGT*WID) + gh*WID + gw];
    rows_s[e] = v;
  }
  __syncthreads();
  float outr[16];
  #pragma unroll
  for (int c = 0; c < 16; ++c){
    const float* rs = &rows_s[c*340];
    float wreg[9];
    #pragma unroll
    for (int t9 = 0; t9 < 9; ++t9) wreg[t9] = pw[(cb+c)*27 + 9 + t9];
    float bias = pb[cb+c];
    float acc = rs[(hl+1)*34 + wl+1] + bias;
    #pragma unroll
    for (int ky = 0; ky < 3; ++ky)
      #pragma unroll
      for (int kx = 0; kx < 3; ++kx)
        acc += wreg[ky*3+kx]*rs[(hl+ky)*34 + wl+kx];
    outr[c] = acc;
  }
  __syncthreads();
  {
    int px = hl*32 + wl;
    #pragma unroll
    for (int c = 0; c < 16; ++c) rows_s[px*17 + c] = outr[c];
  }
  __syncthreads();
  for (int r = 0; r < 16; ++r){
    int e = r*256 + tid;
    int cl = e & 15, hw = e >> 4;
    int h = hw >> 5, w = hw & 31;
    xt[((size_t)(b*HGT + h0+h)*WID + (w0+w))*C_DIM + cb + cl] = rows_s[hw*17 + cl];
  }
}

// ---------------- LN row stats ----------------
__global__ __launch_bounds__(256) void ln_stats_kernel(const float* __restrict__ src, float* __restrict__ stats){
  int wave = threadIdx.x >> 6; int lane = threadIdx.x & 63;
  size_t p = (size_t)blockIdx.x*4 + wave;
  const float* s = src + p*C_DIM;
  float v0 = s[lane], v1 = s[lane+64];
  float sum = v0 + v1;
  #pragma unroll
  for (int o=1; o<64; o<<=1) sum += __shfl_xor(sum, o, 64);
  float m = sum * (1.0f/128.0f);
  float d0 = v0-m, d1 = v1-m;
  float vs = d0*d0 + d1*d1;
  #pragma unroll
  for (int o=1; o<64; o<<=1) vs += __shfl_xor(vs, o, 64);
  float rstd = rsqrtf(vs*(1.0f/128.0f) + 1e-5f);
  if (lane==0){ stats[2*p] = m; stats[2*p+1] = rstd; }
}

// ---------------- 128x128 MFMA GEMM (4 waves, 64x64 quadrant each) ----------------
// dst[p,n] = act(A[p,:] @ W^T[n,:] + bias[n]) (+dst). N multiple of 128; M guarded by Mrows.
template<int ACT, bool ADD, bool LNA, bool ABF, bool OBF>
__global__ __launch_bounds__(256) void gemm3(const void* __restrict__ A1v,
                            const unsigned short* __restrict__ WT, const float* __restrict__ bias,
                            void* __restrict__ dstv, int K, int N, int lda,
                            const float* __restrict__ stats, const float* __restrict__ lng,
                            const float* __restrict__ lnb, int prow0, int pmax, int Mrows){
  __shared__ __align__(16) unsigned short As[128*40];
  __shared__ __align__(16) unsigned short Bs[128*40];
  int p0 = blockIdx.y*128, n0 = blockIdx.x*128;
  int tid = threadIdx.x;
  int wave = tid >> 6, lane = tid & 63;
  int wr = (wave>>1)*64, wc = (wave&1)*64;
  f32x4 acc[4][4];
  #pragma unroll
  for (int i=0;i<4;i++)
    #pragma unroll
    for (int j=0;j<4;j++) acc[i][j] = (f32x4){};
  int srow = tid >> 1, scol = (tid & 1)*16;
  for (int k0 = 0; k0 < K; k0 += 32){
    { // A stage: row srow, cols k0+scol .. +16
      if constexpr (ABF){
        int gr = p0 + srow;
        if (gr >= Mrows) gr = Mrows-1;
        const unsigned short* src = (const unsigned short*)A1v + (size_t)gr*lda + k0 + scol;
        st8u(&As[srow*40 + scol],     *(const bf16x8*)src);
        st8u(&As[srow*40 + scol + 8], *(const bf16x8*)(src+8));
      } else {
        int gp = p0 + srow;
        float s0 = 0.f, s1 = 1.f;
        if (LNA){
          gp += prow0;
          gp = gp < 0 ? 0 : (gp > pmax ? pmax : gp);
          s0 = stats[2*gp]; s1 = stats[2*gp+1];
        } else {
          if (gp >= Mrows) gp = Mrows-1;
        }
        const float* src = (const float*)A1v + (size_t)gp*lda + k0 + scol;
        unsigned short* dp = &As[srow*40 + scol];
        #pragma unroll
        for (int q=0;q<4;q++){
          float4 a4 = *(const float4*)(src + q*4);
          float v[4] = {a4.x,a4.y,a4.z,a4.w};
          #pragma unroll
          for (int j=0;j<4;j++){
            float f = v[j];
            if (LNA) f = (f - s0)*s1*lng[k0+scol+q*4+j] + lnb[k0+scol+q*4+j];
            dp[q*4+j] = f2bf(f);
          }
        }
      }
    }
    { // B stage
      const unsigned short* src = WT + (size_t)(n0 + srow)*K + k0 + scol;
      st8u(&Bs[srow*40 + scol],     *(const bf16x8*)src);
      st8u(&Bs[srow*40 + scol + 8], *(const bf16x8*)(src+8));
    }
    __syncthreads();
    int fm = lane & 15, kg = (lane>>4)*8;
    bf16x8 af[4], bf_[4];
    #pragma unroll
    for (int i=0;i<4;i++){
      af[i]  = *(const bf16x8*)&As[(wr + i*16 + fm)*40 + kg];
      bf_[i] = *(const bf16x8*)&Bs[(wc + i*16 + fm)*40 + kg];
    }
    #pragma unroll
    for (int i=0;i<4;i++)
      #pragma unroll
      for (int j=0;j<4;j++)
        acc[i][j] = __builtin_amdgcn_mfma_f32_16x16x32_bf16(af[i], bf_[j], acc[i][j], 0,0,0);
    __syncthreads();
  }
  int cn = lane & 15, rq = (lane>>4)*4;
  #pragma unroll
  for (int i=0;i<4;i++){
    #pragma unroll
    for (int j=0;j<4;j++){
      f32x4 a = acc[i][j];
      int n = n0 + wc + j*16 + cn;
      float bsv = bias[n];
      #pragma unroll
      for (int r=0;r<4;r++){
        int row = p0 + wr + i*16 + rq + r;
        if (row >= Mrows) continue;
        float v = a[r] + bsv;
        if (ACT==1) v = (v>=0.f) ? v : 0.01f*v;
        if (ACT==2) v = gelu_f(v);
        if constexpr (OBF){
          ((unsigned short*)dstv)[(size_t)row*N + n] = f2bf(v);
        } else {
          float* dst = (float*)dstv;
          if (ADD) v += dst[(size_t)row*N + n];
          dst[(size_t)row*N + n] = v;
        }
      }
    }
  }
}

// ---------------- DFT-as-GEMM (bf16 tables / bf16 spectra) ----------------
template<int MODE>
__global__ __launch_bounds__(256) void dft_gemm(const unsigned short* __restrict__ Atab,
                            const void* __restrict__ W1v, const void* __restrict__ W2v,
                            void* __restrict__ D1v, void* __restrict__ D2v, int k0){
  constexpr int K      = (MODE==0)?192 : (MODE==3)?224 : 384;
  constexpr int MT     = (MODE==0)?4 : (MODE==3)?3 : 6;
  constexpr int MVALID = (MODE==0)?194 : (MODE==3)?192 : 384;
  __shared__ __align__(16) unsigned short As[64*40];
  __shared__ __align__(16) unsigned short Bs[64*40];
  int slab = blockIdx.y / MT;
  int p0 = (blockIdx.y % MT)*64, n0 = blockIdx.x*64;
  int tid = threadIdx.x;
  int wave = tid >> 6, lane = tid & 63;
  int wr = (wave>>1)*32, wc = (wave&1)*32;
  f32x4 acc00 = {}, acc01 = {}, acc10 = {}, acc11 = {};
  int am = tid >> 2, ak = (tid & 3)*8;
  int bk = tid >> 3, bn = (tid & 7)*8;
  for (int kk0 = 0; kk0 < K; kk0 += 32){
    {
      bf16x8 av = *(const bf16x8*)(Atab + (size_t)(p0+am)*K + kk0 + ak);
      st8u(&As[am*40 + ak], av);
    }
    {
      int r = kk0 + bk;
      if (MODE==0){
        const float* src = (const float*)W1v + (size_t)slab*24576 + (size_t)r*128 + n0 + bn;
        float4 wa = *(const float4*)src;
        float4 wb = *(const float4*)(src+4);
        float v[8] = {wa.x,wa.y,wa.z,wa.w,wb.x,wb.y,wb.z,wb.w};
        #pragma unroll
        for (int j=0;j<8;j++) Bs[(bn+j)*40 + bk] = f2bf(v[j]);
      } else {
        const unsigned short* src;
        if (MODE==1) src = (r<192) ? (const unsigned short*)W1v + (size_t)(k0+slab)*128 + (size_t)r*12416
                                   : (const unsigned short*)W2v + (size_t)(k0+slab)*128 + (size_t)(r-192)*12416;
        else if (MODE==2) src = (r<192) ? (const unsigned short*)W1v + (size_t)slab*49152 + (size_t)r*256
                                        : (const unsigned short*)W2v + (size_t)slab*49152 + (size_t)(r-192)*256;
        else src = (r<112) ? (const unsigned short*)W1v + (size_t)slab*24832 + (size_t)r*256
                           : (const unsigned short*)W2v + (size_t)slab*24832 + (size_t)(r-112)*256;
        src += n0 + bn;
        bf16x8 wv = *(const bf16x8*)src;
        #pragma unroll
        for (int j=0;j<8;j++) Bs[(bn+j)*40 + bk] = (unsigned short)wv[j];
      }
    }
    __syncthreads();
    int fm = lane & 15, kg = (lane>>4)*8;
    bf16x8 a0 = *(const bf16x8*)&As[(wr+fm)*40 + kg];
    bf16x8 a1 = *(const bf16x8*)&As[(wr+16+fm)*40 + kg];
    bf16x8 b0 = *(const bf16x8*)&Bs[(wc+fm)*40 + kg];
    bf16x8 b1 = *(const bf16x8*)&Bs[(wc+16+fm)*40 + kg];
    acc00 = __builtin_amdgcn_mfma_f32_16x16x32_bf16(a0, b0, acc00, 0,0,0);
    acc01 = __builtin_amdgcn_mfma_f32_16x16x32_bf16(a0, b1, acc01, 0,0,0);
    acc10 = __builtin_amdgcn_mfma_f32_16x16x32_bf16(a1, b0, acc10, 0,0,0);
    acc11 = __builtin_amdgcn_mfma_f32_16x16x32_bf16(a1, b1, acc11, 0,0,0);
    __syncthreads();
  }
  int cn = lane & 15, rq = (lane>>4)*4;
  #pragma unroll
  for (int mi=0; mi<2; ++mi){
    #pragma unroll
    for (int ni=0; ni<2; ++ni){
      f32x4 a = (mi==0) ? (ni==0?acc00:acc01) : (ni==0?acc10:acc11);
      int n = n0 + wc + ni*16 + cn;
      #pragma unroll
      for (int r=0; r<4; ++r){
        int p = p0 + wr + mi*16 + rq + r;
        if (p >= MVALID) continue;
        float v = a[r];
        if (MODE==0){
          unsigned short* D1 = (unsigned short*)D1v;
          unsigned short* D2 = (unsigned short*)D2v;
          if (p < 97) D1[(size_t)slab*12416 + (size_t)p*128 + n] = f2bf(v);
          else        D2[(size_t)slab*12416 + (size_t)(p-97)*128 + n] = f2bf(v);
        } else if (MODE==1){
          unsigned short* base = (unsigned short*)D1v + (size_t)slab*49152;
          if (p < 192) base[(size_t)p*256 + n] = f2bf(v);
          else         base[(size_t)(p-192)*256 + 128 + n] = f2bf(v);
        } else if (MODE==2){
          unsigned short* D1 = (unsigned short*)D1v;
          int kg2 = k0 + slab;
          if (p < 192) D1[((size_t)p*97 + kg2)*256 + n] = f2bf(v);
          else         D1[((size_t)(p-192)*97 + kg2)*256 + 128 + n] = f2bf(v);
        } else {
          ((float*)D1v)[(size_t)slab*24576 + (size_t)p*128 + n] += v;
        }
      }
    }
  }
}

// ---------------- fused attention: LN + QKV proj (MFMA) + window attn ----------------
#define XS_OFF  0                      // [64][136]
#define WQK_OFF 8704                   // + wave*5120 : Qw [64][40], Kw at +2560; P alias [64][72]
#define VT_OFF  29184                  // + wave*2304 : Vt [32][72]
#define SHM_TOT 38400
__global__ __launch_bounds__(256) void attn_fused2(
    const float* __restrict__ XT, const float* __restrict__ stats,
    const float* __restrict__ g1, const float* __restrict__ b1,
    const unsigned short* __restrict__ QKVW, const float* __restrict__ QKVB,
    const float* __restrict__ biasT, unsigned short* __restrict__ OUTc){
  __shared__ __align__(16) unsigned short shm[SHM_TOT];
  int win = blockIdx.x;
  int b = win/576, rem = win%576, whi = rem/12, wwi = rem%12;
  int tid = threadIdx.x, wave = tid>>6, lane = tid&63, head = wave;
  int fm = lane & 15, kg = (lane>>4)*8;
  size_t rowbase = (size_t)(b*HGT + whi*4)*WID + wwi*16;
  {
    int t = tid >> 2;
    int c0 = (tid & 3)*32;
    size_t grow = rowbase + (size_t)(t>>4)*WID + (t&15);
    const float* src = XT + grow*C_DIM + c0;
    float m = stats[2*grow], rs = stats[2*grow+1];
    unsigned short* dst = &shm[XS_OFF + t*136 + c0];
    #pragma unroll
    for (int j=0;j<32;j++){
      float f = (src[j]-m)*rs*g1[c0+j] + b1[c0+j];
      dst[j] = f2bf(f);
    }
  }
  __syncthreads();
  unsigned short* Qw = &shm[WQK_OFF + wave*5120];
  unsigned short* Kw = Qw + 2560;
  unsigned short* Vt = &shm[VT_OFF + wave*2304];
  #pragma unroll
  for (int op=0; op<3; ++op){
    f32x4 acc[4][2];
    #pragma unroll
    for (int tf=0; tf<4; ++tf){ acc[tf][0] = (f32x4){}; acc[tf][1] = (f32x4){}; }
    int wrow0 = op*128 + head*32;
    #pragma unroll
    for (int kk0=0; kk0<128; kk0+=32){
      bf16x8 bfr0 = *(const bf16x8*)(QKVW + (size_t)(wrow0 + fm)*128 + kk0 + kg);
      bf16x8 bfr1 = *(const bf16x8*)(QKVW + (size_t)(wrow0 + 16 + fm)*128 + kk0 + kg);
      #pragma unroll
      for (int tf=0; tf<4; ++tf){
        bf16x8 af = *(const bf16x8*)&shm[XS_OFF + (tf*16+fm)*136 + kk0 + kg];
        acc[tf][0] = __builtin_amdgcn_mfma_f32_16x16x32_bf16(af, bfr0, acc[tf][0], 0,0,0);
        acc[tf][1] = __builtin_amdgcn_mfma_f32_16x16x32_bf16(af, bfr1, acc[tf][1], 0,0,0);
      }
    }
    #pragma unroll
    for (int tf=0; tf<4; ++tf){
      #pragma unroll
      for (int cf=0; cf<2; ++cf){
        int n = cf*16 + fm;
        float bsv = QKVB[op*128 + head*32 + n];
        #pragma unroll
        for (int r=0;r<4;r++){
          int token = tf*16 + (lane>>4)*4 + r;
          float v = acc[tf][cf][r] + bsv;
          if (op==0) v *= 0.17677669529663688f;
          unsigned short bv = f2bf(v);
          if (op==0)      Qw[token*40 + n] = bv;
          else if (op==1) Kw[token*40 + n] = bv;
          else            Vt[n*72 + token] = bv;
        }
      }
    }
  }
  __syncthreads();
  bf16x8 qf[4], kf[4];
  #pragma unroll
  for (int t4=0; t4<4; ++t4){
    qf[t4] = *(const bf16x8*)&Qw[(t4*16+fm)*40 + kg];
    kf[t4] = *(const bf16x8*)&Kw[(t4*16+fm)*40 + kg];
  }
  f32x4 s[4][4];
  #pragma unroll
  for (int ni=0; ni<4; ++ni)
    #pragma unroll
    for (int mj=0; mj<4; ++mj){
      f32x4 z = {};
      s[ni][mj] = __builtin_amdgcn_mfma_f32_16x16x32_bf16(qf[ni], kf[mj], z, 0,0,0);
    }
  const float* bp = biasT + head*4096;
  #pragma unroll
  for (int ni=0; ni<4; ++ni){
    int nbase = ni*16 + (lane>>4)*4;
    #pragma unroll
    for (int mj=0; mj<4; ++mj){
      int m = mj*16 + fm;
      #pragma unroll
      for (int r=0;r<4;r++)
        s[ni][mj][r] += bp[(nbase+r)*64 + m];
    }
  }
  float rs_[4][4];
  #pragma unroll
  for (int ni=0; ni<4; ++ni){
    #pragma unroll
    for (int r=0;r<4;r++){
      float t = fmaxf(fmaxf(s[ni][0][r], s[ni][1][r]), fmaxf(s[ni][2][r], s[ni][3][r]));
      #pragma unroll
      for (int o=1;o<16;o<<=1) t = fmaxf(t, __shfl_xor(t, o, 64));
      float sum = 0.f;
      #pragma unroll
      for (int mj=0; mj<4; ++mj){
        float e = __expf(s[ni][mj][r] - t);
        s[ni][mj][r] = e;
        sum += e;
      }
      #pragma unroll
      for (int o=1;o<16;o<<=1) sum += __shfl_xor(sum, o, 64);
      rs_[ni][r] = sum;
    }
  }
  __syncthreads();
  unsigned short* Ps = Qw;
  #pragma unroll
  for (int ni=0; ni<4; ++ni){
    int nbase = ni*16 + (lane>>4)*4;
    #pragma unroll
    for (int mj=0; mj<4; ++mj){
      int m = mj*16 + fm;
      #pragma unroll
      for (int r=0;r<4;r++)
        Ps[(nbase+r)*72 + m] = f2bf(s[ni][mj][r]);
    }
  }
  f32x4 o2[4][2];
  #pragma unroll
  for (int ni=0; ni<4; ++ni){ o2[ni][0] = (f32x4){}; o2[ni][1] = (f32x4){}; }
  #pragma unroll
  for (int ks=0; ks<2; ++ks){
    bf16x8 vb0 = *(const bf16x8*)&Vt[fm*72 + ks*32+kg];
    bf16x8 vb1 = *(const bf16x8*)&Vt[(16+fm)*72 + ks*32+kg];
    #pragma unroll
    for (int ni=0; ni<4; ++ni){
      bf16x8 pa = *(const bf16x8*)&Ps[(ni*16+fm)*72 + ks*32+kg];
      o2[ni][0] = __builtin_amdgcn_mfma_f32_16x16x32_bf16(pa, vb0, o2[ni][0], 0,0,0);
      o2[ni][1] = __builtin_amdgcn_mfma_f32_16x16x32_bf16(pa, vb1, o2[ni][1], 0,0,0);
    }
  }
  #pragma unroll
  for (int ni=0; ni<4; ++ni){
    #pragma unroll
    for (int r=0;r<4;r++){
      size_t l = rowbase + (size_t)ni*WID + (lane>>4)*4 + r;
      float inv = 1.0f / rs_[ni][r];
      unsigned short* op = OUTc + l*C_DIM + head*32;
      op[fm]    = f2bf(o2[ni][0][r]*inv);
      op[16+fm] = f2bf(o2[ni][1][r]*inv);
    }
  }
}

// ---------------- LeFF dwconv strip v2: rolling window, weights in registers ----------------
__global__ __launch_bounds__(256) void dwconv_strip(const unsigned short* __restrict__ SB1,
                                                    const float* __restrict__ dw,
                                                    const float* __restrict__ db,
                                                    unsigned short* __restrict__ SB2,
                                                    int r0){
  int blk = blockIdx.x;
  int wt = blk % 12, hl = blk / 12;
  int tid = threadIdx.x;
  int c4 = tid & 127, ph = tid >> 7;
  int ch = c4*4;
  int w0 = wt*16 + ph*8;
  int h = r0 + hl;
  float wreg[9][4], bias[4];
  #pragma unroll
  for (int j=0;j<4;j++){
    bias[j] = db[ch+j];
    #pragma unroll
    for (int t9=0;t9<9;t9++) wreg[t9][j] = dw[(ch+j)*9+t9];
  }
  const unsigned short* rp[3];
  bool rv[3];
  #pragma unroll
  for (int ky=0;ky<3;ky++){
    int hh = h + ky - 1;
    rv[ky] = (hh >= 0) && (hh < HGT);
    rp[ky] = SB1 + ((size_t)(hl+ky)*WID)*512 + ch;
  }
  float win[3][3][4];
  #pragma unroll
  for (int ky=0;ky<3;ky++){
    #pragma unroll
    for (int j=0;j<4;j++){ win[ky][0][j]=0.f; win[ky][1][j]=0.f; }
    if (rv[ky]){
      if (w0 > 0){
        const unsigned int* p = (const unsigned int*)(rp[ky] + (size_t)(w0-1)*512);
        unsigned int u0=p[0], u1=p[1];
        win[ky][0][0]=bf2f((unsigned short)(u0&0xFFFF)); win[ky][0][1]=bf2f((unsigned short)(u0>>16));
        win[ky][0][2]=bf2f((unsigned short)(u1&0xFFFF)); win[ky][0][3]=bf2f((unsigned short)(u1>>16));
      }
      {
        const unsigned int* p = (const unsigned int*)(rp[ky] + (size_t)w0*512);
        unsigned int u0=p[0], u1=p[1];
        win[ky][1][0]=bf2f((unsigned short)(u0&0xFFFF)); win[ky][1][1]=bf2f((unsigned short)(u0>>16));
        win[ky][1][2]=bf2f((unsigned short)(u1&0xFFFF)); win[ky][1][3]=bf2f((unsigned short)(u1>>16));
      }
    }
  }
  #pragma unroll
  for (int px=0; px<8; ++px){
    int w = w0 + px;
    #pragma unroll
    for (int ky=0;ky<3;ky++){
      #pragma unroll
      for (int j=0;j<4;j++) win[ky][2][j]=0.f;
      if (rv[ky] && (w+1) < WID){
        const unsigned int* p = (const unsigned int*)(rp[ky] + (size_t)(w+1)*512);
        unsigned int u0=p[0], u1=p[1];
        win[ky][2][0]=bf2f((unsigned short)(u0&0xFFFF)); win[ky][2][1]=bf2f((unsigned short)(u0>>16));
        win[ky][2][2]=bf2f((unsigned short)(u1&0xFFFF)); win[ky][2][3]=bf2f((unsigned short)(u1>>16));
      }
    }
    float a[4];
    #pragma unroll
    for (int j=0;j<4;j++){
      float acc = bias[j];
      #pragma unroll
      for (int ky=0;ky<3;ky++)
        #pragma unroll
        for (int kx=0;kx<3;kx++)
          acc += wreg[ky*3+kx][j]*win[ky][kx][j];
      a[j] = gelu_f(acc);
    }
    unsigned int o0 = (unsigned int)f2bf(a[0]) | ((unsigned int)f2bf(a[1])<<16);
    unsigned int o1 = (unsigned int)f2bf(a[2]) | ((unsigned int)f2bf(a[3])<<16);
    unsigned int* op = (unsigned int*)&SB2[((size_t)hl*WID + w)*512 + ch];
    op[0] = o0; op[1] = o1;
    #pragma unroll
    for (int ky=0;ky<3;ky++)
      #pragma unroll
      for (int j=0;j<4;j++){ win[ky][0][j]=win[ky][1][j]; win[ky][1][j]=win[ky][2][j]; }
  }
}

// ---------------- per-batch BHWC -> BCHW transpose (z = batch, stride param) ----------------
__global__ __launch_bounds__(256) void transpose_b_kernel(const float* __restrict__ src, float* __restrict__ dst,
                                                          size_t zstride){
  __shared__ float tile[128*65];
  int w0 = blockIdx.x*64, h = blockIdx.y;
  size_t zo = (size_t)blockIdx.z * zstride;
  int tid = threadIdx.x;
  for (int r=0; r<32; r++){
    int e = tid + 256*r; int c = e & 127, wl = e >> 7;
    tile[c*65 + wl] = src[zo + ((size_t)h*WID + w0 + wl)*C_DIM + c];
  }
  __syncthreads();
  for (int r=0; r<32; r++){
    int e = tid + 256*r; int wl = e & 63, c = e >> 6;
    dst[zo + ((size_t)c*HGT + h)*WID + w0 + wl] = tile[c*65 + wl];
  }
}

// ---------------- host ----------------
extern "C" void kernel_launch(void* const* d_in, const int* in_sizes, int n_in,
                              void* d_out, int out_size, void* d_ws, size_t ws_size,
                              hipStream_t stream) {
  const float* x      = (const float*)d_in[0];
  const float* pos_w  = (const float*)d_in[1];
  const float* pos_b  = (const float*)d_in[2];
  const float* ln1_g  = (const float*)d_in[3];
  const float* ln1_b  = (const float*)d_in[4];
  const float* q_w    = (const float*)d_in[5];
  const float* q_b    = (const float*)d_in[6];
  const float* kv_w   = (const float*)d_in[7];
  const float* kv_b   = (const float*)d_in[8];
  const float* rpb    = (const float*)d_in[9];
  const float* proj_w = (const float*)d_in[10];
  const float* proj_b = (const float*)d_in[11];
  const float* fft1_w = (const float*)d_in[12];
  const float* fft1_b = (const float*)d_in[13];
  const float* fft2_w = (const float*)d_in[14];
  const float* fft2_b = (const float*)d_in[15];
  const float* ln2_g  = (const float*)d_in[16];
  const float* ln2_b  = (const float*)d_in[17];
  const float* l1_w   = (const float*)d_in[18];
  const float* l1_b   = (const float*)d_in[19];
  const float* dw_w   = (const float*)d_in[20];
  const float* dw_b   = (const float*)d_in[21];
  const float* l2_w   = (const float*)d_in[22];
  const float* l2_b   = (const float*)d_in[23];

  const size_t S   = (size_t)NB*HGT*WID*C_DIM;   // 18,874,368
  const size_t Sb  = S/NB;                       //  4,718,592
  const size_t SZb = (size_t)HGT*WFD*C_DIM;      //  2,383,872 (u16 per spectrum half)
  const size_t GSZ = (size_t)HGT*WFD*256;        //  4,767,744 (u16)
  const int    P   = (int)(NB*HGT*WID);          // 147,456

  float* ws    = (float*)d_ws;
  float* TAB   = ws;
  float* STATS = ws + TAB_SZ;
  float* POOL  = ws + TAB_SZ + 2*(size_t)P;
  size_t head  = TAB_SZ + 2*(size_t)P;
  size_t pool  = (ws_size/4 > head) ? (ws_size/4 - head) : 0;

  bool xt_in_pool = (pool >= S + 11000000);
  float* XT     = xt_in_pool ? POOL : (float*)d_out;
  float* POOL2  = xt_in_pool ? POOL + S : POOL;
  size_t pool2  = xt_in_pool ? pool - S : pool;

  const float* biasT = TAB + T_BIAS;
  const float* QKVB  = TAB + T_QKVB;
  const unsigned short* UT = (const unsigned short*)(TAB + TF_SZ);
  const unsigned short* MW  = UT + UT_MW;
  const unsigned short* MHF = UT + UT_MHF;
  const unsigned short* MHI = UT + UT_MHI;
  const unsigned short* MWI = UT + UT_MWI;
  const unsigned short* QKVW  = UT + UT_QKVW;
  const unsigned short* PROJW = UT + UT_PROJW;
  const unsigned short* FFT1W = UT + UT_FFT1W;
  const unsigned short* FFT2W = UT + UT_FFT2W;
  const unsigned short* L1W   = UT + UT_L1W;
  const unsigned short* L2W   = UT + UT_L2W;

  build_tables<<<2858, 256, 0, stream>>>(TAB, rpb, q_b, kv_b, q_w, kv_w, proj_w,
                                         fft1_w, fft2_w, l1_w, l2_w);
  posconv3_kernel<<<dim3(6,24,32), 256, 0, stream>>>(x, pos_w, pos_b, XT);

  // ---- attention: LN1 stats -> fused(LN+QKV+attn) -> proj (128-tile GEMM) ----
  ln_stats_kernel<<<P/4, 256, 0, stream>>>(XT, STATS);
  {
    unsigned short* OUTu = (unsigned short*)POOL2;
    attn_fused2<<<2304, 256, 0, stream>>>(XT, STATS, ln1_g, ln1_b, QKVW, QKVB, biasT, OUTu);
    gemm3<0,true,false,true,false><<<dim3(1, P/128), 256, 0, stream>>>(
        OUTu, PROJW, proj_b, XT, 128, 128, 128, nullptr, nullptr, nullptr, 0, 0, P);
  }

  // ---- FFT residual branch: all-MFMA, bf16 spectra, balanced k-chunks ----
  {
    unsigned short* FRu = (unsigned short*)POOL2;
    unsigned short* FIu = FRu + SZb;
    unsigned short* Gu  = FIu + SZb;
    size_t fixed = SZb + GSZ/2;                  // floats used by FR+FI+G
    int CKmax = 1;
    if (pool2 > fixed + 49152) CKmax = (int)((pool2 - fixed)/49152);
    if (CKmax < 1) CKmax = 1;
    if (CKmax > WFD) CKmax = WFD;
    int nch = (WFD + CKmax - 1)/CKmax;
    int CK = (WFD + nch - 1)/nch;
    unsigned short* FF0u = (unsigned short*)(POOL2 + fixed);
    unsigned short* FF1u = FF0u + (size_t)CK*49152;
    for (int b = 0; b < NB; ++b){
      float* XTb = XT + (size_t)b*Sb;
      dft_gemm<0><<<dim3(2, 192*4), 256, 0, stream>>>(MW, XTb, nullptr, FRu, FIu, 0);
      for (int k0 = 0; k0 < WFD; k0 += CK){
        int ck = (WFD - k0 < CK) ? (WFD - k0) : CK;
        int rows = ck*192;
        dft_gemm<1><<<dim3(2, ck*6), 256, 0, stream>>>(MHF, FRu, FIu, FF0u, nullptr, k0);
        gemm3<1,false,false,true,true><<<dim3(2, (rows+127)/128), 256, 0, stream>>>(
            FF0u, FFT1W, fft1_b, FF1u, 256, 256, 256, nullptr, nullptr, nullptr, 0, 0, rows);
        gemm3<0,false,false,true,true><<<dim3(2, (rows+127)/128), 256, 0, stream>>>(
            FF1u, FFT2W, fft2_b, FF0u, 256, 256, 256, nullptr, nullptr, nullptr, 0, 0, rows);
        dft_gemm<2><<<dim3(2, ck*6), 256, 0, stream>>>(MHI, FF0u, FF0u+128, Gu, nullptr, k0);
      }
      dft_gemm<3><<<dim3(2, 192*3), 256, 0, stream>>>(MWI, Gu, Gu+128, XTb, nullptr, 0);
    }
  }

  // ---- LN2 stats ----
  ln_stats_kernel<<<P/4, 256, 0, stream>>>(XT, STATS);

  // ---- LeFF: strip-mined l1 gemm3 -> dwconv+gelu -> l2 gemm3 (+residual) ----
  {
    int SH = 96;
    while ((size_t)(3*SH+4)*49152 > pool2 && SH > 24) SH >>= 1;
    const size_t SB1SZ = (size_t)(SH+2)*98304;   // u16
    unsigned short* SB1u[2] = { (unsigned short*)POOL2, (unsigned short*)POOL2 + SB1SZ };
    unsigned short* SB2u = (unsigned short*)POOL2 + 2*SB1SZ;
    int nStrips = HGT/SH;
    for (int b = 0; b < NB; ++b){
      auto launch_g = [&](int s){
        int r0 = s*SH;
        int prow0 = (b*HGT + r0 - 1)*WID;
        int rows = (SH+2)*192;
        gemm3<2,false,true,false,true><<<dim3(4, (rows+127)/128), 256, 0, stream>>>(
            XT, L1W, l1_b, SB1u[s&1], 128, 512, 128,
            STATS, ln2_g, ln2_b, prow0, P-1, rows);
      };
      launch_g(0);
      for (int s = 0; s < nStrips; ++s){
        if (s+1 < nStrips) launch_g(s+1);
        int r0 = s*SH;
        dwconv_strip<<<12*SH, 256, 0, stream>>>(SB1u[s&1], dw_w, dw_b, SB2u, r0);
        int rows2 = SH*192;
        gemm3<0,true,false,true,false><<<dim3(1, (rows2+127)/128), 256, 0, stream>>>(
            SB2u, L2W, l2_b, XT + ((size_t)(b*HGT + r0)*WID)*C_DIM,
            512, 128, 512, nullptr, nullptr, nullptr, 0, 0, rows2);
      }
    }
  }

  // ---- final transpose ----
  if (xt_in_pool){
    transpose_b_kernel<<<dim3(3,192,4), 256, 0, stream>>>(XT, (float*)d_out, Sb);
  } else {
    for (int b = 0; b < NB; ++b){
      transpose_b_kernel<<<dim3(3,192,1), 256, 0, stream>>>(XT + (size_t)b*Sb, POOL2, 0);
      hipMemcpyAsync((float*)d_out + (size_t)b*Sb, POOL2, Sb*sizeof(float),
                     hipMemcpyDeviceToDevice, stream);
    }
  }
}

// Round 16
// 1257.588 us; speedup vs baseline: 1.1167x; 1.1167x over previous
//
#include <hip/hip_runtime.h>
#include <hip/hip_bf16.h>
#include <math.h>

// ---------------- constants ----------------
#define C_DIM 128
#define HGT 192
#define WID 192
#define NB 4
#define WFD 97   // 192/2+1

// TAB float region
#define T_BIAS  0                // 4*64*64 fp32
#define T_QKVB  16384            // 384 fp32 (q_b | kv_b)
#define TF_SZ   16896
// TAB bf16 region (ushort offsets, base = TAB + TF_SZ floats)
#define UT_MW    0               // [256][192]
#define UT_MHF   49152           // [384][384]
#define UT_MHI   196608          // [384][384]
#define UT_MWI   344064          // [192][224]
#define UT_QKVW  387072          // [384][128]
#define UT_PROJW 436224          // [128][128]
#define UT_FFT1W 452608          // [256][256]
#define UT_FFT2W 518144          // [256][256]
#define UT_L1W   583680          // [512][128]
#define UT_L2W   649216          // [128][512]
#define UT_TOT   714752
#define TAB_SZ   374272          // floats: TF_SZ + UT_TOT/2

typedef __attribute__((ext_vector_type(8))) short bf16x8;
typedef __attribute__((ext_vector_type(4))) float f32x4;

__device__ __forceinline__ float gelu_f(float v){
  return 0.5f*v*(1.0f + erff(v*0.70710678118654752440f));
}
__device__ __forceinline__ unsigned short f2bf(float f){
  __hip_bfloat16 h = __float2bfloat16(f);
  return *reinterpret_cast<unsigned short*>(&h);
}
__device__ __forceinline__ float bf2f(unsigned short u){
  unsigned int x = ((unsigned int)u)<<16;
  return __uint_as_float(x);
}
__device__ __forceinline__ void st8u(unsigned short* d, bf16x8 v){
  unsigned int* wp = (unsigned int*)&v;
  unsigned int* dp = (unsigned int*)d;
  dp[0]=wp[0]; dp[1]=wp[1]; dp[2]=wp[2]; dp[3]=wp[3];
}

// ---------------- table build (exact int mod-192 + float trig) ----------------
__global__ __launch_bounds__(256) void build_tables(float* __restrict__ tab,
        const float* __restrict__ rpb, const float* __restrict__ q_b, const float* __restrict__ kv_b,
        const float* __restrict__ q_w, const float* __restrict__ kv_w, const float* __restrict__ proj_w,
        const float* __restrict__ fft1_w, const float* __restrict__ fft2_w,
        const float* __restrict__ l1_w, const float* __restrict__ l2_w){
  int idx = blockIdx.x*256 + threadIdx.x;
  const float STEP = (float)(6.283185307179586476925286766559/192.0);
  if (idx < 16384){ // attn bias fp32: [head][n][m]
    int head = idx>>12, n = (idx>>6)&63, m = idx&63;
    int dh = n/16 - m/16 + 3;
    int dw = (n&15) - (m&15) + 15;
    tab[T_BIAS+idx] = rpb[(dh*31+dw)*4 + head];
    return;
  }
  idx -= 16384;
  if (idx < 384){ // QKV bias concat fp32
    tab[T_QKVB+idx] = (idx < 128) ? q_b[idx] : kv_b[idx-128];
    return;
  }
  idx -= 384;
  unsigned short* ut = (unsigned short*)(tab + TF_SZ);
  if (idx < 49152){ // MW [256][192]
    int r = idx/192, w = idx%192;
    float v = 0.f;
    if (r < 97){ int a = (r*w)%192; v = cosf(a*STEP); }
    else if (r < 194){ int a = ((r-97)*w)%192; v = -sinf(a*STEP); }
    ut[UT_MW+idx] = f2bf(v);
    return;
  }
  idx -= 49152;
  if (idx < 147456){ // MHF [384][384]
    int r = idx/384, j = idx%384;
    int hf = (r < 192) ? r : r-192;
    int h  = (j < 192) ? j : j-192;
    int a = (hf*h)%192;
    float c = cosf(a*STEP), s = sinf(a*STEP);
    float v;
    if (r < 192) v = (j < 192) ? c : s;
    else         v = (j < 192) ? -s : c;
    ut[UT_MHF+idx] = f2bf(v);
    return;
  }
  idx -= 147456;
  if (idx < 147456){ // MHI [384][384]
    int r = idx/384, j = idx%384;
    int h  = (r < 192) ? r : r-192;
    int hf = (j < 192) ? j : j-192;
    int a = (h*hf)%192;
    float c = cosf(a*STEP), s = sinf(a*STEP);
    float v;
    if (r < 192) v = (j < 192) ? c : -s;
    else         v = (j < 192) ? s : c;
    ut[UT_MHI+idx] = f2bf(v);
    return;
  }
  idx -= 147456;
  if (idx < 43008){ // MWI [192][224]
    int w = idx/224, j = idx%224;
    float v = 0.f;
    if (j < 97){
      int a = (j*w)%192;
      float sc = ((j==0 || j==96) ? 1.f : 2.f) / 36864.f;
      v = sc*cosf(a*STEP);
    } else if (j >= 112 && j < 209){
      int k = j-112;
      int a = (k*w)%192;
      float sc = ((k==0 || k==96) ? 1.f : 2.f) / 36864.f;
      v = -sc*sinf(a*STEP);
    }
    ut[UT_MWI+idx] = f2bf(v);
    return;
  }
  idx -= 43008;
  if (idx < 49152){ // QKVW [384][128]
    int n = idx/128, k = idx%128;
    float v = (n < 128) ? q_w[(size_t)k*128 + n] : kv_w[(size_t)k*256 + (n-128)];
    ut[UT_QKVW+idx] = f2bf(v);
    return;
  }
  idx -= 49152;
  if (idx < 16384){ // PROJW [128][128]
    int n = idx/128, k = idx%128;
    ut[UT_PROJW+idx] = f2bf(proj_w[(size_t)k*128 + n]);
    return;
  }
  idx -= 16384;
  if (idx < 65536){ // FFT1W [256][256]
    int n = idx/256, k = idx%256;
    ut[UT_FFT1W+idx] = f2bf(fft1_w[(size_t)k*256 + n]);
    return;
  }
  idx -= 65536;
  if (idx < 65536){ // FFT2W [256][256]
    int n = idx/256, k = idx%256;
    ut[UT_FFT2W+idx] = f2bf(fft2_w[(size_t)k*256 + n]);
    return;
  }
  idx -= 65536;
  if (idx < 65536){ // L1W [512][128]
    int n = idx/128, k = idx%128;
    ut[UT_L1W+idx] = f2bf(l1_w[(size_t)k*512 + n]);
    return;
  }
  idx -= 65536;
  if (idx < 65536){ // L2W [128][512]
    int n = idx/512, k = idx%512;
    ut[UT_L2W+idx] = f2bf(l2_w[(size_t)k*128 + n]);
  }
}

// ---------------- pos depthwise conv: 8h x 32w x 16c ----------------
__global__ __launch_bounds__(256) void posconv3_kernel(const float* __restrict__ x, const float* __restrict__ pw,
                               const float* __restrict__ pb, float* __restrict__ xt){
  __shared__ float rows_s[16*340];
  int w0 = blockIdx.x*32, h0 = blockIdx.y*8;
  int b = blockIdx.z >> 3, cb = (blockIdx.z & 7)*16;
  int tid = threadIdx.x;
  int hl = tid >> 5, wl = tid & 31;
  for (int e = tid; e < 16*340; e += 256){
    int c = e / 340; int rem = e - c*340;
    int r = rem / 34; int wc = rem - r*34;
    int gh = h0 - 1 + r, gw = w0 - 1 + wc;
    float v = 0.f;
    if (gh >= 0 && gh < HGT && gw >= 0 && gw < WID)
      v = x[((size_t)(b*C_DIM + cb + c))*(HGT*WID) + gh*WID + gw];
    rows_s[e] = v;
  }
  __syncthreads();
  float outr[16];
  #pragma unroll
  for (int c = 0; c < 16; ++c){
    const float* rs = &rows_s[c*340];
    float wreg[9];
    #pragma unroll
    for (int t9 = 0; t9 < 9; ++t9) wreg[t9] = pw[(cb+c)*27 + 9 + t9];
    float bias = pb[cb+c];
    float acc = rs[(hl+1)*34 + wl+1] + bias;
    #pragma unroll
    for (int ky = 0; ky < 3; ++ky)
      #pragma unroll
      for (int kx = 0; kx < 3; ++kx)
        acc += wreg[ky*3+kx]*rs[(hl+ky)*34 + wl+kx];
    outr[c] = acc;
  }
  __syncthreads();
  {
    int px = hl*32 + wl;
    #pragma unroll
    for (int c = 0; c < 16; ++c) rows_s[px*17 + c] = outr[c];
  }
  __syncthreads();
  for (int r = 0; r < 16; ++r){
    int e = r*256 + tid;
    int cl = e & 15, hw = e >> 4;
    int h = hw >> 5, w = hw & 31;
    xt[((size_t)(b*HGT + h0+h)*WID + (w0+w))*C_DIM + cb + cl] = rows_s[hw*17 + cl];
  }
}

// ---------------- LN row stats ----------------
__global__ __launch_bounds__(256) void ln_stats_kernel(const float* __restrict__ src, float* __restrict__ stats){
  int wave = threadIdx.x >> 6; int lane = threadIdx.x & 63;
  size_t p = (size_t)blockIdx.x*4 + wave;
  const float* s = src + p*C_DIM;
  float v0 = s[lane], v1 = s[lane+64];
  float sum = v0 + v1;
  #pragma unroll
  for (int o=1; o<64; o<<=1) sum += __shfl_xor(sum, o, 64);
  float m = sum * (1.0f/128.0f);
  float d0 = v0-m, d1 = v1-m;
  float vs = d0*d0 + d1*d1;
  #pragma unroll
  for (int o=1; o<64; o<<=1) vs += __shfl_xor(vs, o, 64);
  float rstd = rsqrtf(vs*(1.0f/128.0f) + 1e-5f);
  if (lane==0){ stats[2*p] = m; stats[2*p+1] = rstd; }
}

// ---------------- unified MFMA GEMM (64x64 tile, NT n-tiles) ----------------
template<int ACT, bool ADD, bool LNA, bool ABF, bool OBF, int NT>
__global__ __launch_bounds__(256) void gemm2(const void* __restrict__ A1v,
                            const unsigned short* __restrict__ WT, const float* __restrict__ bias,
                            void* __restrict__ dstv, int K, int N, int lda,
                            const float* __restrict__ stats, const float* __restrict__ lng,
                            const float* __restrict__ lnb, int prow0, int pmax){
  __shared__ __align__(16) unsigned short As[64*40];
  __shared__ __align__(16) unsigned short Bs[NT][64*40];
  int p0 = blockIdx.y*64, n00 = blockIdx.x*(64*NT);
  int tid = threadIdx.x;
  int wave = tid >> 6, lane = tid & 63;
  int wr = (wave>>1)*32, wc = (wave&1)*32;
  f32x4 acc[NT][4];
  #pragma unroll
  for (int nt=0; nt<NT; ++nt)
    #pragma unroll
    for (int q=0; q<4; ++q) acc[nt][q] = (f32x4){};
  int am = tid >> 2, ak = (tid & 3)*8;
  int brow = tid >> 2, bkk = (tid & 3)*8;
  for (int k0 = 0; k0 < K; k0 += 32){
    if constexpr (ABF){
      const unsigned short* A1u = (const unsigned short*)A1v;
      bf16x8 av = *(const bf16x8*)(A1u + (size_t)(p0+am)*lda + k0 + ak);
      st8u(&As[am*40 + ak], av);
    } else {
      int gp = p0 + am;
      float s0 = 0.f, s1 = 0.f;
      if (LNA){
        gp += prow0;
        gp = gp < 0 ? 0 : (gp > pmax ? pmax : gp);
        s0 = stats[2*gp]; s1 = stats[2*gp+1];
      }
      const float* src = (const float*)A1v + (size_t)gp*lda + k0 + ak;
      float4 aa = *(const float4*)src;
      float4 ab = *(const float4*)(src+4);
      float v[8] = {aa.x,aa.y,aa.z,aa.w,ab.x,ab.y,ab.z,ab.w};
      unsigned short* dp = &As[am*40 + ak];
      #pragma unroll
      for (int j=0;j<8;j++){
        float f = v[j];
        if (LNA) f = (f - s0)*s1*lng[k0+ak+j] + lnb[k0+ak+j];
        dp[j] = f2bf(f);
      }
    }
    #pragma unroll
    for (int nt=0; nt<NT; ++nt){
      bf16x8 wv = *(const bf16x8*)(WT + (size_t)(n00 + nt*64 + brow)*K + k0 + bkk);
      st8u(&Bs[nt][brow*40 + bkk], wv);
    }
    __syncthreads();
    int fm = lane & 15, kg = (lane>>4)*8;
    bf16x8 a0 = *(const bf16x8*)&As[(wr+fm)*40 + kg];
    bf16x8 a1 = *(const bf16x8*)&As[(wr+16+fm)*40 + kg];
    #pragma unroll
    for (int nt=0; nt<NT; ++nt){
      bf16x8 b0 = *(const bf16x8*)&Bs[nt][(wc+fm)*40 + kg];
      bf16x8 b1 = *(const bf16x8*)&Bs[nt][(wc+16+fm)*40 + kg];
      acc[nt][0] = __builtin_amdgcn_mfma_f32_16x16x32_bf16(a0, b0, acc[nt][0], 0,0,0);
      acc[nt][1] = __builtin_amdgcn_mfma_f32_16x16x32_bf16(a0, b1, acc[nt][1], 0,0,0);
      acc[nt][2] = __builtin_amdgcn_mfma_f32_16x16x32_bf16(a1, b0, acc[nt][2], 0,0,0);
      acc[nt][3] = __builtin_amdgcn_mfma_f32_16x16x32_bf16(a1, b1, acc[nt][3], 0,0,0);
    }
    __syncthreads();
  }
  int cn = lane & 15, rq = (lane>>4)*4;
  #pragma unroll
  for (int nt=0; nt<NT; ++nt){
    #pragma unroll
    for (int mi=0; mi<2; ++mi){
      #pragma unroll
      for (int ni=0; ni<2; ++ni){
        f32x4 a = acc[nt][mi*2+ni];
        int n = n00 + nt*64 + wc + ni*16 + cn;
        float bsv = bias[n];
        #pragma unroll
        for (int r=0; r<4; ++r){
          size_t row = (size_t)p0 + wr + mi*16 + rq + r;
          float v = a[r] + bsv;
          if (ACT==1) v = (v>=0.f) ? v : 0.01f*v;
          if (ACT==2) v = gelu_f(v);
          if constexpr (OBF){
            ((unsigned short*)dstv)[row*(size_t)N + n] = f2bf(v);
          } else {
            float* dst = (float*)dstv;
            if (ADD) v += dst[row*(size_t)N + n];
            dst[row*(size_t)N + n] = v;
          }
        }
      }
    }
  }
}

// ---------------- 128x128 MFMA GEMM (use only when grid >= ~500 blocks) ----------------
template<int ACT, bool ADD, bool LNA, bool ABF, bool OBF>
__global__ __launch_bounds__(256) void gemm3(const void* __restrict__ A1v,
                            const unsigned short* __restrict__ WT, const float* __restrict__ bias,
                            void* __restrict__ dstv, int K, int N, int lda,
                            const float* __restrict__ stats, const float* __restrict__ lng,
                            const float* __restrict__ lnb, int prow0, int pmax, int Mrows){
  __shared__ __align__(16) unsigned short As[128*40];
  __shared__ __align__(16) unsigned short Bs[128*40];
  int p0 = blockIdx.y*128, n0 = blockIdx.x*128;
  int tid = threadIdx.x;
  int wave = tid >> 6, lane = tid & 63;
  int wr = (wave>>1)*64, wc = (wave&1)*64;
  f32x4 acc[4][4];
  #pragma unroll
  for (int i=0;i<4;i++)
    #pragma unroll
    for (int j=0;j<4;j++) acc[i][j] = (f32x4){};
  int srow = tid >> 1, scol = (tid & 1)*16;
  for (int k0 = 0; k0 < K; k0 += 32){
    {
      if constexpr (ABF){
        int gr = p0 + srow;
        if (gr >= Mrows) gr = Mrows-1;
        const unsigned short* src = (const unsigned short*)A1v + (size_t)gr*lda + k0 + scol;
        st8u(&As[srow*40 + scol],     *(const bf16x8*)src);
        st8u(&As[srow*40 + scol + 8], *(const bf16x8*)(src+8));
      } else {
        int gp = p0 + srow;
        float s0 = 0.f, s1 = 1.f;
        if (LNA){
          gp += prow0;
          gp = gp < 0 ? 0 : (gp > pmax ? pmax : gp);
          s0 = stats[2*gp]; s1 = stats[2*gp+1];
        } else {
          if (gp >= Mrows) gp = Mrows-1;
        }
        const float* src = (const float*)A1v + (size_t)gp*lda + k0 + scol;
        unsigned short* dp = &As[srow*40 + scol];
        #pragma unroll
        for (int q=0;q<4;q++){
          float4 a4 = *(const float4*)(src + q*4);
          float v[4] = {a4.x,a4.y,a4.z,a4.w};
          #pragma unroll
          for (int j=0;j<4;j++){
            float f = v[j];
            if (LNA) f = (f - s0)*s1*lng[k0+scol+q*4+j] + lnb[k0+scol+q*4+j];
            dp[q*4+j] = f2bf(f);
          }
        }
      }
    }
    {
      const unsigned short* src = WT + (size_t)(n0 + srow)*K + k0 + scol;
      st8u(&Bs[srow*40 + scol],     *(const bf16x8*)src);
      st8u(&Bs[srow*40 + scol + 8], *(const bf16x8*)(src+8));
    }
    __syncthreads();
    int fm = lane & 15, kg = (lane>>4)*8;
    bf16x8 af[4], bf_[4];
    #pragma unroll
    for (int i=0;i<4;i++){
      af[i]  = *(const bf16x8*)&As[(wr + i*16 + fm)*40 + kg];
      bf_[i] = *(const bf16x8*)&Bs[(wc + i*16 + fm)*40 + kg];
    }
    #pragma unroll
    for (int i=0;i<4;i++)
      #pragma unroll
      for (int j=0;j<4;j++)
        acc[i][j] = __builtin_amdgcn_mfma_f32_16x16x32_bf16(af[i], bf_[j], acc[i][j], 0,0,0);
    __syncthreads();
  }
  int cn = lane & 15, rq = (lane>>4)*4;
  #pragma unroll
  for (int i=0;i<4;i++){
    #pragma unroll
    for (int j=0;j<4;j++){
      f32x4 a = acc[i][j];
      int n = n0 + wc + j*16 + cn;
      float bsv = bias[n];
      #pragma unroll
      for (int r=0;r<4;r++){
        int row = p0 + wr + i*16 + rq + r;
        if (row >= Mrows) continue;
        float v = a[r] + bsv;
        if (ACT==1) v = (v>=0.f) ? v : 0.01f*v;
        if (ACT==2) v = gelu_f(v);
        if constexpr (OBF){
          ((unsigned short*)dstv)[(size_t)row*N + n] = f2bf(v);
        } else {
          float* dst = (float*)dstv;
          if (ADD) v += dst[(size_t)row*N + n];
          dst[(size_t)row*N + n] = v;
        }
      }
    }
  }
}

// ---------------- DFT-as-GEMM (bf16 tables / bf16 spectra) ----------------
template<int MODE>
__global__ __launch_bounds__(256) void dft_gemm(const unsigned short* __restrict__ Atab,
                            const void* __restrict__ W1v, const void* __restrict__ W2v,
                            void* __restrict__ D1v, void* __restrict__ D2v, int k0){
  constexpr int K      = (MODE==0)?192 : (MODE==3)?224 : 384;
  constexpr int MT     = (MODE==0)?4 : (MODE==3)?3 : 6;
  constexpr int MVALID = (MODE==0)?194 : (MODE==3)?192 : 384;
  __shared__ __align__(16) unsigned short As[64*40];
  __shared__ __align__(16) unsigned short Bs[64*40];
  int slab = blockIdx.y / MT;
  int p0 = (blockIdx.y % MT)*64, n0 = blockIdx.x*64;
  int tid = threadIdx.x;
  int wave = tid >> 6, lane = tid & 63;
  int wr = (wave>>1)*32, wc = (wave&1)*32;
  f32x4 acc00 = {}, acc01 = {}, acc10 = {}, acc11 = {};
  int am = tid >> 2, ak = (tid & 3)*8;
  int bk = tid >> 3, bn = (tid & 7)*8;
  for (int kk0 = 0; kk0 < K; kk0 += 32){
    {
      bf16x8 av = *(const bf16x8*)(Atab + (size_t)(p0+am)*K + kk0 + ak);
      st8u(&As[am*40 + ak], av);
    }
    {
      int r = kk0 + bk;
      if (MODE==0){
        const float* src = (const float*)W1v + (size_t)slab*24576 + (size_t)r*128 + n0 + bn;
        float4 wa = *(const float4*)src;
        float4 wb = *(const float4*)(src+4);
        float v[8] = {wa.x,wa.y,wa.z,wa.w,wb.x,wb.y,wb.z,wb.w};
        #pragma unroll
        for (int j=0;j<8;j++) Bs[(bn+j)*40 + bk] = f2bf(v[j]);
      } else {
        const unsigned short* src;
        if (MODE==1) src = (r<192) ? (const unsigned short*)W1v + (size_t)(k0+slab)*128 + (size_t)r*12416
                                   : (const unsigned short*)W2v + (size_t)(k0+slab)*128 + (size_t)(r-192)*12416;
        else if (MODE==2) src = (r<192) ? (const unsigned short*)W1v + (size_t)slab*49152 + (size_t)r*256
                                        : (const unsigned short*)W2v + (size_t)slab*49152 + (size_t)(r-192)*256;
        else src = (r<112) ? (const unsigned short*)W1v + (size_t)slab*24832 + (size_t)r*256
                           : (const unsigned short*)W2v + (size_t)slab*24832 + (size_t)(r-112)*256;
        src += n0 + bn;
        bf16x8 wv = *(const bf16x8*)src;
        #pragma unroll
        for (int j=0;j<8;j++) Bs[(bn+j)*40 + bk] = (unsigned short)wv[j];
      }
    }
    __syncthreads();
    int fm = lane & 15, kg = (lane>>4)*8;
    bf16x8 a0 = *(const bf16x8*)&As[(wr+fm)*40 + kg];
    bf16x8 a1 = *(const bf16x8*)&As[(wr+16+fm)*40 + kg];
    bf16x8 b0 = *(const bf16x8*)&Bs[(wc+fm)*40 + kg];
    bf16x8 b1 = *(const bf16x8*)&Bs[(wc+16+fm)*40 + kg];
    acc00 = __builtin_amdgcn_mfma_f32_16x16x32_bf16(a0, b0, acc00, 0,0,0);
    acc01 = __builtin_amdgcn_mfma_f32_16x16x32_bf16(a0, b1, acc01, 0,0,0);
    acc10 = __builtin_amdgcn_mfma_f32_16x16x32_bf16(a1, b0, acc10, 0,0,0);
    acc11 = __builtin_amdgcn_mfma_f32_16x16x32_bf16(a1, b1, acc11, 0,0,0);
    __syncthreads();
  }
  int cn = lane & 15, rq = (lane>>4)*4;
  #pragma unroll
  for (int mi=0; mi<2; ++mi){
    #pragma unroll
    for (int ni=0; ni<2; ++ni){
      f32x4 a = (mi==0) ? (ni==0?acc00:acc01) : (ni==0?acc10:acc11);
      int n = n0 + wc + ni*16 + cn;
      #pragma unroll
      for (int r=0; r<4; ++r){
        int p = p0 + wr + mi*16 + rq + r;
        if (p >= MVALID) continue;
        float v = a[r];
        if (MODE==0){
          unsigned short* D1 = (unsigned short*)D1v;
          unsigned short* D2 = (unsigned short*)D2v;
          if (p < 97) D1[(size_t)slab*12416 + (size_t)p*128 + n] = f2bf(v);
          else        D2[(size_t)slab*12416 + (size_t)(p-97)*128 + n] = f2bf(v);
        } else if (MODE==1){
          unsigned short* base = (unsigned short*)D1v + (size_t)slab*49152;
          if (p < 192) base[(size_t)p*256 + n] = f2bf(v);
          else         base[(size_t)(p-192)*256 + 128 + n] = f2bf(v);
        } else if (MODE==2){
          unsigned short* D1 = (unsigned short*)D1v;
          int kg2 = k0 + slab;
          if (p < 192) D1[((size_t)p*97 + kg2)*256 + n] = f2bf(v);
          else         D1[((size_t)(p-192)*97 + kg2)*256 + 128 + n] = f2bf(v);
        } else {
          ((float*)D1v)[(size_t)slab*24576 + (size_t)p*128 + n] += v;
        }
      }
    }
  }
}

// ---------------- fused attention: LN + QKV proj (MFMA) + window attn ----------------
#define XS_OFF  0                      // [64][136]
#define WQK_OFF 8704                   // + wave*5120 : Qw [64][40], Kw at +2560; P alias [64][72]
#define VT_OFF  29184                  // + wave*2304 : Vt [32][72]
#define SHM_TOT 38400
__global__ __launch_bounds__(256) void attn_fused2(
    const float* __restrict__ XT, const float* __restrict__ stats,
    const float* __restrict__ g1, const float* __restrict__ b1,
    const unsigned short* __restrict__ QKVW, const float* __restrict__ QKVB,
    const float* __restrict__ biasT, unsigned short* __restrict__ OUTc){
  __shared__ __align__(16) unsigned short shm[SHM_TOT];
  int win = blockIdx.x;
  int b = win/576, rem = win%576, whi = rem/12, wwi = rem%12;
  int tid = threadIdx.x, wave = tid>>6, lane = tid&63, head = wave;
  int fm = lane & 15, kg = (lane>>4)*8;
  size_t rowbase = (size_t)(b*HGT + whi*4)*WID + wwi*16;
  {
    int t = tid >> 2;
    int c0 = (tid & 3)*32;
    size_t grow = rowbase + (size_t)(t>>4)*WID + (t&15);
    const float* src = XT + grow*C_DIM + c0;
    float m = stats[2*grow], rs = stats[2*grow+1];
    unsigned short* dst = &shm[XS_OFF + t*136 + c0];
    #pragma unroll
    for (int j=0;j<32;j++){
      float f = (src[j]-m)*rs*g1[c0+j] + b1[c0+j];
      dst[j] = f2bf(f);
    }
  }
  __syncthreads();
  unsigned short* Qw = &shm[WQK_OFF + wave*5120];
  unsigned short* Kw = Qw + 2560;
  unsigned short* Vt = &shm[VT_OFF + wave*2304];
  #pragma unroll
  for (int op=0; op<3; ++op){
    f32x4 acc[4][2];
    #pragma unroll
    for (int tf=0; tf<4; ++tf){ acc[tf][0] = (f32x4){}; acc[tf][1] = (f32x4){}; }
    int wrow0 = op*128 + head*32;
    #pragma unroll
    for (int kk0=0; kk0<128; kk0+=32){
      bf16x8 bfr0 = *(const bf16x8*)(QKVW + (size_t)(wrow0 + fm)*128 + kk0 + kg);
      bf16x8 bfr1 = *(const bf16x8*)(QKVW + (size_t)(wrow0 + 16 + fm)*128 + kk0 + kg);
      #pragma unroll
      for (int tf=0; tf<4; ++tf){
        bf16x8 af = *(const bf16x8*)&shm[XS_OFF + (tf*16+fm)*136 + kk0 + kg];
        acc[tf][0] = __builtin_amdgcn_mfma_f32_16x16x32_bf16(af, bfr0, acc[tf][0], 0,0,0);
        acc[tf][1] = __builtin_amdgcn_mfma_f32_16x16x32_bf16(af, bfr1, acc[tf][1], 0,0,0);
      }
    }
    #pragma unroll
    for (int tf=0; tf<4; ++tf){
      #pragma unroll
      for (int cf=0; cf<2; ++cf){
        int n = cf*16 + fm;
        float bsv = QKVB[op*128 + head*32 + n];
        #pragma unroll
        for (int r=0;r<4;r++){
          int token = tf*16 + (lane>>4)*4 + r;
          float v = acc[tf][cf][r] + bsv;
          if (op==0) v *= 0.17677669529663688f;
          unsigned short bv = f2bf(v);
          if (op==0)      Qw[token*40 + n] = bv;
          else if (op==1) Kw[token*40 + n] = bv;
          else            Vt[n*72 + token] = bv;
        }
      }
    }
  }
  __syncthreads();
  bf16x8 qf[4], kf[4];
  #pragma unroll
  for (int t4=0; t4<4; ++t4){
    qf[t4] = *(const bf16x8*)&Qw[(t4*16+fm)*40 + kg];
    kf[t4] = *(const bf16x8*)&Kw[(t4*16+fm)*40 + kg];
  }
  f32x4 s[4][4];
  #pragma unroll
  for (int ni=0; ni<4; ++ni)
    #pragma unroll
    for (int mj=0; mj<4; ++mj){
      f32x4 z = {};
      s[ni][mj] = __builtin_amdgcn_mfma_f32_16x16x32_bf16(qf[ni], kf[mj], z, 0,0,0);
    }
  const float* bp = biasT + head*4096;
  #pragma unroll
  for (int ni=0; ni<4; ++ni){
    int nbase = ni*16 + (lane>>4)*4;
    #pragma unroll
    for (int mj=0; mj<4; ++mj){
      int m = mj*16 + fm;
      #pragma unroll
      for (int r=0;r<4;r++)
        s[ni][mj][r] += bp[(nbase+r)*64 + m];
    }
  }
  float rs_[4][4];
  #pragma unroll
  for (int ni=0; ni<4; ++ni){
    #pragma unroll
    for (int r=0;r<4;r++){
      float t = fmaxf(fmaxf(s[ni][0][r], s[ni][1][r]), fmaxf(s[ni][2][r], s[ni][3][r]));
      #pragma unroll
      for (int o=1;o<16;o<<=1) t = fmaxf(t, __shfl_xor(t, o, 64));
      float sum = 0.f;
      #pragma unroll
      for (int mj=0; mj<4; ++mj){
        float e = __expf(s[ni][mj][r] - t);
        s[ni][mj][r] = e;
        sum += e;
      }
      #pragma unroll
      for (int o=1;o<16;o<<=1) sum += __shfl_xor(sum, o, 64);
      rs_[ni][r] = sum;
    }
  }
  __syncthreads();
  unsigned short* Ps = Qw;
  #pragma unroll
  for (int ni=0; ni<4; ++ni){
    int nbase = ni*16 + (lane>>4)*4;
    #pragma unroll
    for (int mj=0; mj<4; ++mj){
      int m = mj*16 + fm;
      #pragma unroll
      for (int r=0;r<4;r++)
        Ps[(nbase+r)*72 + m] = f2bf(s[ni][mj][r]);
    }
  }
  f32x4 o2[4][2];
  #pragma unroll
  for (int ni=0; ni<4; ++ni){ o2[ni][0] = (f32x4){}; o2[ni][1] = (f32x4){}; }
  #pragma unroll
  for (int ks=0; ks<2; ++ks){
    bf16x8 vb0 = *(const bf16x8*)&Vt[fm*72 + ks*32+kg];
    bf16x8 vb1 = *(const bf16x8*)&Vt[(16+fm)*72 + ks*32+kg];
    #pragma unroll
    for (int ni=0; ni<4; ++ni){
      bf16x8 pa = *(const bf16x8*)&Ps[(ni*16+fm)*72 + ks*32+kg];
      o2[ni][0] = __builtin_amdgcn_mfma_f32_16x16x32_bf16(pa, vb0, o2[ni][0], 0,0,0);
      o2[ni][1] = __builtin_amdgcn_mfma_f32_16x16x32_bf16(pa, vb1, o2[ni][1], 0,0,0);
    }
  }
  #pragma unroll
  for (int ni=0; ni<4; ++ni){
    #pragma unroll
    for (int r=0;r<4;r++){
      size_t l = rowbase + (size_t)ni*WID + (lane>>4)*4 + r;
      float inv = 1.0f / rs_[ni][r];
      unsigned short* op = OUTc + l*C_DIM + head*32;
      op[fm]    = f2bf(o2[ni][0][r]*inv);
      op[16+fm] = f2bf(o2[ni][1][r]*inv);
    }
  }
}

// ---------------- LeFF dwconv strip v2: rolling window, weights in registers ----------------
__global__ __launch_bounds__(256) void dwconv_strip(const unsigned short* __restrict__ SB1,
                                                    const float* __restrict__ dw,
                                                    const float* __restrict__ db,
                                                    unsigned short* __restrict__ SB2,
                                                    int r0){
  int blk = blockIdx.x;
  int wt = blk % 12, hl = blk / 12;
  int tid = threadIdx.x;
  int c4 = tid & 127, ph = tid >> 7;
  int ch = c4*4;
  int w0 = wt*16 + ph*8;
  int h = r0 + hl;
  float wreg[9][4], bias[4];
  #pragma unroll
  for (int j=0;j<4;j++){
    bias[j] = db[ch+j];
    #pragma unroll
    for (int t9=0;t9<9;t9++) wreg[t9][j] = dw[(ch+j)*9+t9];
  }
  const unsigned short* rp[3];
  bool rv[3];
  #pragma unroll
  for (int ky=0;ky<3;ky++){
    int hh = h + ky - 1;
    rv[ky] = (hh >= 0) && (hh < HGT);
    rp[ky] = SB1 + ((size_t)(hl+ky)*WID)*512 + ch;
  }
  float win[3][3][4];
  #pragma unroll
  for (int ky=0;ky<3;ky++){
    #pragma unroll
    for (int j=0;j<4;j++){ win[ky][0][j]=0.f; win[ky][1][j]=0.f; }
    if (rv[ky]){
      if (w0 > 0){
        const unsigned int* p = (const unsigned int*)(rp[ky] + (size_t)(w0-1)*512);
        unsigned int u0=p[0], u1=p[1];
        win[ky][0][0]=bf2f((unsigned short)(u0&0xFFFF)); win[ky][0][1]=bf2f((unsigned short)(u0>>16));
        win[ky][0][2]=bf2f((unsigned short)(u1&0xFFFF)); win[ky][0][3]=bf2f((unsigned short)(u1>>16));
      }
      {
        const unsigned int* p = (const unsigned int*)(rp[ky] + (size_t)w0*512);
        unsigned int u0=p[0], u1=p[1];
        win[ky][1][0]=bf2f((unsigned short)(u0&0xFFFF)); win[ky][1][1]=bf2f((unsigned short)(u0>>16));
        win[ky][1][2]=bf2f((unsigned short)(u1&0xFFFF)); win[ky][1][3]=bf2f((unsigned short)(u1>>16));
      }
    }
  }
  #pragma unroll
  for (int px=0; px<8; ++px){
    int w = w0 + px;
    #pragma unroll
    for (int ky=0;ky<3;ky++){
      #pragma unroll
      for (int j=0;j<4;j++) win[ky][2][j]=0.f;
      if (rv[ky] && (w+1) < WID){
        const unsigned int* p = (const unsigned int*)(rp[ky] + (size_t)(w+1)*512);
        unsigned int u0=p[0], u1=p[1];
        win[ky][2][0]=bf2f((unsigned short)(u0&0xFFFF)); win[ky][2][1]=bf2f((unsigned short)(u0>>16));
        win[ky][2][2]=bf2f((unsigned short)(u1&0xFFFF)); win[ky][2][3]=bf2f((unsigned short)(u1>>16));
      }
    }
    float a[4];
    #pragma unroll
    for (int j=0;j<4;j++){
      float acc = bias[j];
      #pragma unroll
      for (int ky=0;ky<3;ky++)
        #pragma unroll
        for (int kx=0;kx<3;kx++)
          acc += wreg[ky*3+kx][j]*win[ky][kx][j];
      a[j] = gelu_f(acc);
    }
    unsigned int o0 = (unsigned int)f2bf(a[0]) | ((unsigned int)f2bf(a[1])<<16);
    unsigned int o1 = (unsigned int)f2bf(a[2]) | ((unsigned int)f2bf(a[3])<<16);
    unsigned int* op = (unsigned int*)&SB2[((size_t)hl*WID + w)*512 + ch];
    op[0] = o0; op[1] = o1;
    #pragma unroll
    for (int ky=0;ky<3;ky++)
      #pragma unroll
      for (int j=0;j<4;j++){ win[ky][0][j]=win[ky][1][j]; win[ky][1][j]=win[ky][2][j]; }
  }
}

// ---------------- per-batch BHWC -> BCHW transpose (z = batch, stride param) ----------------
__global__ __launch_bounds__(256) void transpose_b_kernel(const float* __restrict__ src, float* __restrict__ dst,
                                                          size_t zstride){
  __shared__ float tile[128*65];
  int w0 = blockIdx.x*64, h = blockIdx.y;
  size_t zo = (size_t)blockIdx.z * zstride;
  int tid = threadIdx.x;
  for (int r=0; r<32; r++){
    int e = tid + 256*r; int c = e & 127, wl = e >> 7;
    tile[c*65 + wl] = src[zo + ((size_t)h*WID + w0 + wl)*C_DIM + c];
  }
  __syncthreads();
  for (int r=0; r<32; r++){
    int e = tid + 256*r; int wl = e & 63, c = e >> 6;
    dst[zo + ((size_t)c*HGT + h)*WID + w0 + wl] = tile[c*65 + wl];
  }
}

// ---------------- host ----------------
extern "C" void kernel_launch(void* const* d_in, const int* in_sizes, int n_in,
                              void* d_out, int out_size, void* d_ws, size_t ws_size,
                              hipStream_t stream) {
  const float* x      = (const float*)d_in[0];
  const float* pos_w  = (const float*)d_in[1];
  const float* pos_b  = (const float*)d_in[2];
  const float* ln1_g  = (const float*)d_in[3];
  const float* ln1_b  = (const float*)d_in[4];
  const float* q_w    = (const float*)d_in[5];
  const float* q_b    = (const float*)d_in[6];
  const float* kv_w   = (const float*)d_in[7];
  const float* kv_b   = (const float*)d_in[8];
  const float* rpb    = (const float*)d_in[9];
  const float* proj_w = (const float*)d_in[10];
  const float* proj_b = (const float*)d_in[11];
  const float* fft1_w = (const float*)d_in[12];
  const float* fft1_b = (const float*)d_in[13];
  const float* fft2_w = (const float*)d_in[14];
  const float* fft2_b = (const float*)d_in[15];
  const float* ln2_g  = (const float*)d_in[16];
  const float* ln2_b  = (const float*)d_in[17];
  const float* l1_w   = (const float*)d_in[18];
  const float* l1_b   = (const float*)d_in[19];
  const float* dw_w   = (const float*)d_in[20];
  const float* dw_b   = (const float*)d_in[21];
  const float* l2_w   = (const float*)d_in[22];
  const float* l2_b   = (const float*)d_in[23];

  const size_t S   = (size_t)NB*HGT*WID*C_DIM;   // 18,874,368
  const size_t Sb  = S/NB;                       //  4,718,592
  const size_t SZb = (size_t)HGT*WFD*C_DIM;      //  2,383,872 (u16 per spectrum half)
  const size_t GSZ = (size_t)HGT*WFD*256;        //  4,767,744 (u16)
  const int    P   = (int)(NB*HGT*WID);          // 147,456

  float* ws    = (float*)d_ws;
  float* TAB   = ws;
  float* STATS = ws + TAB_SZ;
  float* POOL  = ws + TAB_SZ + 2*(size_t)P;
  size_t head  = TAB_SZ + 2*(size_t)P;
  size_t pool  = (ws_size/4 > head) ? (ws_size/4 - head) : 0;

  bool xt_in_pool = (pool >= S + 11000000);
  float* XT     = xt_in_pool ? POOL : (float*)d_out;
  float* POOL2  = xt_in_pool ? POOL + S : POOL;
  size_t pool2  = xt_in_pool ? pool - S : pool;

  const float* biasT = TAB + T_BIAS;
  const float* QKVB  = TAB + T_QKVB;
  const unsigned short* UT = (const unsigned short*)(TAB + TF_SZ);
  const unsigned short* MW  = UT + UT_MW;
  const unsigned short* MHF = UT + UT_MHF;
  const unsigned short* MHI = UT + UT_MHI;
  const unsigned short* MWI = UT + UT_MWI;
  const unsigned short* QKVW  = UT + UT_QKVW;
  const unsigned short* PROJW = UT + UT_PROJW;
  const unsigned short* FFT1W = UT + UT_FFT1W;
  const unsigned short* FFT2W = UT + UT_FFT2W;
  const unsigned short* L1W   = UT + UT_L1W;
  const unsigned short* L2W   = UT + UT_L2W;

  build_tables<<<2858, 256, 0, stream>>>(TAB, rpb, q_b, kv_b, q_w, kv_w, proj_w,
                                         fft1_w, fft2_w, l1_w, l2_w);
  posconv3_kernel<<<dim3(6,24,32), 256, 0, stream>>>(x, pos_w, pos_b, XT);

  // ---- attention: LN1 stats -> fused(LN+QKV+attn) -> proj (gemm3, 1152 blocks) ----
  ln_stats_kernel<<<P/4, 256, 0, stream>>>(XT, STATS);
  {
    unsigned short* OUTu = (unsigned short*)POOL2;
    attn_fused2<<<2304, 256, 0, stream>>>(XT, STATS, ln1_g, ln1_b, QKVW, QKVB, biasT, OUTu);
    gemm3<0,true,false,true,false><<<dim3(1, P/128), 256, 0, stream>>>(
        OUTu, PROJW, proj_b, XT, 128, 128, 128, nullptr, nullptr, nullptr, 0, 0, P);
  }

  // ---- FFT residual branch: all-MFMA, bf16 spectra, balanced k-chunks; mixes = gemm2 ----
  {
    unsigned short* FRu = (unsigned short*)POOL2;
    unsigned short* FIu = FRu + SZb;
    unsigned short* Gu  = FIu + SZb;
    size_t fixed = SZb + GSZ/2;                  // floats used by FR+FI+G
    int CKmax = 1;
    if (pool2 > fixed + 49152) CKmax = (int)((pool2 - fixed)/49152);
    if (CKmax < 1) CKmax = 1;
    if (CKmax > WFD) CKmax = WFD;
    int nch = (WFD + CKmax - 1)/CKmax;
    int CK = (WFD + nch - 1)/nch;
    unsigned short* FF0u = (unsigned short*)(POOL2 + fixed);
    unsigned short* FF1u = FF0u + (size_t)CK*49152;
    for (int b = 0; b < NB; ++b){
      float* XTb = XT + (size_t)b*Sb;
      dft_gemm<0><<<dim3(2, 192*4), 256, 0, stream>>>(MW, XTb, nullptr, FRu, FIu, 0);
      for (int k0 = 0; k0 < WFD; k0 += CK){
        int ck = (WFD - k0 < CK) ? (WFD - k0) : CK;
        int rows = ck*192;
        dft_gemm<1><<<dim3(2, ck*6), 256, 0, stream>>>(MHF, FRu, FIu, FF0u, nullptr, k0);
        gemm2<1,false,false,true,true,1><<<dim3(4, rows/64), 256, 0, stream>>>(
            FF0u, FFT1W, fft1_b, FF1u, 256, 256, 256, nullptr, nullptr, nullptr, 0, 0);
        gemm2<0,false,false,true,true,1><<<dim3(4, rows/64), 256, 0, stream>>>(
            FF1u, FFT2W, fft2_b, FF0u, 256, 256, 256, nullptr, nullptr, nullptr, 0, 0);
        dft_gemm<2><<<dim3(2, ck*6), 256, 0, stream>>>(MHI, FF0u, FF0u+128, Gu, nullptr, k0);
      }
      dft_gemm<3><<<dim3(2, 192*3), 256, 0, stream>>>(MWI, Gu, Gu+128, XTb, nullptr, 0);
    }
  }

  // ---- LN2 stats ----
  ln_stats_kernel<<<P/4, 256, 0, stream>>>(XT, STATS);

  // ---- LeFF: strip-mined l1 (gemm3, 588 blocks) -> dwconv+gelu -> l2 (gemm2, 576 blocks) ----
  {
    int SH = 96;
    while ((size_t)(3*SH+4)*49152 > pool2 && SH > 24) SH >>= 1;
    const size_t SB1SZ = (size_t)(SH+2)*98304;   // u16
    unsigned short* SB1u[2] = { (unsigned short*)POOL2, (unsigned short*)POOL2 + SB1SZ };
    unsigned short* SB2u = (unsigned short*)POOL2 + 2*SB1SZ;
    int nStrips = HGT/SH;
    for (int b = 0; b < NB; ++b){
      auto launch_g = [&](int s){
        int r0 = s*SH;
        int prow0 = (b*HGT + r0 - 1)*WID;
        int rows = (SH+2)*192;
        gemm3<2,false,true,false,true><<<dim3(4, (rows+127)/128), 256, 0, stream>>>(
            XT, L1W, l1_b, SB1u[s&1], 128, 512, 128,
            STATS, ln2_g, ln2_b, prow0, P-1, rows);
      };
      launch_g(0);
      for (int s = 0; s < nStrips; ++s){
        if (s+1 < nStrips) launch_g(s+1);
        int r0 = s*SH;
        dwconv_strip<<<12*SH, 256, 0, stream>>>(SB1u[s&1], dw_w, dw_b, SB2u, r0);
        gemm2<0,true,false,true,false,1><<<dim3(2, SH*3), 256, 0, stream>>>(
            SB2u, L2W, l2_b, XT + ((size_t)(b*HGT + r0)*WID)*C_DIM,
            512, 128, 512, nullptr, nullptr, nullptr, 0, 0);
      }
    }
  }

  // ---- final transpose ----
  if (xt_in_pool){
    transpose_b_kernel<<<dim3(3,192,4), 256, 0, stream>>>(XT, (float*)d_out, Sb);
  } else {
    for (int b = 0; b < NB; ++b){
      transpose_b_kernel<<<dim3(3,192,1), 256, 0, stream>>>(XT + (size_t)b*Sb, POOL2, 0);
      hipMemcpyAsync((float*)d_out + (size_t)b*Sb, POOL2, Sb*sizeof(float),
                     hipMemcpyDeviceToDevice, stream);
    }
  }
}

// Round 17
// 1183.591 us; speedup vs baseline: 1.1866x; 1.0625x over previous
//
#include <hip/hip_runtime.h>
#include <hip/hip_bf16.h>
#include <math.h>

// ---------------- constants ----------------
#define C_DIM 128
#define HGT 192
#define WID 192
#define NB 4
#define WFD 97   // 192/2+1

// TAB float region
#define T_BIAS  0                // 4*64*64 fp32
#define T_QKVB  16384            // 384 fp32 (q_b | kv_b)
#define TF_SZ   16896
// TAB bf16 region (ushort offsets, base = TAB + TF_SZ floats)
#define UT_MW    0               // [256][192]
#define UT_MHF   49152           // [384][384]
#define UT_MHI   196608          // [384][384]
#define UT_MWI   344064          // [192][224]
#define UT_QKVW  387072          // [384][128]
#define UT_PROJW 436224          // [128][128]
#define UT_FFT1W 452608          // [256][256]
#define UT_FFT2W 518144          // [256][256]
#define UT_L1W   583680          // [512][128]
#define UT_L2W   649216          // [128][512]
#define UT_TOT   714752
#define TAB_SZ   374272          // floats: TF_SZ + UT_TOT/2

typedef __attribute__((ext_vector_type(8))) short bf16x8;
typedef __attribute__((ext_vector_type(4))) float f32x4;

__device__ __forceinline__ float gelu_f(float v){
  return 0.5f*v*(1.0f + erff(v*0.70710678118654752440f));
}
__device__ __forceinline__ unsigned short f2bf(float f){
  __hip_bfloat16 h = __float2bfloat16(f);
  return *reinterpret_cast<unsigned short*>(&h);
}
__device__ __forceinline__ float bf2f(unsigned short u){
  unsigned int x = ((unsigned int)u)<<16;
  return __uint_as_float(x);
}
__device__ __forceinline__ void st8u(unsigned short* d, bf16x8 v){
  unsigned int* wp = (unsigned int*)&v;
  unsigned int* dp = (unsigned int*)d;
  dp[0]=wp[0]; dp[1]=wp[1]; dp[2]=wp[2]; dp[3]=wp[3];
}

// ---------------- table build (exact int mod-192 + float trig) ----------------
__global__ __launch_bounds__(256) void build_tables(float* __restrict__ tab,
        const float* __restrict__ rpb, const float* __restrict__ q_b, const float* __restrict__ kv_b,
        const float* __restrict__ q_w, const float* __restrict__ kv_w, const float* __restrict__ proj_w,
        const float* __restrict__ fft1_w, const float* __restrict__ fft2_w,
        const float* __restrict__ l1_w, const float* __restrict__ l2_w){
  int idx = blockIdx.x*256 + threadIdx.x;
  const float STEP = (float)(6.283185307179586476925286766559/192.0);
  if (idx < 16384){ // attn bias fp32: [head][n][m]
    int head = idx>>12, n = (idx>>6)&63, m = idx&63;
    int dh = n/16 - m/16 + 3;
    int dw = (n&15) - (m&15) + 15;
    tab[T_BIAS+idx] = rpb[(dh*31+dw)*4 + head];
    return;
  }
  idx -= 16384;
  if (idx < 384){ // QKV bias concat fp32
    tab[T_QKVB+idx] = (idx < 128) ? q_b[idx] : kv_b[idx-128];
    return;
  }
  idx -= 384;
  unsigned short* ut = (unsigned short*)(tab + TF_SZ);
  if (idx < 49152){ // MW [256][192]
    int r = idx/192, w = idx%192;
    float v = 0.f;
    if (r < 97){ int a = (r*w)%192; v = cosf(a*STEP); }
    else if (r < 194){ int a = ((r-97)*w)%192; v = -sinf(a*STEP); }
    ut[UT_MW+idx] = f2bf(v);
    return;
  }
  idx -= 49152;
  if (idx < 147456){ // MHF [384][384]
    int r = idx/384, j = idx%384;
    int hf = (r < 192) ? r : r-192;
    int h  = (j < 192) ? j : j-192;
    int a = (hf*h)%192;
    float c = cosf(a*STEP), s = sinf(a*STEP);
    float v;
    if (r < 192) v = (j < 192) ? c : s;
    else         v = (j < 192) ? -s : c;
    ut[UT_MHF+idx] = f2bf(v);
    return;
  }
  idx -= 147456;
  if (idx < 147456){ // MHI [384][384]
    int r = idx/384, j = idx%384;
    int h  = (r < 192) ? r : r-192;
    int hf = (j < 192) ? j : j-192;
    int a = (h*hf)%192;
    float c = cosf(a*STEP), s = sinf(a*STEP);
    float v;
    if (r < 192) v = (j < 192) ? c : -s;
    else         v = (j < 192) ? s : c;
    ut[UT_MHI+idx] = f2bf(v);
    return;
  }
  idx -= 147456;
  if (idx < 43008){ // MWI [192][224]
    int w = idx/224, j = idx%224;
    float v = 0.f;
    if (j < 97){
      int a = (j*w)%192;
      float sc = ((j==0 || j==96) ? 1.f : 2.f) / 36864.f;
      v = sc*cosf(a*STEP);
    } else if (j >= 112 && j < 209){
      int k = j-112;
      int a = (k*w)%192;
      float sc = ((k==0 || k==96) ? 1.f : 2.f) / 36864.f;
      v = -sc*sinf(a*STEP);
    }
    ut[UT_MWI+idx] = f2bf(v);
    return;
  }
  idx -= 43008;
  if (idx < 49152){ // QKVW [384][128]
    int n = idx/128, k = idx%128;
    float v = (n < 128) ? q_w[(size_t)k*128 + n] : kv_w[(size_t)k*256 + (n-128)];
    ut[UT_QKVW+idx] = f2bf(v);
    return;
  }
  idx -= 49152;
  if (idx < 16384){ // PROJW [128][128]
    int n = idx/128, k = idx%128;
    ut[UT_PROJW+idx] = f2bf(proj_w[(size_t)k*128 + n]);
    return;
  }
  idx -= 16384;
  if (idx < 65536){ // FFT1W [256][256]
    int n = idx/256, k = idx%256;
    ut[UT_FFT1W+idx] = f2bf(fft1_w[(size_t)k*256 + n]);
    return;
  }
  idx -= 65536;
  if (idx < 65536){ // FFT2W [256][256]
    int n = idx/256, k = idx%256;
    ut[UT_FFT2W+idx] = f2bf(fft2_w[(size_t)k*256 + n]);
    return;
  }
  idx -= 65536;
  if (idx < 65536){ // L1W [512][128]
    int n = idx/128, k = idx%128;
    ut[UT_L1W+idx] = f2bf(l1_w[(size_t)k*512 + n]);
    return;
  }
  idx -= 65536;
  if (idx < 65536){ // L2W [128][512]
    int n = idx/512, k = idx%512;
    ut[UT_L2W+idx] = f2bf(l2_w[(size_t)k*128 + n]);
  }
}

// ---------------- pos depthwise conv: 8h x 32w x 16c ----------------
__global__ __launch_bounds__(256) void posconv3_kernel(const float* __restrict__ x, const float* __restrict__ pw,
                               const float* __restrict__ pb, float* __restrict__ xt){
  __shared__ float rows_s[16*340];
  int w0 = blockIdx.x*32, h0 = blockIdx.y*8;
  int b = blockIdx.z >> 3, cb = (blockIdx.z & 7)*16;
  int tid = threadIdx.x;
  int hl = tid >> 5, wl = tid & 31;
  for (int e = tid; e < 16*340; e += 256){
    int c = e / 340; int rem = e - c*340;
    int r = rem / 34; int wc = rem - r*34;
    int gh = h0 - 1 + r, gw = w0 - 1 + wc;
    float v = 0.f;
    if (gh >= 0 && gh < HGT && gw >= 0 && gw < WID)
      v = x[((size_t)(b*C_DIM + cb + c))*(HGT*WID) + gh*WID + gw];
    rows_s[e] = v;
  }
  __syncthreads();
  float outr[16];
  #pragma unroll
  for (int c = 0; c < 16; ++c){
    const float* rs = &rows_s[c*340];
    float wreg[9];
    #pragma unroll
    for (int t9 = 0; t9 < 9; ++t9) wreg[t9] = pw[(cb+c)*27 + 9 + t9];
    float bias = pb[cb+c];
    float acc = rs[(hl+1)*34 + wl+1] + bias;
    #pragma unroll
    for (int ky = 0; ky < 3; ++ky)
      #pragma unroll
      for (int kx = 0; kx < 3; ++kx)
        acc += wreg[ky*3+kx]*rs[(hl+ky)*34 + wl+kx];
    outr[c] = acc;
  }
  __syncthreads();
  {
    int px = hl*32 + wl;
    #pragma unroll
    for (int c = 0; c < 16; ++c) rows_s[px*17 + c] = outr[c];
  }
  __syncthreads();
  for (int r = 0; r < 16; ++r){
    int e = r*256 + tid;
    int cl = e & 15, hw = e >> 4;
    int h = hw >> 5, w = hw & 31;
    xt[((size_t)(b*HGT + h0+h)*WID + (w0+w))*C_DIM + cb + cl] = rows_s[hw*17 + cl];
  }
}

// ---------------- LN row stats ----------------
__global__ __launch_bounds__(256) void ln_stats_kernel(const float* __restrict__ src, float* __restrict__ stats){
  int wave = threadIdx.x >> 6; int lane = threadIdx.x & 63;
  size_t p = (size_t)blockIdx.x*4 + wave;
  const float* s = src + p*C_DIM;
  float v0 = s[lane], v1 = s[lane+64];
  float sum = v0 + v1;
  #pragma unroll
  for (int o=1; o<64; o<<=1) sum += __shfl_xor(sum, o, 64);
  float m = sum * (1.0f/128.0f);
  float d0 = v0-m, d1 = v1-m;
  float vs = d0*d0 + d1*d1;
  #pragma unroll
  for (int o=1; o<64; o<<=1) vs += __shfl_xor(vs, o, 64);
  float rstd = rsqrtf(vs*(1.0f/128.0f) + 1e-5f);
  if (lane==0){ stats[2*p] = m; stats[2*p+1] = rstd; }
}

// ---------------- unified MFMA GEMM (64x64 tile, NT n-tiles) ----------------
template<int ACT, bool ADD, bool LNA, bool ABF, bool OBF, int NT>
__global__ __launch_bounds__(256) void gemm2(const void* __restrict__ A1v,
                            const unsigned short* __restrict__ WT, const float* __restrict__ bias,
                            void* __restrict__ dstv, int K, int N, int lda,
                            const float* __restrict__ stats, const float* __restrict__ lng,
                            const float* __restrict__ lnb, int prow0, int pmax){
  __shared__ __align__(16) unsigned short As[64*40];
  __shared__ __align__(16) unsigned short Bs[NT][64*40];
  int p0 = blockIdx.y*64, n00 = blockIdx.x*(64*NT);
  int tid = threadIdx.x;
  int wave = tid >> 6, lane = tid & 63;
  int wr = (wave>>1)*32, wc = (wave&1)*32;
  f32x4 acc[NT][4];
  #pragma unroll
  for (int nt=0; nt<NT; ++nt)
    #pragma unroll
    for (int q=0; q<4; ++q) acc[nt][q] = (f32x4){};
  int am = tid >> 2, ak = (tid & 3)*8;
  int brow = tid >> 2, bkk = (tid & 3)*8;
  for (int k0 = 0; k0 < K; k0 += 32){
    if constexpr (ABF){
      const unsigned short* A1u = (const unsigned short*)A1v;
      bf16x8 av = *(const bf16x8*)(A1u + (size_t)(p0+am)*lda + k0 + ak);
      st8u(&As[am*40 + ak], av);
    } else {
      int gp = p0 + am;
      float s0 = 0.f, s1 = 0.f;
      if (LNA){
        gp += prow0;
        gp = gp < 0 ? 0 : (gp > pmax ? pmax : gp);
        s0 = stats[2*gp]; s1 = stats[2*gp+1];
      }
      const float* src = (const float*)A1v + (size_t)gp*lda + k0 + ak;
      float4 aa = *(const float4*)src;
      float4 ab = *(const float4*)(src+4);
      float v[8] = {aa.x,aa.y,aa.z,aa.w,ab.x,ab.y,ab.z,ab.w};
      unsigned short* dp = &As[am*40 + ak];
      #pragma unroll
      for (int j=0;j<8;j++){
        float f = v[j];
        if (LNA) f = (f - s0)*s1*lng[k0+ak+j] + lnb[k0+ak+j];
        dp[j] = f2bf(f);
      }
    }
    #pragma unroll
    for (int nt=0; nt<NT; ++nt){
      bf16x8 wv = *(const bf16x8*)(WT + (size_t)(n00 + nt*64 + brow)*K + k0 + bkk);
      st8u(&Bs[nt][brow*40 + bkk], wv);
    }
    __syncthreads();
    int fm = lane & 15, kg = (lane>>4)*8;
    bf16x8 a0 = *(const bf16x8*)&As[(wr+fm)*40 + kg];
    bf16x8 a1 = *(const bf16x8*)&As[(wr+16+fm)*40 + kg];
    #pragma unroll
    for (int nt=0; nt<NT; ++nt){
      bf16x8 b0 = *(const bf16x8*)&Bs[nt][(wc+fm)*40 + kg];
      bf16x8 b1 = *(const bf16x8*)&Bs[nt][(wc+16+fm)*40 + kg];
      acc[nt][0] = __builtin_amdgcn_mfma_f32_16x16x32_bf16(a0, b0, acc[nt][0], 0,0,0);
      acc[nt][1] = __builtin_amdgcn_mfma_f32_16x16x32_bf16(a0, b1, acc[nt][1], 0,0,0);
      acc[nt][2] = __builtin_amdgcn_mfma_f32_16x16x32_bf16(a1, b0, acc[nt][2], 0,0,0);
      acc[nt][3] = __builtin_amdgcn_mfma_f32_16x16x32_bf16(a1, b1, acc[nt][3], 0,0,0);
    }
    __syncthreads();
  }
  int cn = lane & 15, rq = (lane>>4)*4;
  #pragma unroll
  for (int nt=0; nt<NT; ++nt){
    #pragma unroll
    for (int mi=0; mi<2; ++mi){
      #pragma unroll
      for (int ni=0; ni<2; ++ni){
        f32x4 a = acc[nt][mi*2+ni];
        int n = n00 + nt*64 + wc + ni*16 + cn;
        float bsv = bias[n];
        #pragma unroll
        for (int r=0; r<4; ++r){
          size_t row = (size_t)p0 + wr + mi*16 + rq + r;
          float v = a[r] + bsv;
          if (ACT==1) v = (v>=0.f) ? v : 0.01f*v;
          if (ACT==2) v = gelu_f(v);
          if constexpr (OBF){
            ((unsigned short*)dstv)[row*(size_t)N + n] = f2bf(v);
          } else {
            float* dst = (float*)dstv;
            if (ADD) v += dst[row*(size_t)N + n];
            dst[row*(size_t)N + n] = v;
          }
        }
      }
    }
  }
}

// ---------------- DFT-as-GEMM (bf16 tables / bf16 spectra) ----------------
template<int MODE>
__global__ __launch_bounds__(256) void dft_gemm(const unsigned short* __restrict__ Atab,
                            const void* __restrict__ W1v, const void* __restrict__ W2v,
                            void* __restrict__ D1v, void* __restrict__ D2v, int k0){
  constexpr int K      = (MODE==0)?192 : (MODE==3)?224 : 384;
  constexpr int MT     = (MODE==0)?4 : (MODE==3)?3 : 6;
  constexpr int MVALID = (MODE==0)?194 : (MODE==3)?192 : 384;
  __shared__ __align__(16) unsigned short As[64*40];
  __shared__ __align__(16) unsigned short Bs[64*40];
  int slab = blockIdx.y / MT;
  int p0 = (blockIdx.y % MT)*64, n0 = blockIdx.x*64;
  int tid = threadIdx.x;
  int wave = tid >> 6, lane = tid & 63;
  int wr = (wave>>1)*32, wc = (wave&1)*32;
  f32x4 acc00 = {}, acc01 = {}, acc10 = {}, acc11 = {};
  int am = tid >> 2, ak = (tid & 3)*8;
  int bk = tid >> 3, bn = (tid & 7)*8;
  for (int kk0 = 0; kk0 < K; kk0 += 32){
    {
      bf16x8 av = *(const bf16x8*)(Atab + (size_t)(p0+am)*K + kk0 + ak);
      st8u(&As[am*40 + ak], av);
    }
    {
      int r = kk0 + bk;
      if (MODE==0){
        const float* src = (const float*)W1v + (size_t)slab*24576 + (size_t)r*128 + n0 + bn;
        float4 wa = *(const float4*)src;
        float4 wb = *(const float4*)(src+4);
        float v[8] = {wa.x,wa.y,wa.z,wa.w,wb.x,wb.y,wb.z,wb.w};
        #pragma unroll
        for (int j=0;j<8;j++) Bs[(bn+j)*40 + bk] = f2bf(v[j]);
      } else {
        const unsigned short* src;
        if (MODE==1) src = (r<192) ? (const unsigned short*)W1v + (size_t)(k0+slab)*128 + (size_t)r*12416
                                   : (const unsigned short*)W2v + (size_t)(k0+slab)*128 + (size_t)(r-192)*12416;
        else if (MODE==2) src = (r<192) ? (const unsigned short*)W1v + (size_t)slab*49152 + (size_t)r*256
                                        : (const unsigned short*)W2v + (size_t)slab*49152 + (size_t)(r-192)*256;
        else src = (r<112) ? (const unsigned short*)W1v + (size_t)slab*24832 + (size_t)r*256
                           : (const unsigned short*)W2v + (size_t)slab*24832 + (size_t)(r-112)*256;
        src += n0 + bn;
        bf16x8 wv = *(const bf16x8*)src;
        #pragma unroll
        for (int j=0;j<8;j++) Bs[(bn+j)*40 + bk] = (unsigned short)wv[j];
      }
    }
    __syncthreads();
    int fm = lane & 15, kg = (lane>>4)*8;
    bf16x8 a0 = *(const bf16x8*)&As[(wr+fm)*40 + kg];
    bf16x8 a1 = *(const bf16x8*)&As[(wr+16+fm)*40 + kg];
    bf16x8 b0 = *(const bf16x8*)&Bs[(wc+fm)*40 + kg];
    bf16x8 b1 = *(const bf16x8*)&Bs[(wc+16+fm)*40 + kg];
    acc00 = __builtin_amdgcn_mfma_f32_16x16x32_bf16(a0, b0, acc00, 0,0,0);
    acc01 = __builtin_amdgcn_mfma_f32_16x16x32_bf16(a0, b1, acc01, 0,0,0);
    acc10 = __builtin_amdgcn_mfma_f32_16x16x32_bf16(a1, b0, acc10, 0,0,0);
    acc11 = __builtin_amdgcn_mfma_f32_16x16x32_bf16(a1, b1, acc11, 0,0,0);
    __syncthreads();
  }
  int cn = lane & 15, rq = (lane>>4)*4;
  #pragma unroll
  for (int mi=0; mi<2; ++mi){
    #pragma unroll
    for (int ni=0; ni<2; ++ni){
      f32x4 a = (mi==0) ? (ni==0?acc00:acc01) : (ni==0?acc10:acc11);
      int n = n0 + wc + ni*16 + cn;
      #pragma unroll
      for (int r=0; r<4; ++r){
        int p = p0 + wr + mi*16 + rq + r;
        if (p >= MVALID) continue;
        float v = a[r];
        if (MODE==0){
          unsigned short* D1 = (unsigned short*)D1v;
          unsigned short* D2 = (unsigned short*)D2v;
          if (p < 97) D1[(size_t)slab*12416 + (size_t)p*128 + n] = f2bf(v);
          else        D2[(size_t)slab*12416 + (size_t)(p-97)*128 + n] = f2bf(v);
        } else if (MODE==1){
          unsigned short* base = (unsigned short*)D1v + (size_t)slab*49152;
          if (p < 192) base[(size_t)p*256 + n] = f2bf(v);
          else         base[(size_t)(p-192)*256 + 128 + n] = f2bf(v);
        } else if (MODE==2){
          unsigned short* D1 = (unsigned short*)D1v;
          int kg2 = k0 + slab;
          if (p < 192) D1[((size_t)p*97 + kg2)*256 + n] = f2bf(v);
          else         D1[((size_t)(p-192)*97 + kg2)*256 + 128 + n] = f2bf(v);
        } else {
          ((float*)D1v)[(size_t)slab*24576 + (size_t)p*128 + n] += v;
        }
      }
    }
  }
}

// ---------------- fused attention: LN + QKV proj (MFMA) + window attn ----------------
#define XS_OFF  0                      // [64][136]
#define WQK_OFF 8704                   // + wave*5120 : Qw [64][40], Kw at +2560; P alias [64][72]
#define VT_OFF  29184                  // + wave*2304 : Vt [32][72]
#define SHM_TOT 38400
__global__ __launch_bounds__(256) void attn_fused2(
    const float* __restrict__ XT, const float* __restrict__ stats,
    const float* __restrict__ g1, const float* __restrict__ b1,
    const unsigned short* __restrict__ QKVW, const float* __restrict__ QKVB,
    const float* __restrict__ biasT, unsigned short* __restrict__ OUTc){
  __shared__ __align__(16) unsigned short shm[SHM_TOT];
  int win = blockIdx.x;
  int b = win/576, rem = win%576, whi = rem/12, wwi = rem%12;
  int tid = threadIdx.x, wave = tid>>6, lane = tid&63, head = wave;
  int fm = lane & 15, kg = (lane>>4)*8;
  size_t rowbase = (size_t)(b*HGT + whi*4)*WID + wwi*16;
  {
    int t = tid >> 2;
    int c0 = (tid & 3)*32;
    size_t grow = rowbase + (size_t)(t>>4)*WID + (t&15);
    const float* src = XT + grow*C_DIM + c0;
    float m = stats[2*grow], rs = stats[2*grow+1];
    unsigned short* dst = &shm[XS_OFF + t*136 + c0];
    #pragma unroll
    for (int j=0;j<32;j++){
      float f = (src[j]-m)*rs*g1[c0+j] + b1[c0+j];
      dst[j] = f2bf(f);
    }
  }
  __syncthreads();
  unsigned short* Qw = &shm[WQK_OFF + wave*5120];
  unsigned short* Kw = Qw + 2560;
  unsigned short* Vt = &shm[VT_OFF + wave*2304];
  #pragma unroll
  for (int op=0; op<3; ++op){
    f32x4 acc[4][2];
    #pragma unroll
    for (int tf=0; tf<4; ++tf){ acc[tf][0] = (f32x4){}; acc[tf][1] = (f32x4){}; }
    int wrow0 = op*128 + head*32;
    #pragma unroll
    for (int kk0=0; kk0<128; kk0+=32){
      bf16x8 bfr0 = *(const bf16x8*)(QKVW + (size_t)(wrow0 + fm)*128 + kk0 + kg);
      bf16x8 bfr1 = *(const bf16x8*)(QKVW + (size_t)(wrow0 + 16 + fm)*128 + kk0 + kg);
      #pragma unroll
      for (int tf=0; tf<4; ++tf){
        bf16x8 af = *(const bf16x8*)&shm[XS_OFF + (tf*16+fm)*136 + kk0 + kg];
        acc[tf][0] = __builtin_amdgcn_mfma_f32_16x16x32_bf16(af, bfr0, acc[tf][0], 0,0,0);
        acc[tf][1] = __builtin_amdgcn_mfma_f32_16x16x32_bf16(af, bfr1, acc[tf][1], 0,0,0);
      }
    }
    #pragma unroll
    for (int tf=0; tf<4; ++tf){
      #pragma unroll
      for (int cf=0; cf<2; ++cf){
        int n = cf*16 + fm;
        float bsv = QKVB[op*128 + head*32 + n];
        #pragma unroll
        for (int r=0;r<4;r++){
          int token = tf*16 + (lane>>4)*4 + r;
          float v = acc[tf][cf][r] + bsv;
          if (op==0) v *= 0.17677669529663688f;
          unsigned short bv = f2bf(v);
          if (op==0)      Qw[token*40 + n] = bv;
          else if (op==1) Kw[token*40 + n] = bv;
          else            Vt[n*72 + token] = bv;
        }
      }
    }
  }
  __syncthreads();
  bf16x8 qf[4], kf[4];
  #pragma unroll
  for (int t4=0; t4<4; ++t4){
    qf[t4] = *(const bf16x8*)&Qw[(t4*16+fm)*40 + kg];
    kf[t4] = *(const bf16x8*)&Kw[(t4*16+fm)*40 + kg];
  }
  f32x4 s[4][4];
  #pragma unroll
  for (int ni=0; ni<4; ++ni)
    #pragma unroll
    for (int mj=0; mj<4; ++mj){
      f32x4 z = {};
      s[ni][mj] = __builtin_amdgcn_mfma_f32_16x16x32_bf16(qf[ni], kf[mj], z, 0,0,0);
    }
  const float* bp = biasT + head*4096;
  #pragma unroll
  for (int ni=0; ni<4; ++ni){
    int nbase = ni*16 + (lane>>4)*4;
    #pragma unroll
    for (int mj=0; mj<4; ++mj){
      int m = mj*16 + fm;
      #pragma unroll
      for (int r=0;r<4;r++)
        s[ni][mj][r] += bp[(nbase+r)*64 + m];
    }
  }
  float rs_[4][4];
  #pragma unroll
  for (int ni=0; ni<4; ++ni){
    #pragma unroll
    for (int r=0;r<4;r++){
      float t = fmaxf(fmaxf(s[ni][0][r], s[ni][1][r]), fmaxf(s[ni][2][r], s[ni][3][r]));
      #pragma unroll
      for (int o=1;o<16;o<<=1) t = fmaxf(t, __shfl_xor(t, o, 64));
      float sum = 0.f;
      #pragma unroll
      for (int mj=0; mj<4; ++mj){
        float e = __expf(s[ni][mj][r] - t);
        s[ni][mj][r] = e;
        sum += e;
      }
      #pragma unroll
      for (int o=1;o<16;o<<=1) sum += __shfl_xor(sum, o, 64);
      rs_[ni][r] = sum;
    }
  }
  __syncthreads();
  unsigned short* Ps = Qw;
  #pragma unroll
  for (int ni=0; ni<4; ++ni){
    int nbase = ni*16 + (lane>>4)*4;
    #pragma unroll
    for (int mj=0; mj<4; ++mj){
      int m = mj*16 + fm;
      #pragma unroll
      for (int r=0;r<4;r++)
        Ps[(nbase+r)*72 + m] = f2bf(s[ni][mj][r]);
    }
  }
  f32x4 o2[4][2];
  #pragma unroll
  for (int ni=0; ni<4; ++ni){ o2[ni][0] = (f32x4){}; o2[ni][1] = (f32x4){}; }
  #pragma unroll
  for (int ks=0; ks<2; ++ks){
    bf16x8 vb0 = *(const bf16x8*)&Vt[fm*72 + ks*32+kg];
    bf16x8 vb1 = *(const bf16x8*)&Vt[(16+fm)*72 + ks*32+kg];
    #pragma unroll
    for (int ni=0; ni<4; ++ni){
      bf16x8 pa = *(const bf16x8*)&Ps[(ni*16+fm)*72 + ks*32+kg];
      o2[ni][0] = __builtin_amdgcn_mfma_f32_16x16x32_bf16(pa, vb0, o2[ni][0], 0,0,0);
      o2[ni][1] = __builtin_amdgcn_mfma_f32_16x16x32_bf16(pa, vb1, o2[ni][1], 0,0,0);
    }
  }
  #pragma unroll
  for (int ni=0; ni<4; ++ni){
    #pragma unroll
    for (int r=0;r<4;r++){
      size_t l = rowbase + (size_t)ni*WID + (lane>>4)*4 + r;
      float inv = 1.0f / rs_[ni][r];
      unsigned short* op = OUTc + l*C_DIM + head*32;
      op[fm]    = f2bf(o2[ni][0][r]*inv);
      op[16+fm] = f2bf(o2[ni][1][r]*inv);
    }
  }
}

// ---------------- LeFF dwconv strip v2: rolling window, weights in registers ----------------
__global__ __launch_bounds__(256) void dwconv_strip(const unsigned short* __restrict__ SB1,
                                                    const float* __restrict__ dw,
                                                    const float* __restrict__ db,
                                                    unsigned short* __restrict__ SB2,
                                                    int r0){
  int blk = blockIdx.x;
  int wt = blk % 12, hl = blk / 12;
  int tid = threadIdx.x;
  int c4 = tid & 127, ph = tid >> 7;
  int ch = c4*4;
  int w0 = wt*16 + ph*8;
  int h = r0 + hl;
  float wreg[9][4], bias[4];
  #pragma unroll
  for (int j=0;j<4;j++){
    bias[j] = db[ch+j];
    #pragma unroll
    for (int t9=0;t9<9;t9++) wreg[t9][j] = dw[(ch+j)*9+t9];
  }
  const unsigned short* rp[3];
  bool rv[3];
  #pragma unroll
  for (int ky=0;ky<3;ky++){
    int hh = h + ky - 1;
    rv[ky] = (hh >= 0) && (hh < HGT);
    rp[ky] = SB1 + ((size_t)(hl+ky)*WID)*512 + ch;
  }
  float win[3][3][4];
  #pragma unroll
  for (int ky=0;ky<3;ky++){
    #pragma unroll
    for (int j=0;j<4;j++){ win[ky][0][j]=0.f; win[ky][1][j]=0.f; }
    if (rv[ky]){
      if (w0 > 0){
        const unsigned int* p = (const unsigned int*)(rp[ky] + (size_t)(w0-1)*512);
        unsigned int u0=p[0], u1=p[1];
        win[ky][0][0]=bf2f((unsigned short)(u0&0xFFFF)); win[ky][0][1]=bf2f((unsigned short)(u0>>16));
        win[ky][0][2]=bf2f((unsigned short)(u1&0xFFFF)); win[ky][0][3]=bf2f((unsigned short)(u1>>16));
      }
      {
        const unsigned int* p = (const unsigned int*)(rp[ky] + (size_t)w0*512);
        unsigned int u0=p[0], u1=p[1];
        win[ky][1][0]=bf2f((unsigned short)(u0&0xFFFF)); win[ky][1][1]=bf2f((unsigned short)(u0>>16));
        win[ky][1][2]=bf2f((unsigned short)(u1&0xFFFF)); win[ky][1][3]=bf2f((unsigned short)(u1>>16));
      }
    }
  }
  #pragma unroll
  for (int px=0; px<8; ++px){
    int w = w0 + px;
    #pragma unroll
    for (int ky=0;ky<3;ky++){
      #pragma unroll
      for (int j=0;j<4;j++) win[ky][2][j]=0.f;
      if (rv[ky] && (w+1) < WID){
        const unsigned int* p = (const unsigned int*)(rp[ky] + (size_t)(w+1)*512);
        unsigned int u0=p[0], u1=p[1];
        win[ky][2][0]=bf2f((unsigned short)(u0&0xFFFF)); win[ky][2][1]=bf2f((unsigned short)(u0>>16));
        win[ky][2][2]=bf2f((unsigned short)(u1&0xFFFF)); win[ky][2][3]=bf2f((unsigned short)(u1>>16));
      }
    }
    float a[4];
    #pragma unroll
    for (int j=0;j<4;j++){
      float acc = bias[j];
      #pragma unroll
      for (int ky=0;ky<3;ky++)
        #pragma unroll
        for (int kx=0;kx<3;kx++)
          acc += wreg[ky*3+kx][j]*win[ky][kx][j];
      a[j] = gelu_f(acc);
    }
    unsigned int o0 = (unsigned int)f2bf(a[0]) | ((unsigned int)f2bf(a[1])<<16);
    unsigned int o1 = (unsigned int)f2bf(a[2]) | ((unsigned int)f2bf(a[3])<<16);
    unsigned int* op = (unsigned int*)&SB2[((size_t)hl*WID + w)*512 + ch];
    op[0] = o0; op[1] = o1;
    #pragma unroll
    for (int ky=0;ky<3;ky++)
      #pragma unroll
      for (int j=0;j<4;j++){ win[ky][0][j]=win[ky][1][j]; win[ky][1][j]=win[ky][2][j]; }
  }
}

// ---------------- per-batch BHWC -> BCHW transpose (z = batch, stride param) ----------------
__global__ __launch_bounds__(256) void transpose_b_kernel(const float* __restrict__ src, float* __restrict__ dst,
                                                          size_t zstride){
  __shared__ float tile[128*65];
  int w0 = blockIdx.x*64, h = blockIdx.y;
  size_t zo = (size_t)blockIdx.z * zstride;
  int tid = threadIdx.x;
  for (int r=0; r<32; r++){
    int e = tid + 256*r; int c = e & 127, wl = e >> 7;
    tile[c*65 + wl] = src[zo + ((size_t)h*WID + w0 + wl)*C_DIM + c];
  }
  __syncthreads();
  for (int r=0; r<32; r++){
    int e = tid + 256*r; int wl = e & 63, c = e >> 6;
    dst[zo + ((size_t)c*HGT + h)*WID + w0 + wl] = tile[c*65 + wl];
  }
}

// ---------------- host ----------------
extern "C" void kernel_launch(void* const* d_in, const int* in_sizes, int n_in,
                              void* d_out, int out_size, void* d_ws, size_t ws_size,
                              hipStream_t stream) {
  const float* x      = (const float*)d_in[0];
  const float* pos_w  = (const float*)d_in[1];
  const float* pos_b  = (const float*)d_in[2];
  const float* ln1_g  = (const float*)d_in[3];
  const float* ln1_b  = (const float*)d_in[4];
  const float* q_w    = (const float*)d_in[5];
  const float* q_b    = (const float*)d_in[6];
  const float* kv_w   = (const float*)d_in[7];
  const float* kv_b   = (const float*)d_in[8];
  const float* rpb    = (const float*)d_in[9];
  const float* proj_w = (const float*)d_in[10];
  const float* proj_b = (const float*)d_in[11];
  const float* fft1_w = (const float*)d_in[12];
  const float* fft1_b = (const float*)d_in[13];
  const float* fft2_w = (const float*)d_in[14];
  const float* fft2_b = (const float*)d_in[15];
  const float* ln2_g  = (const float*)d_in[16];
  const float* ln2_b  = (const float*)d_in[17];
  const float* l1_w   = (const float*)d_in[18];
  const float* l1_b   = (const float*)d_in[19];
  const float* dw_w   = (const float*)d_in[20];
  const float* dw_b   = (const float*)d_in[21];
  const float* l2_w   = (const float*)d_in[22];
  const float* l2_b   = (const float*)d_in[23];

  const size_t S   = (size_t)NB*HGT*WID*C_DIM;   // 18,874,368
  const size_t Sb  = S/NB;                       //  4,718,592
  const size_t SZb = (size_t)HGT*WFD*C_DIM;      //  2,383,872 (u16 per spectrum half)
  const size_t GSZ = (size_t)HGT*WFD*256;        //  4,767,744 (u16)
  const int    P   = (int)(NB*HGT*WID);          // 147,456

  float* ws    = (float*)d_ws;
  float* TAB   = ws;
  float* STATS = ws + TAB_SZ;
  float* POOL  = ws + TAB_SZ + 2*(size_t)P;
  size_t head  = TAB_SZ + 2*(size_t)P;
  size_t pool  = (ws_size/4 > head) ? (ws_size/4 - head) : 0;

  bool xt_in_pool = (pool >= S + 11000000);
  float* XT     = xt_in_pool ? POOL : (float*)d_out;
  float* POOL2  = xt_in_pool ? POOL + S : POOL;
  size_t pool2  = xt_in_pool ? pool - S : pool;

  const float* biasT = TAB + T_BIAS;
  const float* QKVB  = TAB + T_QKVB;
  const unsigned short* UT = (const unsigned short*)(TAB + TF_SZ);
  const unsigned short* MW  = UT + UT_MW;
  const unsigned short* MHF = UT + UT_MHF;
  const unsigned short* MHI = UT + UT_MHI;
  const unsigned short* MWI = UT + UT_MWI;
  const unsigned short* QKVW  = UT + UT_QKVW;
  const unsigned short* PROJW = UT + UT_PROJW;
  const unsigned short* FFT1W = UT + UT_FFT1W;
  const unsigned short* FFT2W = UT + UT_FFT2W;
  const unsigned short* L1W   = UT + UT_L1W;
  const unsigned short* L2W   = UT + UT_L2W;

  build_tables<<<2858, 256, 0, stream>>>(TAB, rpb, q_b, kv_b, q_w, kv_w, proj_w,
                                         fft1_w, fft2_w, l1_w, l2_w);
  posconv3_kernel<<<dim3(6,24,32), 256, 0, stream>>>(x, pos_w, pos_b, XT);

  // ---- attention: LN1 stats -> fused(LN+QKV+attn) -> proj (gemm2 NT=2, 2304 blocks) ----
  ln_stats_kernel<<<P/4, 256, 0, stream>>>(XT, STATS);
  {
    unsigned short* OUTu = (unsigned short*)POOL2;
    attn_fused2<<<2304, 256, 0, stream>>>(XT, STATS, ln1_g, ln1_b, QKVW, QKVB, biasT, OUTu);
    gemm2<0,true,false,true,false,2><<<dim3(1, P/64), 256, 0, stream>>>(
        OUTu, PROJW, proj_b, XT, 128, 128, 128, nullptr, nullptr, nullptr, 0, 0);
  }

  // ---- FFT residual branch: all-MFMA, bf16 spectra, balanced k-chunks; mixes = gemm2 NT=1 ----
  {
    unsigned short* FRu = (unsigned short*)POOL2;
    unsigned short* FIu = FRu + SZb;
    unsigned short* Gu  = FIu + SZb;
    size_t fixed = SZb + GSZ/2;                  // floats used by FR+FI+G
    int CKmax = 1;
    if (pool2 > fixed + 49152) CKmax = (int)((pool2 - fixed)/49152);
    if (CKmax < 1) CKmax = 1;
    if (CKmax > WFD) CKmax = WFD;
    int nch = (WFD + CKmax - 1)/CKmax;
    int CK = (WFD + nch - 1)/nch;
    unsigned short* FF0u = (unsigned short*)(POOL2 + fixed);
    unsigned short* FF1u = FF0u + (size_t)CK*49152;
    for (int b = 0; b < NB; ++b){
      float* XTb = XT + (size_t)b*Sb;
      dft_gemm<0><<<dim3(2, 192*4), 256, 0, stream>>>(MW, XTb, nullptr, FRu, FIu, 0);
      for (int k0 = 0; k0 < WFD; k0 += CK){
        int ck = (WFD - k0 < CK) ? (WFD - k0) : CK;
        int rows = ck*192;
        dft_gemm<1><<<dim3(2, ck*6), 256, 0, stream>>>(MHF, FRu, FIu, FF0u, nullptr, k0);
        gemm2<1,false,false,true,true,1><<<dim3(4, rows/64), 256, 0, stream>>>(
            FF0u, FFT1W, fft1_b, FF1u, 256, 256, 256, nullptr, nullptr, nullptr, 0, 0);
        gemm2<0,false,false,true,true,1><<<dim3(4, rows/64), 256, 0, stream>>>(
            FF1u, FFT2W, fft2_b, FF0u, 256, 256, 256, nullptr, nullptr, nullptr, 0, 0);
        dft_gemm<2><<<dim3(2, ck*6), 256, 0, stream>>>(MHI, FF0u, FF0u+128, Gu, nullptr, k0);
      }
      dft_gemm<3><<<dim3(2, 192*3), 256, 0, stream>>>(MWI, Gu, Gu+128, XTb, nullptr, 0);
    }
  }

  // ---- LN2 stats ----
  ln_stats_kernel<<<P/4, 256, 0, stream>>>(XT, STATS);

  // ---- LeFF: strip-mined l1 (gemm2 NT=2, 1176 blocks) -> dwconv -> l2 (gemm2 NT=1, 576 blocks) ----
  {
    int SH = 96;
    while ((size_t)(3*SH+4)*49152 > pool2 && SH > 24) SH >>= 1;
    const size_t SB1SZ = (size_t)(SH+2)*98304;   // u16
    unsigned short* SB1u[2] = { (unsigned short*)POOL2, (unsigned short*)POOL2 + SB1SZ };
    unsigned short* SB2u = (unsigned short*)POOL2 + 2*SB1SZ;
    int nStrips = HGT/SH;
    for (int b = 0; b < NB; ++b){
      auto launch_g = [&](int s){
        int r0 = s*SH;
        int prow0 = (b*HGT + r0 - 1)*WID;
        gemm2<2,false,true,false,true,2><<<dim3(4, (SH+2)*3), 256, 0, stream>>>(
            XT, L1W, l1_b, SB1u[s&1], 128, 512, 128,
            STATS, ln2_g, ln2_b, prow0, P-1);
      };
      launch_g(0);
      for (int s = 0; s < nStrips; ++s){
        if (s+1 < nStrips) launch_g(s+1);
        int r0 = s*SH;
        dwconv_strip<<<12*SH, 256, 0, stream>>>(SB1u[s&1], dw_w, dw_b, SB2u, r0);
        gemm2<0,true,false,true,false,1><<<dim3(2, SH*3), 256, 0, stream>>>(
            SB2u, L2W, l2_b, XT + ((size_t)(b*HGT + r0)*WID)*C_DIM,
            512, 128, 512, nullptr, nullptr, nullptr, 0, 0);
      }
    }
  }

  // ---- final transpose ----
  if (xt_in_pool){
    transpose_b_kernel<<<dim3(3,192,4), 256, 0, stream>>>(XT, (float*)d_out, Sb);
  } else {
    for (int b = 0; b < NB; ++b){
      transpose_b_kernel<<<dim3(3,192,1), 256, 0, stream>>>(XT + (size_t)b*Sb, POOL2, 0);
      hipMemcpyAsync((float*)d_out + (size_t)b*Sb, POOL2, Sb*sizeof(float),
                     hipMemcpyDeviceToDevice, stream);
    }
  }
}

// Round 18
// 1153.488 us; speedup vs baseline: 1.2175x; 1.0261x over previous
//
#include <hip/hip_runtime.h>
#include <hip/hip_bf16.h>
#include <math.h>

// ---------------- constants ----------------
#define C_DIM 128
#define HGT 192
#define WID 192
#define NB 4
#define WFD 97   // 192/2+1

// TAB float region
#define T_BIAS  0                // 4*64*64 fp32
#define T_QKVB  16384            // 384 fp32 (q_b | kv_b)
#define TF_SZ   16896
// TAB bf16 region (ushort offsets, base = TAB + TF_SZ floats)
#define UT_MW    0               // [256][192]
#define UT_MHF   49152           // [384][384]
#define UT_MHI   196608          // [384][384]
#define UT_MWI   344064          // [192][224]
#define UT_QKVW  387072          // [384][128]
#define UT_PROJW 436224          // [128][128]
#define UT_FFT1W 452608          // [256][256]
#define UT_FFT2W 518144          // [256][256]
#define UT_L1W   583680          // [512][128]
#define UT_L2W   649216          // [128][512]
#define UT_TOT   714752
#define TAB_SZ   374272          // floats: TF_SZ + UT_TOT/2

typedef __attribute__((ext_vector_type(8))) short bf16x8;
typedef __attribute__((ext_vector_type(4))) float f32x4;

__device__ __forceinline__ float gelu_f(float v){
  return 0.5f*v*(1.0f + erff(v*0.70710678118654752440f));
}
__device__ __forceinline__ unsigned short f2bf(float f){
  __hip_bfloat16 h = __float2bfloat16(f);
  return *reinterpret_cast<unsigned short*>(&h);
}
__device__ __forceinline__ float bf2f(unsigned short u){
  unsigned int x = ((unsigned int)u)<<16;
  return __uint_as_float(x);
}
__device__ __forceinline__ void st8u(unsigned short* d, bf16x8 v){
  unsigned int* wp = (unsigned int*)&v;
  unsigned int* dp = (unsigned int*)d;
  dp[0]=wp[0]; dp[1]=wp[1]; dp[2]=wp[2]; dp[3]=wp[3];
}

// ---------------- table build (exact int mod-192 + float trig) ----------------
__global__ __launch_bounds__(256) void build_tables(float* __restrict__ tab,
        const float* __restrict__ rpb, const float* __restrict__ q_b, const float* __restrict__ kv_b,
        const float* __restrict__ q_w, const float* __restrict__ kv_w, const float* __restrict__ proj_w,
        const float* __restrict__ fft1_w, const float* __restrict__ fft2_w,
        const float* __restrict__ l1_w, const float* __restrict__ l2_w){
  int idx = blockIdx.x*256 + threadIdx.x;
  const float STEP = (float)(6.283185307179586476925286766559/192.0);
  if (idx < 16384){ // attn bias fp32: [head][n][m]
    int head = idx>>12, n = (idx>>6)&63, m = idx&63;
    int dh = n/16 - m/16 + 3;
    int dw = (n&15) - (m&15) + 15;
    tab[T_BIAS+idx] = rpb[(dh*31+dw)*4 + head];
    return;
  }
  idx -= 16384;
  if (idx < 384){ // QKV bias concat fp32
    tab[T_QKVB+idx] = (idx < 128) ? q_b[idx] : kv_b[idx-128];
    return;
  }
  idx -= 384;
  unsigned short* ut = (unsigned short*)(tab + TF_SZ);
  if (idx < 49152){ // MW [256][192]
    int r = idx/192, w = idx%192;
    float v = 0.f;
    if (r < 97){ int a = (r*w)%192; v = cosf(a*STEP); }
    else if (r < 194){ int a = ((r-97)*w)%192; v = -sinf(a*STEP); }
    ut[UT_MW+idx] = f2bf(v);
    return;
  }
  idx -= 49152;
  if (idx < 147456){ // MHF [384][384]
    int r = idx/384, j = idx%384;
    int hf = (r < 192) ? r : r-192;
    int h  = (j < 192) ? j : j-192;
    int a = (hf*h)%192;
    float c = cosf(a*STEP), s = sinf(a*STEP);
    float v;
    if (r < 192) v = (j < 192) ? c : s;
    else         v = (j < 192) ? -s : c;
    ut[UT_MHF+idx] = f2bf(v);
    return;
  }
  idx -= 147456;
  if (idx < 147456){ // MHI [384][384]
    int r = idx/384, j = idx%384;
    int h  = (r < 192) ? r : r-192;
    int hf = (j < 192) ? j : j-192;
    int a = (h*hf)%192;
    float c = cosf(a*STEP), s = sinf(a*STEP);
    float v;
    if (r < 192) v = (j < 192) ? c : -s;
    else         v = (j < 192) ? s : c;
    ut[UT_MHI+idx] = f2bf(v);
    return;
  }
  idx -= 147456;
  if (idx < 43008){ // MWI [192][224]
    int w = idx/224, j = idx%224;
    float v = 0.f;
    if (j < 97){
      int a = (j*w)%192;
      float sc = ((j==0 || j==96) ? 1.f : 2.f) / 36864.f;
      v = sc*cosf(a*STEP);
    } else if (j >= 112 && j < 209){
      int k = j-112;
      int a = (k*w)%192;
      float sc = ((k==0 || k==96) ? 1.f : 2.f) / 36864.f;
      v = -sc*sinf(a*STEP);
    }
    ut[UT_MWI+idx] = f2bf(v);
    return;
  }
  idx -= 43008;
  if (idx < 49152){ // QKVW [384][128]
    int n = idx/128, k = idx%128;
    float v = (n < 128) ? q_w[(size_t)k*128 + n] : kv_w[(size_t)k*256 + (n-128)];
    ut[UT_QKVW+idx] = f2bf(v);
    return;
  }
  idx -= 49152;
  if (idx < 16384){ // PROJW [128][128]
    int n = idx/128, k = idx%128;
    ut[UT_PROJW+idx] = f2bf(proj_w[(size_t)k*128 + n]);
    return;
  }
  idx -= 16384;
  if (idx < 65536){ // FFT1W [256][256]
    int n = idx/256, k = idx%256;
    ut[UT_FFT1W+idx] = f2bf(fft1_w[(size_t)k*256 + n]);
    return;
  }
  idx -= 65536;
  if (idx < 65536){ // FFT2W [256][256]
    int n = idx/256, k = idx%256;
    ut[UT_FFT2W+idx] = f2bf(fft2_w[(size_t)k*256 + n]);
    return;
  }
  idx -= 65536;
  if (idx < 65536){ // L1W [512][128]
    int n = idx/128, k = idx%128;
    ut[UT_L1W+idx] = f2bf(l1_w[(size_t)k*512 + n]);
    return;
  }
  idx -= 65536;
  if (idx < 65536){ // L2W [128][512]
    int n = idx/512, k = idx%512;
    ut[UT_L2W+idx] = f2bf(l2_w[(size_t)k*128 + n]);
  }
}

// ---------------- pos depthwise conv: 8h x 32w x 16c ----------------
__global__ __launch_bounds__(256) void posconv3_kernel(const float* __restrict__ x, const float* __restrict__ pw,
                               const float* __restrict__ pb, float* __restrict__ xt){
  __shared__ float rows_s[16*340];
  int w0 = blockIdx.x*32, h0 = blockIdx.y*8;
  int b = blockIdx.z >> 3, cb = (blockIdx.z & 7)*16;
  int tid = threadIdx.x;
  int hl = tid >> 5, wl = tid & 31;
  for (int e = tid; e < 16*340; e += 256){
    int c = e / 340; int rem = e - c*340;
    int r = rem / 34; int wc = rem - r*34;
    int gh = h0 - 1 + r, gw = w0 - 1 + wc;
    float v = 0.f;
    if (gh >= 0 && gh < HGT && gw >= 0 && gw < WID)
      v = x[((size_t)(b*C_DIM + cb + c))*(HGT*WID) + gh*WID + gw];
    rows_s[e] = v;
  }
  __syncthreads();
  float outr[16];
  #pragma unroll
  for (int c = 0; c < 16; ++c){
    const float* rs = &rows_s[c*340];
    float wreg[9];
    #pragma unroll
    for (int t9 = 0; t9 < 9; ++t9) wreg[t9] = pw[(cb+c)*27 + 9 + t9];
    float bias = pb[cb+c];
    float acc = rs[(hl+1)*34 + wl+1] + bias;
    #pragma unroll
    for (int ky = 0; ky < 3; ++ky)
      #pragma unroll
      for (int kx = 0; kx < 3; ++kx)
        acc += wreg[ky*3+kx]*rs[(hl+ky)*34 + wl+kx];
    outr[c] = acc;
  }
  __syncthreads();
  {
    int px = hl*32 + wl;
    #pragma unroll
    for (int c = 0; c < 16; ++c) rows_s[px*17 + c] = outr[c];
  }
  __syncthreads();
  for (int r = 0; r < 16; ++r){
    int e = r*256 + tid;
    int cl = e & 15, hw = e >> 4;
    int h = hw >> 5, w = hw & 31;
    xt[((size_t)(b*HGT + h0+h)*WID + (w0+w))*C_DIM + cb + cl] = rows_s[hw*17 + cl];
  }
}

// ---------------- LN row stats ----------------
__global__ __launch_bounds__(256) void ln_stats_kernel(const float* __restrict__ src, float* __restrict__ stats){
  int wave = threadIdx.x >> 6; int lane = threadIdx.x & 63;
  size_t p = (size_t)blockIdx.x*4 + wave;
  const float* s = src + p*C_DIM;
  float v0 = s[lane], v1 = s[lane+64];
  float sum = v0 + v1;
  #pragma unroll
  for (int o=1; o<64; o<<=1) sum += __shfl_xor(sum, o, 64);
  float m = sum * (1.0f/128.0f);
  float d0 = v0-m, d1 = v1-m;
  float vs = d0*d0 + d1*d1;
  #pragma unroll
  for (int o=1; o<64; o<<=1) vs += __shfl_xor(vs, o, 64);
  float rstd = rsqrtf(vs*(1.0f/128.0f) + 1e-5f);
  if (lane==0){ stats[2*p] = m; stats[2*p+1] = rstd; }
}

// ---------------- unified MFMA GEMM (64x64 tile, NT n-tiles) ----------------
template<int ACT, bool ADD, bool LNA, bool ABF, bool OBF, int NT>
__global__ __launch_bounds__(256) void gemm2(const void* __restrict__ A1v,
                            const unsigned short* __restrict__ WT, const float* __restrict__ bias,
                            void* __restrict__ dstv, int K, int N, int lda,
                            const float* __restrict__ stats, const float* __restrict__ lng,
                            const float* __restrict__ lnb, int prow0, int pmax){
  __shared__ __align__(16) unsigned short As[64*40];
  __shared__ __align__(16) unsigned short Bs[NT][64*40];
  int p0 = blockIdx.y*64, n00 = blockIdx.x*(64*NT);
  int tid = threadIdx.x;
  int wave = tid >> 6, lane = tid & 63;
  int wr = (wave>>1)*32, wc = (wave&1)*32;
  f32x4 acc[NT][4];
  #pragma unroll
  for (int nt=0; nt<NT; ++nt)
    #pragma unroll
    for (int q=0; q<4; ++q) acc[nt][q] = (f32x4){};
  int am = tid >> 2, ak = (tid & 3)*8;
  int brow = tid >> 2, bkk = (tid & 3)*8;
  for (int k0 = 0; k0 < K; k0 += 32){
    if constexpr (ABF){
      const unsigned short* A1u = (const unsigned short*)A1v;
      bf16x8 av = *(const bf16x8*)(A1u + (size_t)(p0+am)*lda + k0 + ak);
      st8u(&As[am*40 + ak], av);
    } else {
      int gp = p0 + am;
      float s0 = 0.f, s1 = 0.f;
      if (LNA){
        gp += prow0;
        gp = gp < 0 ? 0 : (gp > pmax ? pmax : gp);
        s0 = stats[2*gp]; s1 = stats[2*gp+1];
      }
      const float* src = (const float*)A1v + (size_t)gp*lda + k0 + ak;
      float4 aa = *(const float4*)src;
      float4 ab = *(const float4*)(src+4);
      float v[8] = {aa.x,aa.y,aa.z,aa.w,ab.x,ab.y,ab.z,ab.w};
      unsigned short* dp = &As[am*40 + ak];
      #pragma unroll
      for (int j=0;j<8;j++){
        float f = v[j];
        if (LNA) f = (f - s0)*s1*lng[k0+ak+j] + lnb[k0+ak+j];
        dp[j] = f2bf(f);
      }
    }
    #pragma unroll
    for (int nt=0; nt<NT; ++nt){
      bf16x8 wv = *(const bf16x8*)(WT + (size_t)(n00 + nt*64 + brow)*K + k0 + bkk);
      st8u(&Bs[nt][brow*40 + bkk], wv);
    }
    __syncthreads();
    int fm = lane & 15, kg = (lane>>4)*8;
    bf16x8 a0 = *(const bf16x8*)&As[(wr+fm)*40 + kg];
    bf16x8 a1 = *(const bf16x8*)&As[(wr+16+fm)*40 + kg];
    #pragma unroll
    for (int nt=0; nt<NT; ++nt){
      bf16x8 b0 = *(const bf16x8*)&Bs[nt][(wc+fm)*40 + kg];
      bf16x8 b1 = *(const bf16x8*)&Bs[nt][(wc+16+fm)*40 + kg];
      acc[nt][0] = __builtin_amdgcn_mfma_f32_16x16x32_bf16(a0, b0, acc[nt][0], 0,0,0);
      acc[nt][1] = __builtin_amdgcn_mfma_f32_16x16x32_bf16(a0, b1, acc[nt][1], 0,0,0);
      acc[nt][2] = __builtin_amdgcn_mfma_f32_16x16x32_bf16(a1, b0, acc[nt][2], 0,0,0);
      acc[nt][3] = __builtin_amdgcn_mfma_f32_16x16x32_bf16(a1, b1, acc[nt][3], 0,0,0);
    }
    __syncthreads();
  }
  int cn = lane & 15, rq = (lane>>4)*4;
  #pragma unroll
  for (int nt=0; nt<NT; ++nt){
    #pragma unroll
    for (int mi=0; mi<2; ++mi){
      #pragma unroll
      for (int ni=0; ni<2; ++ni){
        f32x4 a = acc[nt][mi*2+ni];
        int n = n00 + nt*64 + wc + ni*16 + cn;
        float bsv = bias[n];
        #pragma unroll
        for (int r=0; r<4; ++r){
          size_t row = (size_t)p0 + wr + mi*16 + rq + r;
          float v = a[r] + bsv;
          if (ACT==1) v = (v>=0.f) ? v : 0.01f*v;
          if (ACT==2) v = gelu_f(v);
          if constexpr (OBF){
            ((unsigned short*)dstv)[row*(size_t)N + n] = f2bf(v);
          } else {
            float* dst = (float*)dstv;
            if (ADD) v += dst[row*(size_t)N + n];
            dst[row*(size_t)N + n] = v;
          }
        }
      }
    }
  }
}

// ---------------- DFT-as-GEMM (bf16 tables / bf16 spectra) ----------------
template<int MODE>
__global__ __launch_bounds__(256) void dft_gemm(const unsigned short* __restrict__ Atab,
                            const void* __restrict__ W1v, const void* __restrict__ W2v,
                            void* __restrict__ D1v, void* __restrict__ D2v, int k0){
  constexpr int K      = (MODE==0)?192 : (MODE==3)?224 : 384;
  constexpr int MT     = (MODE==0)?4 : (MODE==3)?3 : 6;
  constexpr int MVALID = (MODE==0)?194 : (MODE==3)?192 : 384;
  __shared__ __align__(16) unsigned short As[64*40];
  __shared__ __align__(16) unsigned short Bs[64*40];
  int slab = blockIdx.y / MT;
  int p0 = (blockIdx.y % MT)*64, n0 = blockIdx.x*64;
  int tid = threadIdx.x;
  int wave = tid >> 6, lane = tid & 63;
  int wr = (wave>>1)*32, wc = (wave&1)*32;
  f32x4 acc00 = {}, acc01 = {}, acc10 = {}, acc11 = {};
  int am = tid >> 2, ak = (tid & 3)*8;
  int bk = tid >> 3, bn = (tid & 7)*8;
  for (int kk0 = 0; kk0 < K; kk0 += 32){
    {
      bf16x8 av = *(const bf16x8*)(Atab + (size_t)(p0+am)*K + kk0 + ak);
      st8u(&As[am*40 + ak], av);
    }
    {
      int r = kk0 + bk;
      if (MODE==0){
        const float* src = (const float*)W1v + (size_t)slab*24576 + (size_t)r*128 + n0 + bn;
        float4 wa = *(const float4*)src;
        float4 wb = *(const float4*)(src+4);
        float v[8] = {wa.x,wa.y,wa.z,wa.w,wb.x,wb.y,wb.z,wb.w};
        #pragma unroll
        for (int j=0;j<8;j++) Bs[(bn+j)*40 + bk] = f2bf(v[j]);
      } else {
        const unsigned short* src;
        if (MODE==1) src = (r<192) ? (const unsigned short*)W1v + (size_t)(k0+slab)*128 + (size_t)r*12416
                                   : (const unsigned short*)W2v + (size_t)(k0+slab)*128 + (size_t)(r-192)*12416;
        else if (MODE==2) src = (r<192) ? (const unsigned short*)W1v + (size_t)slab*49152 + (size_t)r*256
                                        : (const unsigned short*)W2v + (size_t)slab*49152 + (size_t)(r-192)*256;
        else src = (r<112) ? (const unsigned short*)W1v + (size_t)slab*24832 + (size_t)r*256
                           : (const unsigned short*)W2v + (size_t)slab*24832 + (size_t)(r-112)*256;
        src += n0 + bn;
        bf16x8 wv = *(const bf16x8*)src;
        #pragma unroll
        for (int j=0;j<8;j++) Bs[(bn+j)*40 + bk] = (unsigned short)wv[j];
      }
    }
    __syncthreads();
    int fm = lane & 15, kg = (lane>>4)*8;
    bf16x8 a0 = *(const bf16x8*)&As[(wr+fm)*40 + kg];
    bf16x8 a1 = *(const bf16x8*)&As[(wr+16+fm)*40 + kg];
    bf16x8 b0 = *(const bf16x8*)&Bs[(wc+fm)*40 + kg];
    bf16x8 b1 = *(const bf16x8*)&Bs[(wc+16+fm)*40 + kg];
    acc00 = __builtin_amdgcn_mfma_f32_16x16x32_bf16(a0, b0, acc00, 0,0,0);
    acc01 = __builtin_amdgcn_mfma_f32_16x16x32_bf16(a0, b1, acc01, 0,0,0);
    acc10 = __builtin_amdgcn_mfma_f32_16x16x32_bf16(a1, b0, acc10, 0,0,0);
    acc11 = __builtin_amdgcn_mfma_f32_16x16x32_bf16(a1, b1, acc11, 0,0,0);
    __syncthreads();
  }
  int cn = lane & 15, rq = (lane>>4)*4;
  #pragma unroll
  for (int mi=0; mi<2; ++mi){
    #pragma unroll
    for (int ni=0; ni<2; ++ni){
      f32x4 a = (mi==0) ? (ni==0?acc00:acc01) : (ni==0?acc10:acc11);
      int n = n0 + wc + ni*16 + cn;
      #pragma unroll
      for (int r=0; r<4; ++r){
        int p = p0 + wr + mi*16 + rq + r;
        if (p >= MVALID) continue;
        float v = a[r];
        if (MODE==0){
          unsigned short* D1 = (unsigned short*)D1v;
          unsigned short* D2 = (unsigned short*)D2v;
          if (p < 97) D1[(size_t)slab*12416 + (size_t)p*128 + n] = f2bf(v);
          else        D2[(size_t)slab*12416 + (size_t)(p-97)*128 + n] = f2bf(v);
        } else if (MODE==1){
          unsigned short* base = (unsigned short*)D1v + (size_t)slab*49152;
          if (p < 192) base[(size_t)p*256 + n] = f2bf(v);
          else         base[(size_t)(p-192)*256 + 128 + n] = f2bf(v);
        } else if (MODE==2){
          unsigned short* D1 = (unsigned short*)D1v;
          int kg2 = k0 + slab;
          if (p < 192) D1[((size_t)p*97 + kg2)*256 + n] = f2bf(v);
          else         D1[((size_t)(p-192)*97 + kg2)*256 + 128 + n] = f2bf(v);
        } else {
          ((float*)D1v)[(size_t)slab*24576 + (size_t)p*128 + n] += v;
        }
      }
    }
  }
}

// ---------------- fused attention: LN + QKV + window attn + proj (RMW XT) ----------------
#define XS_OFF  0                      // [64][136] ; O (bf16 [64][128]) aliases after PV
#define WQK_OFF 8704                   // + wave*5120 : Qw [64][40], Kw at +2560; P alias [64][72]
#define VT_OFF  29184                  // + wave*2304 : Vt [32][72]
#define SHM_TOT 38400
__global__ __launch_bounds__(256) void attn_fused3(
    float* __restrict__ XT, const float* __restrict__ stats,
    const float* __restrict__ g1, const float* __restrict__ b1,
    const unsigned short* __restrict__ QKVW, const float* __restrict__ QKVB,
    const float* __restrict__ biasT, const unsigned short* __restrict__ PROJW,
    const float* __restrict__ projb){
  __shared__ __align__(16) unsigned short shm[SHM_TOT];
  int win = blockIdx.x;
  int b = win/576, rem = win%576, whi = rem/12, wwi = rem%12;
  int tid = threadIdx.x, wave = tid>>6, lane = tid&63, head = wave;
  int fm = lane & 15, kg = (lane>>4)*8;
  size_t rowbase = (size_t)(b*HGT + whi*4)*WID + wwi*16;
  {
    int t = tid >> 2;
    int c0 = (tid & 3)*32;
    size_t grow = rowbase + (size_t)(t>>4)*WID + (t&15);
    const float* src = XT + grow*C_DIM + c0;
    float m = stats[2*grow], rs = stats[2*grow+1];
    unsigned short* dst = &shm[XS_OFF + t*136 + c0];
    #pragma unroll
    for (int j=0;j<32;j++){
      float f = (src[j]-m)*rs*g1[c0+j] + b1[c0+j];
      dst[j] = f2bf(f);
    }
  }
  __syncthreads();
  unsigned short* Qw = &shm[WQK_OFF + wave*5120];
  unsigned short* Kw = Qw + 2560;
  unsigned short* Vt = &shm[VT_OFF + wave*2304];
  #pragma unroll
  for (int op=0; op<3; ++op){
    f32x4 acc[4][2];
    #pragma unroll
    for (int tf=0; tf<4; ++tf){ acc[tf][0] = (f32x4){}; acc[tf][1] = (f32x4){}; }
    int wrow0 = op*128 + head*32;
    #pragma unroll
    for (int kk0=0; kk0<128; kk0+=32){
      bf16x8 bfr0 = *(const bf16x8*)(QKVW + (size_t)(wrow0 + fm)*128 + kk0 + kg);
      bf16x8 bfr1 = *(const bf16x8*)(QKVW + (size_t)(wrow0 + 16 + fm)*128 + kk0 + kg);
      #pragma unroll
      for (int tf=0; tf<4; ++tf){
        bf16x8 af = *(const bf16x8*)&shm[XS_OFF + (tf*16+fm)*136 + kk0 + kg];
        acc[tf][0] = __builtin_amdgcn_mfma_f32_16x16x32_bf16(af, bfr0, acc[tf][0], 0,0,0);
        acc[tf][1] = __builtin_amdgcn_mfma_f32_16x16x32_bf16(af, bfr1, acc[tf][1], 0,0,0);
      }
    }
    #pragma unroll
    for (int tf=0; tf<4; ++tf){
      #pragma unroll
      for (int cf=0; cf<2; ++cf){
        int n = cf*16 + fm;
        float bsv = QKVB[op*128 + head*32 + n];
        #pragma unroll
        for (int r=0;r<4;r++){
          int token = tf*16 + (lane>>4)*4 + r;
          float v = acc[tf][cf][r] + bsv;
          if (op==0) v *= 0.17677669529663688f;
          unsigned short bv = f2bf(v);
          if (op==0)      Qw[token*40 + n] = bv;
          else if (op==1) Kw[token*40 + n] = bv;
          else            Vt[n*72 + token] = bv;
        }
      }
    }
  }
  __syncthreads();
  bf16x8 qf[4], kf[4];
  #pragma unroll
  for (int t4=0; t4<4; ++t4){
    qf[t4] = *(const bf16x8*)&Qw[(t4*16+fm)*40 + kg];
    kf[t4] = *(const bf16x8*)&Kw[(t4*16+fm)*40 + kg];
  }
  f32x4 s[4][4];
  #pragma unroll
  for (int ni=0; ni<4; ++ni)
    #pragma unroll
    for (int mj=0; mj<4; ++mj){
      f32x4 z = {};
      s[ni][mj] = __builtin_amdgcn_mfma_f32_16x16x32_bf16(qf[ni], kf[mj], z, 0,0,0);
    }
  const float* bp = biasT + head*4096;
  #pragma unroll
  for (int ni=0; ni<4; ++ni){
    int nbase = ni*16 + (lane>>4)*4;
    #pragma unroll
    for (int mj=0; mj<4; ++mj){
      int m = mj*16 + fm;
      #pragma unroll
      for (int r=0;r<4;r++)
        s[ni][mj][r] += bp[(nbase+r)*64 + m];
    }
  }
  float rs_[4][4];
  #pragma unroll
  for (int ni=0; ni<4; ++ni){
    #pragma unroll
    for (int r=0;r<4;r++){
      float t = fmaxf(fmaxf(s[ni][0][r], s[ni][1][r]), fmaxf(s[ni][2][r], s[ni][3][r]));
      #pragma unroll
      for (int o=1;o<16;o<<=1) t = fmaxf(t, __shfl_xor(t, o, 64));
      float sum = 0.f;
      #pragma unroll
      for (int mj=0; mj<4; ++mj){
        float e = __expf(s[ni][mj][r] - t);
        s[ni][mj][r] = e;
        sum += e;
      }
      #pragma unroll
      for (int o=1;o<16;o<<=1) sum += __shfl_xor(sum, o, 64);
      rs_[ni][r] = sum;
    }
  }
  __syncthreads();
  unsigned short* Ps = Qw;
  #pragma unroll
  for (int ni=0; ni<4; ++ni){
    int nbase = ni*16 + (lane>>4)*4;
    #pragma unroll
    for (int mj=0; mj<4; ++mj){
      int m = mj*16 + fm;
      #pragma unroll
      for (int r=0;r<4;r++)
        Ps[(nbase+r)*72 + m] = f2bf(s[ni][mj][r]);
    }
  }
  f32x4 o2[4][2];
  #pragma unroll
  for (int ni=0; ni<4; ++ni){ o2[ni][0] = (f32x4){}; o2[ni][1] = (f32x4){}; }
  #pragma unroll
  for (int ks=0; ks<2; ++ks){
    bf16x8 vb0 = *(const bf16x8*)&Vt[fm*72 + ks*32+kg];
    bf16x8 vb1 = *(const bf16x8*)&Vt[(16+fm)*72 + ks*32+kg];
    #pragma unroll
    for (int ni=0; ni<4; ++ni){
      bf16x8 pa = *(const bf16x8*)&Ps[(ni*16+fm)*72 + ks*32+kg];
      o2[ni][0] = __builtin_amdgcn_mfma_f32_16x16x32_bf16(pa, vb0, o2[ni][0], 0,0,0);
      o2[ni][1] = __builtin_amdgcn_mfma_f32_16x16x32_bf16(pa, vb1, o2[ni][1], 0,0,0);
    }
  }
  // normalized O (bf16) -> X_s region [64][136] (dead after QKV phase)
  #pragma unroll
  for (int ni=0; ni<4; ++ni){
    #pragma unroll
    for (int r=0;r<4;r++){
      int token = ni*16 + (lane>>4)*4 + r;
      float inv = 1.0f / rs_[ni][r];
      unsigned short* op = &shm[XS_OFF + token*136 + head*32];
      op[fm]    = f2bf(o2[ni][0][r]*inv);
      op[16+fm] = f2bf(o2[ni][1][r]*inv);
    }
  }
  __syncthreads();
  // proj: per-wave 64x32 slice, same fragment/k-order as the gemm2 proj (bitwise identical)
  {
    f32x4 pacc[4][2];
    #pragma unroll
    for (int tf=0; tf<4; ++tf){ pacc[tf][0] = (f32x4){}; pacc[tf][1] = (f32x4){}; }
    int wrow0 = wave*32;
    #pragma unroll
    for (int kk0=0; kk0<128; kk0+=32){
      bf16x8 bfr0 = *(const bf16x8*)(PROJW + (size_t)(wrow0 + fm)*128 + kk0 + kg);
      bf16x8 bfr1 = *(const bf16x8*)(PROJW + (size_t)(wrow0 + 16 + fm)*128 + kk0 + kg);
      #pragma unroll
      for (int tf=0; tf<4; ++tf){
        bf16x8 af = *(const bf16x8*)&shm[XS_OFF + (tf*16+fm)*136 + kk0 + kg];
        pacc[tf][0] = __builtin_amdgcn_mfma_f32_16x16x32_bf16(af, bfr0, pacc[tf][0], 0,0,0);
        pacc[tf][1] = __builtin_amdgcn_mfma_f32_16x16x32_bf16(af, bfr1, pacc[tf][1], 0,0,0);
      }
    }
    #pragma unroll
    for (int tf=0; tf<4; ++tf){
      #pragma unroll
      for (int cf=0; cf<2; ++cf){
        int n = wave*32 + cf*16 + fm;
        float bsv = projb[n];
        #pragma unroll
        for (int r=0;r<4;r++){
          size_t l = rowbase + (size_t)tf*WID + (lane>>4)*4 + r;
          XT[l*C_DIM + n] += pacc[tf][cf][r] + bsv;
        }
      }
    }
  }
}

// ---------------- LeFF dwconv strip v2: rolling window, weights in registers ----------------
__global__ __launch_bounds__(256) void dwconv_strip(const unsigned short* __restrict__ SB1,
                                                    const float* __restrict__ dw,
                                                    const float* __restrict__ db,
                                                    unsigned short* __restrict__ SB2,
                                                    int r0){
  int blk = blockIdx.x;
  int wt = blk % 12, hl = blk / 12;
  int tid = threadIdx.x;
  int c4 = tid & 127, ph = tid >> 7;
  int ch = c4*4;
  int w0 = wt*16 + ph*8;
  int h = r0 + hl;
  float wreg[9][4], bias[4];
  #pragma unroll
  for (int j=0;j<4;j++){
    bias[j] = db[ch+j];
    #pragma unroll
    for (int t9=0;t9<9;t9++) wreg[t9][j] = dw[(ch+j)*9+t9];
  }
  const unsigned short* rp[3];
  bool rv[3];
  #pragma unroll
  for (int ky=0;ky<3;ky++){
    int hh = h + ky - 1;
    rv[ky] = (hh >= 0) && (hh < HGT);
    rp[ky] = SB1 + ((size_t)(hl+ky)*WID)*512 + ch;
  }
  float win[3][3][4];
  #pragma unroll
  for (int ky=0;ky<3;ky++){
    #pragma unroll
    for (int j=0;j<4;j++){ win[ky][0][j]=0.f; win[ky][1][j]=0.f; }
    if (rv[ky]){
      if (w0 > 0){
        const unsigned int* p = (const unsigned int*)(rp[ky] + (size_t)(w0-1)*512);
        unsigned int u0=p[0], u1=p[1];
        win[ky][0][0]=bf2f((unsigned short)(u0&0xFFFF)); win[ky][0][1]=bf2f((unsigned short)(u0>>16));
        win[ky][0][2]=bf2f((unsigned short)(u1&0xFFFF)); win[ky][0][3]=bf2f((unsigned short)(u1>>16));
      }
      {
        const unsigned int* p = (const unsigned int*)(rp[ky] + (size_t)w0*512);
        unsigned int u0=p[0], u1=p[1];
        win[ky][1][0]=bf2f((unsigned short)(u0&0xFFFF)); win[ky][1][1]=bf2f((unsigned short)(u0>>16));
        win[ky][1][2]=bf2f((unsigned short)(u1&0xFFFF)); win[ky][1][3]=bf2f((unsigned short)(u1>>16));
      }
    }
  }
  #pragma unroll
  for (int px=0; px<8; ++px){
    int w = w0 + px;
    #pragma unroll
    for (int ky=0;ky<3;ky++){
      #pragma unroll
      for (int j=0;j<4;j++) win[ky][2][j]=0.f;
      if (rv[ky] && (w+1) < WID){
        const unsigned int* p = (const unsigned int*)(rp[ky] + (size_t)(w+1)*512);
        unsigned int u0=p[0], u1=p[1];
        win[ky][2][0]=bf2f((unsigned short)(u0&0xFFFF)); win[ky][2][1]=bf2f((unsigned short)(u0>>16));
        win[ky][2][2]=bf2f((unsigned short)(u1&0xFFFF)); win[ky][2][3]=bf2f((unsigned short)(u1>>16));
      }
    }
    float a[4];
    #pragma unroll
    for (int j=0;j<4;j++){
      float acc = bias[j];
      #pragma unroll
      for (int ky=0;ky<3;ky++)
        #pragma unroll
        for (int kx=0;kx<3;kx++)
          acc += wreg[ky*3+kx][j]*win[ky][kx][j];
      a[j] = gelu_f(acc);
    }
    unsigned int o0 = (unsigned int)f2bf(a[0]) | ((unsigned int)f2bf(a[1])<<16);
    unsigned int o1 = (unsigned int)f2bf(a[2]) | ((unsigned int)f2bf(a[3])<<16);
    unsigned int* op = (unsigned int*)&SB2[((size_t)hl*WID + w)*512 + ch];
    op[0] = o0; op[1] = o1;
    #pragma unroll
    for (int ky=0;ky<3;ky++)
      #pragma unroll
      for (int j=0;j<4;j++){ win[ky][0][j]=win[ky][1][j]; win[ky][1][j]=win[ky][2][j]; }
  }
}

// ---------------- per-batch BHWC -> BCHW transpose (z = batch, stride param) ----------------
__global__ __launch_bounds__(256) void transpose_b_kernel(const float* __restrict__ src, float* __restrict__ dst,
                                                          size_t zstride){
  __shared__ float tile[128*65];
  int w0 = blockIdx.x*64, h = blockIdx.y;
  size_t zo = (size_t)blockIdx.z * zstride;
  int tid = threadIdx.x;
  for (int r=0; r<32; r++){
    int e = tid + 256*r; int c = e & 127, wl = e >> 7;
    tile[c*65 + wl] = src[zo + ((size_t)h*WID + w0 + wl)*C_DIM + c];
  }
  __syncthreads();
  for (int r=0; r<32; r++){
    int e = tid + 256*r; int wl = e & 63, c = e >> 6;
    dst[zo + ((size_t)c*HGT + h)*WID + w0 + wl] = tile[c*65 + wl];
  }
}

// ---------------- host ----------------
extern "C" void kernel_launch(void* const* d_in, const int* in_sizes, int n_in,
                              void* d_out, int out_size, void* d_ws, size_t ws_size,
                              hipStream_t stream) {
  const float* x      = (const float*)d_in[0];
  const float* pos_w  = (const float*)d_in[1];
  const float* pos_b  = (const float*)d_in[2];
  const float* ln1_g  = (const float*)d_in[3];
  const float* ln1_b  = (const float*)d_in[4];
  const float* q_w    = (const float*)d_in[5];
  const float* q_b    = (const float*)d_in[6];
  const float* kv_w   = (const float*)d_in[7];
  const float* kv_b   = (const float*)d_in[8];
  const float* rpb    = (const float*)d_in[9];
  const float* proj_w = (const float*)d_in[10];
  const float* proj_b = (const float*)d_in[11];
  const float* fft1_w = (const float*)d_in[12];
  const float* fft1_b = (const float*)d_in[13];
  const float* fft2_w = (const float*)d_in[14];
  const float* fft2_b = (const float*)d_in[15];
  const float* ln2_g  = (const float*)d_in[16];
  const float* ln2_b  = (const float*)d_in[17];
  const float* l1_w   = (const float*)d_in[18];
  const float* l1_b   = (const float*)d_in[19];
  const float* dw_w   = (const float*)d_in[20];
  const float* dw_b   = (const float*)d_in[21];
  const float* l2_w   = (const float*)d_in[22];
  const float* l2_b   = (const float*)d_in[23];

  const size_t S   = (size_t)NB*HGT*WID*C_DIM;   // 18,874,368
  const size_t Sb  = S/NB;                       //  4,718,592
  const size_t SZb = (size_t)HGT*WFD*C_DIM;      //  2,383,872 (u16 per spectrum half)
  const size_t GSZ = (size_t)HGT*WFD*256;        //  4,767,744 (u16)
  const int    P   = (int)(NB*HGT*WID);          // 147,456

  float* ws    = (float*)d_ws;
  float* TAB   = ws;
  float* STATS = ws + TAB_SZ;
  float* POOL  = ws + TAB_SZ + 2*(size_t)P;
  size_t head  = TAB_SZ + 2*(size_t)P;
  size_t pool  = (ws_size/4 > head) ? (ws_size/4 - head) : 0;

  bool xt_in_pool = (pool >= S + 11000000);
  float* XT     = xt_in_pool ? POOL : (float*)d_out;
  float* POOL2  = xt_in_pool ? POOL + S : POOL;
  size_t pool2  = xt_in_pool ? pool - S : pool;

  const float* biasT = TAB + T_BIAS;
  const float* QKVB  = TAB + T_QKVB;
  const unsigned short* UT = (const unsigned short*)(TAB + TF_SZ);
  const unsigned short* MW  = UT + UT_MW;
  const unsigned short* MHF = UT + UT_MHF;
  const unsigned short* MHI = UT + UT_MHI;
  const unsigned short* MWI = UT + UT_MWI;
  const unsigned short* QKVW  = UT + UT_QKVW;
  const unsigned short* PROJW = UT + UT_PROJW;
  const unsigned short* FFT1W = UT + UT_FFT1W;
  const unsigned short* FFT2W = UT + UT_FFT2W;
  const unsigned short* L1W   = UT + UT_L1W;
  const unsigned short* L2W   = UT + UT_L2W;

  build_tables<<<2858, 256, 0, stream>>>(TAB, rpb, q_b, kv_b, q_w, kv_w, proj_w,
                                         fft1_w, fft2_w, l1_w, l2_w);
  posconv3_kernel<<<dim3(6,24,32), 256, 0, stream>>>(x, pos_w, pos_b, XT);

  // ---- attention: LN1 stats -> fused(LN+QKV+attn+proj, RMW XT) ----
  ln_stats_kernel<<<P/4, 256, 0, stream>>>(XT, STATS);
  attn_fused3<<<2304, 256, 0, stream>>>(XT, STATS, ln1_g, ln1_b, QKVW, QKVB,
                                        biasT, PROJW, proj_b);

  // ---- FFT residual branch: all-MFMA, bf16 spectra, balanced k-chunks; mixes = gemm2 NT=1 ----
  {
    unsigned short* FRu = (unsigned short*)POOL2;
    unsigned short* FIu = FRu + SZb;
    unsigned short* Gu  = FIu + SZb;
    size_t fixed = SZb + GSZ/2;                  // floats used by FR+FI+G
    int CKmax = 1;
    if (pool2 > fixed + 49152) CKmax = (int)((pool2 - fixed)/49152);
    if (CKmax < 1) CKmax = 1;
    if (CKmax > WFD) CKmax = WFD;
    int nch = (WFD + CKmax - 1)/CKmax;
    int CK = (WFD + nch - 1)/nch;
    unsigned short* FF0u = (unsigned short*)(POOL2 + fixed);
    unsigned short* FF1u = FF0u + (size_t)CK*49152;
    for (int b = 0; b < NB; ++b){
      float* XTb = XT + (size_t)b*Sb;
      dft_gemm<0><<<dim3(2, 192*4), 256, 0, stream>>>(MW, XTb, nullptr, FRu, FIu, 0);
      for (int k0 = 0; k0 < WFD; k0 += CK){
        int ck = (WFD - k0 < CK) ? (WFD - k0) : CK;
        int rows = ck*192;
        dft_gemm<1><<<dim3(2, ck*6), 256, 0, stream>>>(MHF, FRu, FIu, FF0u, nullptr, k0);
        gemm2<1,false,false,true,true,1><<<dim3(4, rows/64), 256, 0, stream>>>(
            FF0u, FFT1W, fft1_b, FF1u, 256, 256, 256, nullptr, nullptr, nullptr, 0, 0);
        gemm2<0,false,false,true,true,1><<<dim3(4, rows/64), 256, 0, stream>>>(
            FF1u, FFT2W, fft2_b, FF0u, 256, 256, 256, nullptr, nullptr, nullptr, 0, 0);
        dft_gemm<2><<<dim3(2, ck*6), 256, 0, stream>>>(MHI, FF0u, FF0u+128, Gu, nullptr, k0);
      }
      dft_gemm<3><<<dim3(2, 192*3), 256, 0, stream>>>(MWI, Gu, Gu+128, XTb, nullptr, 0);
    }
  }

  // ---- LN2 stats ----
  ln_stats_kernel<<<P/4, 256, 0, stream>>>(XT, STATS);

  // ---- LeFF: strip-mined l1 (gemm2 NT=2) -> dwconv -> l2 (gemm2 NT=1) ----
  {
    int SH = 96;
    while ((size_t)(3*SH+4)*49152 > pool2 && SH > 24) SH >>= 1;
    const size_t SB1SZ = (size_t)(SH+2)*98304;   // u16
    unsigned short* SB1u[2] = { (unsigned short*)POOL2, (unsigned short*)POOL2 + SB1SZ };
    unsigned short* SB2u = (unsigned short*)POOL2 + 2*SB1SZ;
    int nStrips = HGT/SH;
    for (int b = 0; b < NB; ++b){
      auto launch_g = [&](int s){
        int r0 = s*SH;
        int prow0 = (b*HGT + r0 - 1)*WID;
        gemm2<2,false,true,false,true,2><<<dim3(4, (SH+2)*3), 256, 0, stream>>>(
            XT, L1W, l1_b, SB1u[s&1], 128, 512, 128,
            STATS, ln2_g, ln2_b, prow0, P-1);
      };
      launch_g(0);
      for (int s = 0; s < nStrips; ++s){
        if (s+1 < nStrips) launch_g(s+1);
        int r0 = s*SH;
        dwconv_strip<<<12*SH, 256, 0, stream>>>(SB1u[s&1], dw_w, dw_b, SB2u, r0);
        gemm2<0,true,false,true,false,1><<<dim3(2, SH*3), 256, 0, stream>>>(
            SB2u, L2W, l2_b, XT + ((size_t)(b*HGT + r0)*WID)*C_DIM,
            512, 128, 512, nullptr, nullptr, nullptr, 0, 0);
      }
    }
  }

  // ---- final transpose ----
  if (xt_in_pool){
    transpose_b_kernel<<<dim3(3,192,4), 256, 0, stream>>>(XT, (float*)d_out, Sb);
  } else {
    for (int b = 0; b < NB; ++b){
      transpose_b_kernel<<<dim3(3,192,1), 256, 0, stream>>>(XT + (size_t)b*Sb, POOL2, 0);
      hipMemcpyAsync((float*)d_out + (size_t)b*Sb, POOL2, Sb*sizeof(float),
                     hipMemcpyDeviceToDevice, stream);
    }
  }
}

// Round 19
// 1109.097 us; speedup vs baseline: 1.2662x; 1.0400x over previous
//
#include <hip/hip_runtime.h>
#include <hip/hip_bf16.h>
#include <math.h>

// ---------------- constants ----------------
#define C_DIM 128
#define HGT 192
#define WID 192
#define NB 4
#define WFD 97   // 192/2+1

// TAB float region
#define T_BIAS  0                // 4*64*64 fp32
#define T_QKVB  16384            // 384 fp32 (q_b | kv_b)
#define TF_SZ   16896
// TAB bf16 region (ushort offsets, base = TAB + TF_SZ floats)
#define UT_MW    0               // [256][192]
#define UT_MHF   49152           // [384][384]
#define UT_MHI   196608          // [384][384]
#define UT_MWI   344064          // [192][224]
#define UT_QKVW  387072          // [384][128]
#define UT_PROJW 436224          // [128][128]
#define UT_FFT1W 452608          // [256][256]
#define UT_FFT2W 518144          // [256][256]
#define UT_L1W   583680          // [512][128]
#define UT_L2W   649216          // [128][512]
#define UT_TOT   714752
#define TAB_SZ   374272          // floats: TF_SZ + UT_TOT/2

typedef __attribute__((ext_vector_type(8))) short bf16x8;
typedef __attribute__((ext_vector_type(4))) float f32x4;

__device__ __forceinline__ float gelu_f(float v){
  return 0.5f*v*(1.0f + erff(v*0.70710678118654752440f));
}
__device__ __forceinline__ unsigned short f2bf(float f){
  __hip_bfloat16 h = __float2bfloat16(f);
  return *reinterpret_cast<unsigned short*>(&h);
}
__device__ __forceinline__ float bf2f(unsigned short u){
  unsigned int x = ((unsigned int)u)<<16;
  return __uint_as_float(x);
}
__device__ __forceinline__ void st8u(unsigned short* d, bf16x8 v){
  unsigned int* wp = (unsigned int*)&v;
  unsigned int* dp = (unsigned int*)d;
  dp[0]=wp[0]; dp[1]=wp[1]; dp[2]=wp[2]; dp[3]=wp[3];
}

// ---------------- table build (exact int mod-192 + float trig) ----------------
__global__ __launch_bounds__(256) void build_tables(float* __restrict__ tab,
        const float* __restrict__ rpb, const float* __restrict__ q_b, const float* __restrict__ kv_b,
        const float* __restrict__ q_w, const float* __restrict__ kv_w, const float* __restrict__ proj_w,
        const float* __restrict__ fft1_w, const float* __restrict__ fft2_w,
        const float* __restrict__ l1_w, const float* __restrict__ l2_w){
  int idx = blockIdx.x*256 + threadIdx.x;
  const float STEP = (float)(6.283185307179586476925286766559/192.0);
  if (idx < 16384){ // attn bias fp32: [head][n][m]
    int head = idx>>12, n = (idx>>6)&63, m = idx&63;
    int dh = n/16 - m/16 + 3;
    int dw = (n&15) - (m&15) + 15;
    tab[T_BIAS+idx] = rpb[(dh*31+dw)*4 + head];
    return;
  }
  idx -= 16384;
  if (idx < 384){ // QKV bias concat fp32
    tab[T_QKVB+idx] = (idx < 128) ? q_b[idx] : kv_b[idx-128];
    return;
  }
  idx -= 384;
  unsigned short* ut = (unsigned short*)(tab + TF_SZ);
  if (idx < 49152){ // MW [256][192]
    int r = idx/192, w = idx%192;
    float v = 0.f;
    if (r < 97){ int a = (r*w)%192; v = cosf(a*STEP); }
    else if (r < 194){ int a = ((r-97)*w)%192; v = -sinf(a*STEP); }
    ut[UT_MW+idx] = f2bf(v);
    return;
  }
  idx -= 49152;
  if (idx < 147456){ // MHF [384][384]
    int r = idx/384, j = idx%384;
    int hf = (r < 192) ? r : r-192;
    int h  = (j < 192) ? j : j-192;
    int a = (hf*h)%192;
    float c = cosf(a*STEP), s = sinf(a*STEP);
    float v;
    if (r < 192) v = (j < 192) ? c : s;
    else         v = (j < 192) ? -s : c;
    ut[UT_MHF+idx] = f2bf(v);
    return;
  }
  idx -= 147456;
  if (idx < 147456){ // MHI [384][384]
    int r = idx/384, j = idx%384;
    int h  = (r < 192) ? r : r-192;
    int hf = (j < 192) ? j : j-192;
    int a = (h*hf)%192;
    float c = cosf(a*STEP), s = sinf(a*STEP);
    float v;
    if (r < 192) v = (j < 192) ? c : -s;
    else         v = (j < 192) ? s : c;
    ut[UT_MHI+idx] = f2bf(v);
    return;
  }
  idx -= 147456;
  if (idx < 43008){ // MWI [192][224]
    int w = idx/224, j = idx%224;
    float v = 0.f;
    if (j < 97){
      int a = (j*w)%192;
      float sc = ((j==0 || j==96) ? 1.f : 2.f) / 36864.f;
      v = sc*cosf(a*STEP);
    } else if (j >= 112 && j < 209){
      int k = j-112;
      int a = (k*w)%192;
      float sc = ((k==0 || k==96) ? 1.f : 2.f) / 36864.f;
      v = -sc*sinf(a*STEP);
    }
    ut[UT_MWI+idx] = f2bf(v);
    return;
  }
  idx -= 43008;
  if (idx < 49152){ // QKVW [384][128]
    int n = idx/128, k = idx%128;
    float v = (n < 128) ? q_w[(size_t)k*128 + n] : kv_w[(size_t)k*256 + (n-128)];
    ut[UT_QKVW+idx] = f2bf(v);
    return;
  }
  idx -= 49152;
  if (idx < 16384){ // PROJW [128][128]
    int n = idx/128, k = idx%128;
    ut[UT_PROJW+idx] = f2bf(proj_w[(size_t)k*128 + n]);
    return;
  }
  idx -= 16384;
  if (idx < 65536){ // FFT1W [256][256]
    int n = idx/256, k = idx%256;
    ut[UT_FFT1W+idx] = f2bf(fft1_w[(size_t)k*256 + n]);
    return;
  }
  idx -= 65536;
  if (idx < 65536){ // FFT2W [256][256]
    int n = idx/256, k = idx%256;
    ut[UT_FFT2W+idx] = f2bf(fft2_w[(size_t)k*256 + n]);
    return;
  }
  idx -= 65536;
  if (idx < 65536){ // L1W [512][128]
    int n = idx/128, k = idx%128;
    ut[UT_L1W+idx] = f2bf(l1_w[(size_t)k*512 + n]);
    return;
  }
  idx -= 65536;
  if (idx < 65536){ // L2W [128][512]
    int n = idx/512, k = idx%512;
    ut[UT_L2W+idx] = f2bf(l2_w[(size_t)k*128 + n]);
  }
}

// ---------------- pos depthwise conv: 8h x 32w x 16c ----------------
__global__ __launch_bounds__(256) void posconv3_kernel(const float* __restrict__ x, const float* __restrict__ pw,
                               const float* __restrict__ pb, float* __restrict__ xt){
  __shared__ float rows_s[16*340];
  int w0 = blockIdx.x*32, h0 = blockIdx.y*8;
  int b = blockIdx.z >> 3, cb = (blockIdx.z & 7)*16;
  int tid = threadIdx.x;
  int hl = tid >> 5, wl = tid & 31;
  for (int e = tid; e < 16*340; e += 256){
    int c = e / 340; int rem = e - c*340;
    int r = rem / 34; int wc = rem - r*34;
    int gh = h0 - 1 + r, gw = w0 - 1 + wc;
    float v = 0.f;
    if (gh >= 0 && gh < HGT && gw >= 0 && gw < WID)
      v = x[((size_t)(b*C_DIM + cb + c))*(HGT*WID) + gh*WID + gw];
    rows_s[e] = v;
  }
  __syncthreads();
  float outr[16];
  #pragma unroll
  for (int c = 0; c < 16; ++c){
    const float* rs = &rows_s[c*340];
    float wreg[9];
    #pragma unroll
    for (int t9 = 0; t9 < 9; ++t9) wreg[t9] = pw[(cb+c)*27 + 9 + t9];
    float bias = pb[cb+c];
    float acc = rs[(hl+1)*34 + wl+1] + bias;
    #pragma unroll
    for (int ky = 0; ky < 3; ++ky)
      #pragma unroll
      for (int kx = 0; kx < 3; ++kx)
        acc += wreg[ky*3+kx]*rs[(hl+ky)*34 + wl+kx];
    outr[c] = acc;
  }
  __syncthreads();
  {
    int px = hl*32 + wl;
    #pragma unroll
    for (int c = 0; c < 16; ++c) rows_s[px*17 + c] = outr[c];
  }
  __syncthreads();
  for (int r = 0; r < 16; ++r){
    int e = r*256 + tid;
    int cl = e & 15, hw = e >> 4;
    int h = hw >> 5, w = hw & 31;
    xt[((size_t)(b*HGT + h0+h)*WID + (w0+w))*C_DIM + cb + cl] = rows_s[hw*17 + cl];
  }
}

// ---------------- LN row stats ----------------
__global__ __launch_bounds__(256) void ln_stats_kernel(const float* __restrict__ src, float* __restrict__ stats){
  int wave = threadIdx.x >> 6; int lane = threadIdx.x & 63;
  size_t p = (size_t)blockIdx.x*4 + wave;
  const float* s = src + p*C_DIM;
  float v0 = s[lane], v1 = s[lane+64];
  float sum = v0 + v1;
  #pragma unroll
  for (int o=1; o<64; o<<=1) sum += __shfl_xor(sum, o, 64);
  float m = sum * (1.0f/128.0f);
  float d0 = v0-m, d1 = v1-m;
  float vs = d0*d0 + d1*d1;
  #pragma unroll
  for (int o=1; o<64; o<<=1) vs += __shfl_xor(vs, o, 64);
  float rstd = rsqrtf(vs*(1.0f/128.0f) + 1e-5f);
  if (lane==0){ stats[2*p] = m; stats[2*p+1] = rstd; }
}

// ---------------- unified MFMA GEMM (64x64 tile, NT n-tiles) ----------------
// OUTT: BCHW direct output with fp32 residual from `stats` (pixel base in prow0).
template<int ACT, bool ADD, bool LNA, bool ABF, bool OBF, int NT, bool OUTT = false>
__global__ __launch_bounds__(256) void gemm2(const void* __restrict__ A1v,
                            const unsigned short* __restrict__ WT, const float* __restrict__ bias,
                            void* __restrict__ dstv, int K, int N, int lda,
                            const float* __restrict__ stats, const float* __restrict__ lng,
                            const float* __restrict__ lnb, int prow0, int pmax){
  __shared__ __align__(16) unsigned short As[64*40];
  __shared__ __align__(16) unsigned short Bs[NT][64*40];
  __shared__ float tileT[OUTT ? 64*66 : 1];
  int p0 = blockIdx.y*64, n00 = blockIdx.x*(64*NT);
  int tid = threadIdx.x;
  int wave = tid >> 6, lane = tid & 63;
  int wr = (wave>>1)*32, wc = (wave&1)*32;
  f32x4 acc[NT][4];
  #pragma unroll
  for (int nt=0; nt<NT; ++nt)
    #pragma unroll
    for (int q=0; q<4; ++q) acc[nt][q] = (f32x4){};
  int am = tid >> 2, ak = (tid & 3)*8;
  int brow = tid >> 2, bkk = (tid & 3)*8;
  for (int k0 = 0; k0 < K; k0 += 32){
    if constexpr (ABF){
      const unsigned short* A1u = (const unsigned short*)A1v;
      bf16x8 av = *(const bf16x8*)(A1u + (size_t)(p0+am)*lda + k0 + ak);
      st8u(&As[am*40 + ak], av);
    } else {
      int gp = p0 + am;
      float s0 = 0.f, s1 = 0.f;
      if (LNA){
        gp += prow0;
        gp = gp < 0 ? 0 : (gp > pmax ? pmax : gp);
        s0 = stats[2*gp]; s1 = stats[2*gp+1];
      }
      const float* src = (const float*)A1v + (size_t)gp*lda + k0 + ak;
      float4 aa = *(const float4*)src;
      float4 ab = *(const float4*)(src+4);
      float v[8] = {aa.x,aa.y,aa.z,aa.w,ab.x,ab.y,ab.z,ab.w};
      unsigned short* dp = &As[am*40 + ak];
      #pragma unroll
      for (int j=0;j<8;j++){
        float f = v[j];
        if (LNA) f = (f - s0)*s1*lng[k0+ak+j] + lnb[k0+ak+j];
        dp[j] = f2bf(f);
      }
    }
    #pragma unroll
    for (int nt=0; nt<NT; ++nt){
      bf16x8 wv = *(const bf16x8*)(WT + (size_t)(n00 + nt*64 + brow)*K + k0 + bkk);
      st8u(&Bs[nt][brow*40 + bkk], wv);
    }
    __syncthreads();
    int fm = lane & 15, kg = (lane>>4)*8;
    bf16x8 a0 = *(const bf16x8*)&As[(wr+fm)*40 + kg];
    bf16x8 a1 = *(const bf16x8*)&As[(wr+16+fm)*40 + kg];
    #pragma unroll
    for (int nt=0; nt<NT; ++nt){
      bf16x8 b0 = *(const bf16x8*)&Bs[nt][(wc+fm)*40 + kg];
      bf16x8 b1 = *(const bf16x8*)&Bs[nt][(wc+16+fm)*40 + kg];
      acc[nt][0] = __builtin_amdgcn_mfma_f32_16x16x32_bf16(a0, b0, acc[nt][0], 0,0,0);
      acc[nt][1] = __builtin_amdgcn_mfma_f32_16x16x32_bf16(a0, b1, acc[nt][1], 0,0,0);
      acc[nt][2] = __builtin_amdgcn_mfma_f32_16x16x32_bf16(a1, b0, acc[nt][2], 0,0,0);
      acc[nt][3] = __builtin_amdgcn_mfma_f32_16x16x32_bf16(a1, b1, acc[nt][3], 0,0,0);
    }
    __syncthreads();
  }
  int cn = lane & 15, rq = (lane>>4)*4;
  if constexpr (OUTT){
    // l2 path: out = acc + bias + XTres; stage tile then BCHW write
    const float* XTres = stats;
    int p0b = prow0 + p0;   // global pixel index of tile row 0 (64-aligned, same h-row)
    #pragma unroll
    for (int mi=0; mi<2; ++mi){
      #pragma unroll
      for (int ni=0; ni<2; ++ni){
        f32x4 a = acc[0][mi*2+ni];
        int nl = wc + ni*16 + cn;
        float bsv = bias[n00 + nl];
        #pragma unroll
        for (int r=0; r<4; ++r){
          int rowl = wr + mi*16 + rq + r;
          float v = a[r] + bsv;
          v += XTres[(size_t)(p0b + rowl)*C_DIM + n00 + nl];
          tileT[rowl*66 + nl] = v;
        }
      }
    }
    __syncthreads();
    int bb = p0b/36864;
    int hh = (p0b/192)%192;
    int w0 = p0b%192;
    float* dout = (float*)dstv;
    #pragma unroll
    for (int it=0; it<16; ++it){
      int e = it*256 + tid;
      int c = e >> 6, wl = e & 63;
      dout[((size_t)bb*C_DIM + n00 + c)*36864 + (size_t)hh*192 + w0 + wl] = tileT[wl*66 + c];
    }
  } else {
    #pragma unroll
    for (int nt=0; nt<NT; ++nt){
      #pragma unroll
      for (int mi=0; mi<2; ++mi){
        #pragma unroll
        for (int ni=0; ni<2; ++ni){
          f32x4 a = acc[nt][mi*2+ni];
          int n = n00 + nt*64 + wc + ni*16 + cn;
          float bsv = bias[n];
          #pragma unroll
          for (int r=0; r<4; ++r){
            size_t row = (size_t)p0 + wr + mi*16 + rq + r;
            float v = a[r] + bsv;
            if (ACT==1) v = (v>=0.f) ? v : 0.01f*v;
            if (ACT==2) v = gelu_f(v);
            if constexpr (OBF){
              ((unsigned short*)dstv)[row*(size_t)N + n] = f2bf(v);
            } else {
              float* dst = (float*)dstv;
              if (ADD) v += dst[row*(size_t)N + n];
              dst[row*(size_t)N + n] = v;
            }
          }
        }
      }
    }
  }
}

// ---------------- DFT-as-GEMM (bf16 tables / bf16 spectra) ----------------
template<int MODE>
__global__ __launch_bounds__(256) void dft_gemm(const unsigned short* __restrict__ Atab,
                            const void* __restrict__ W1v, const void* __restrict__ W2v,
                            void* __restrict__ D1v, void* __restrict__ D2v, int k0){
  constexpr int K      = (MODE==0)?192 : (MODE==3)?224 : 384;
  constexpr int MT     = (MODE==0)?4 : (MODE==3)?3 : 6;
  constexpr int MVALID = (MODE==0)?194 : (MODE==3)?192 : 384;
  __shared__ __align__(16) unsigned short As[64*40];
  __shared__ __align__(16) unsigned short Bs[64*40];
  int slab = blockIdx.y / MT;
  int p0 = (blockIdx.y % MT)*64, n0 = blockIdx.x*64;
  int tid = threadIdx.x;
  int wave = tid >> 6, lane = tid & 63;
  int wr = (wave>>1)*32, wc = (wave&1)*32;
  f32x4 acc00 = {}, acc01 = {}, acc10 = {}, acc11 = {};
  int am = tid >> 2, ak = (tid & 3)*8;
  int bk = tid >> 3, bn = (tid & 7)*8;
  for (int kk0 = 0; kk0 < K; kk0 += 32){
    {
      bf16x8 av = *(const bf16x8*)(Atab + (size_t)(p0+am)*K + kk0 + ak);
      st8u(&As[am*40 + ak], av);
    }
    {
      int r = kk0 + bk;
      if (MODE==0){
        const float* src = (const float*)W1v + (size_t)slab*24576 + (size_t)r*128 + n0 + bn;
        float4 wa = *(const float4*)src;
        float4 wb = *(const float4*)(src+4);
        float v[8] = {wa.x,wa.y,wa.z,wa.w,wb.x,wb.y,wb.z,wb.w};
        #pragma unroll
        for (int j=0;j<8;j++) Bs[(bn+j)*40 + bk] = f2bf(v[j]);
      } else {
        const unsigned short* src;
        if (MODE==1) src = (r<192) ? (const unsigned short*)W1v + (size_t)(k0+slab)*128 + (size_t)r*12416
                                   : (const unsigned short*)W2v + (size_t)(k0+slab)*128 + (size_t)(r-192)*12416;
        else if (MODE==2) src = (r<192) ? (const unsigned short*)W1v + (size_t)slab*49152 + (size_t)r*256
                                        : (const unsigned short*)W2v + (size_t)slab*49152 + (size_t)(r-192)*256;
        else src = (r<112) ? (const unsigned short*)W1v + (size_t)slab*24832 + (size_t)r*256
                           : (const unsigned short*)W2v + (size_t)slab*24832 + (size_t)(r-112)*256;
        src += n0 + bn;
        bf16x8 wv = *(const bf16x8*)src;
        #pragma unroll
        for (int j=0;j<8;j++) Bs[(bn+j)*40 + bk] = (unsigned short)wv[j];
      }
    }
    __syncthreads();
    int fm = lane & 15, kg = (lane>>4)*8;
    bf16x8 a0 = *(const bf16x8*)&As[(wr+fm)*40 + kg];
    bf16x8 a1 = *(const bf16x8*)&As[(wr+16+fm)*40 + kg];
    bf16x8 b0 = *(const bf16x8*)&Bs[(wc+fm)*40 + kg];
    bf16x8 b1 = *(const bf16x8*)&Bs[(wc+16+fm)*40 + kg];
    acc00 = __builtin_amdgcn_mfma_f32_16x16x32_bf16(a0, b0, acc00, 0,0,0);
    acc01 = __builtin_amdgcn_mfma_f32_16x16x32_bf16(a0, b1, acc01, 0,0,0);
    acc10 = __builtin_amdgcn_mfma_f32_16x16x32_bf16(a1, b0, acc10, 0,0,0);
    acc11 = __builtin_amdgcn_mfma_f32_16x16x32_bf16(a1, b1, acc11, 0,0,0);
    __syncthreads();
  }
  int cn = lane & 15, rq = (lane>>4)*4;
  #pragma unroll
  for (int mi=0; mi<2; ++mi){
    #pragma unroll
    for (int ni=0; ni<2; ++ni){
      f32x4 a = (mi==0) ? (ni==0?acc00:acc01) : (ni==0?acc10:acc11);
      int n = n0 + wc + ni*16 + cn;
      #pragma unroll
      for (int r=0; r<4; ++r){
        int p = p0 + wr + mi*16 + rq + r;
        if (p >= MVALID) continue;
        float v = a[r];
        if (MODE==0){
          unsigned short* D1 = (unsigned short*)D1v;
          unsigned short* D2 = (unsigned short*)D2v;
          if (p < 97) D1[(size_t)slab*12416 + (size_t)p*128 + n] = f2bf(v);
          else        D2[(size_t)slab*12416 + (size_t)(p-97)*128 + n] = f2bf(v);
        } else if (MODE==1){
          unsigned short* base = (unsigned short*)D1v + (size_t)slab*49152;
          if (p < 192) base[(size_t)p*256 + n] = f2bf(v);
          else         base[(size_t)(p-192)*256 + 128 + n] = f2bf(v);
        } else if (MODE==2){
          unsigned short* D1 = (unsigned short*)D1v;
          int kg2 = k0 + slab;
          if (p < 192) D1[((size_t)p*97 + kg2)*256 + n] = f2bf(v);
          else         D1[((size_t)(p-192)*97 + kg2)*256 + 128 + n] = f2bf(v);
        } else {
          ((float*)D1v)[(size_t)slab*24576 + (size_t)p*128 + n] += v;
        }
      }
    }
  }
}

// ---------------- fused attention: LN + QKV + window attn + proj (RMW XT) ----------------
#define XS_OFF  0                      // [64][136] ; O (bf16 [64][128]) aliases after PV
#define WQK_OFF 8704                   // + wave*5120 : Qw [64][40], Kw at +2560; P alias [64][72]
#define VT_OFF  29184                  // + wave*2304 : Vt [32][72]
#define SHM_TOT 38400
__global__ __launch_bounds__(256) void attn_fused3(
    float* __restrict__ XT, const float* __restrict__ stats,
    const float* __restrict__ g1, const float* __restrict__ b1,
    const unsigned short* __restrict__ QKVW, const float* __restrict__ QKVB,
    const float* __restrict__ biasT, const unsigned short* __restrict__ PROJW,
    const float* __restrict__ projb){
  __shared__ __align__(16) unsigned short shm[SHM_TOT];
  int win = blockIdx.x;
  int b = win/576, rem = win%576, whi = rem/12, wwi = rem%12;
  int tid = threadIdx.x, wave = tid>>6, lane = tid&63, head = wave;
  int fm = lane & 15, kg = (lane>>4)*8;
  size_t rowbase = (size_t)(b*HGT + whi*4)*WID + wwi*16;
  {
    int t = tid >> 2;
    int c0 = (tid & 3)*32;
    size_t grow = rowbase + (size_t)(t>>4)*WID + (t&15);
    const float* src = XT + grow*C_DIM + c0;
    float m = stats[2*grow], rs = stats[2*grow+1];
    unsigned short* dst = &shm[XS_OFF + t*136 + c0];
    #pragma unroll
    for (int j=0;j<32;j++){
      float f = (src[j]-m)*rs*g1[c0+j] + b1[c0+j];
      dst[j] = f2bf(f);
    }
  }
  __syncthreads();
  unsigned short* Qw = &shm[WQK_OFF + wave*5120];
  unsigned short* Kw = Qw + 2560;
  unsigned short* Vt = &shm[VT_OFF + wave*2304];
  #pragma unroll
  for (int op=0; op<3; ++op){
    f32x4 acc[4][2];
    #pragma unroll
    for (int tf=0; tf<4; ++tf){ acc[tf][0] = (f32x4){}; acc[tf][1] = (f32x4){}; }
    int wrow0 = op*128 + head*32;
    #pragma unroll
    for (int kk0=0; kk0<128; kk0+=32){
      bf16x8 bfr0 = *(const bf16x8*)(QKVW + (size_t)(wrow0 + fm)*128 + kk0 + kg);
      bf16x8 bfr1 = *(const bf16x8*)(QKVW + (size_t)(wrow0 + 16 + fm)*128 + kk0 + kg);
      #pragma unroll
      for (int tf=0; tf<4; ++tf){
        bf16x8 af = *(const bf16x8*)&shm[XS_OFF + (tf*16+fm)*136 + kk0 + kg];
        acc[tf][0] = __builtin_amdgcn_mfma_f32_16x16x32_bf16(af, bfr0, acc[tf][0], 0,0,0);
        acc[tf][1] = __builtin_amdgcn_mfma_f32_16x16x32_bf16(af, bfr1, acc[tf][1], 0,0,0);
      }
    }
    #pragma unroll
    for (int tf=0; tf<4; ++tf){
      #pragma unroll
      for (int cf=0; cf<2; ++cf){
        int n = cf*16 + fm;
        float bsv = QKVB[op*128 + head*32 + n];
        #pragma unroll
        for (int r=0;r<4;r++){
          int token = tf*16 + (lane>>4)*4 + r;
          float v = acc[tf][cf][r] + bsv;
          if (op==0) v *= 0.17677669529663688f;
          unsigned short bv = f2bf(v);
          if (op==0)      Qw[token*40 + n] = bv;
          else if (op==1) Kw[token*40 + n] = bv;
          else            Vt[n*72 + token] = bv;
        }
      }
    }
  }
  __syncthreads();
  bf16x8 qf[4], kf[4];
  #pragma unroll
  for (int t4=0; t4<4; ++t4){
    qf[t4] = *(const bf16x8*)&Qw[(t4*16+fm)*40 + kg];
    kf[t4] = *(const bf16x8*)&Kw[(t4*16+fm)*40 + kg];
  }
  f32x4 s[4][4];
  #pragma unroll
  for (int ni=0; ni<4; ++ni)
    #pragma unroll
    for (int mj=0; mj<4; ++mj){
      f32x4 z = {};
      s[ni][mj] = __builtin_amdgcn_mfma_f32_16x16x32_bf16(qf[ni], kf[mj], z, 0,0,0);
    }
  const float* bp = biasT + head*4096;
  #pragma unroll
  for (int ni=0; ni<4; ++ni){
    int nbase = ni*16 + (lane>>4)*4;
    #pragma unroll
    for (int mj=0; mj<4; ++mj){
      int m = mj*16 + fm;
      #pragma unroll
      for (int r=0;r<4;r++)
        s[ni][mj][r] += bp[(nbase+r)*64 + m];
    }
  }
  float rs_[4][4];
  #pragma unroll
  for (int ni=0; ni<4; ++ni){
    #pragma unroll
    for (int r=0;r<4;r++){
      float t = fmaxf(fmaxf(s[ni][0][r], s[ni][1][r]), fmaxf(s[ni][2][r], s[ni][3][r]));
      #pragma unroll
      for (int o=1;o<16;o<<=1) t = fmaxf(t, __shfl_xor(t, o, 64));
      float sum = 0.f;
      #pragma unroll
      for (int mj=0; mj<4; ++mj){
        float e = __expf(s[ni][mj][r] - t);
        s[ni][mj][r] = e;
        sum += e;
      }
      #pragma unroll
      for (int o=1;o<16;o<<=1) sum += __shfl_xor(sum, o, 64);
      rs_[ni][r] = sum;
    }
  }
  __syncthreads();
  unsigned short* Ps = Qw;
  #pragma unroll
  for (int ni=0; ni<4; ++ni){
    int nbase = ni*16 + (lane>>4)*4;
    #pragma unroll
    for (int mj=0; mj<4; ++mj){
      int m = mj*16 + fm;
      #pragma unroll
      for (int r=0;r<4;r++)
        Ps[(nbase+r)*72 + m] = f2bf(s[ni][mj][r]);
    }
  }
  f32x4 o2[4][2];
  #pragma unroll
  for (int ni=0; ni<4; ++ni){ o2[ni][0] = (f32x4){}; o2[ni][1] = (f32x4){}; }
  #pragma unroll
  for (int ks=0; ks<2; ++ks){
    bf16x8 vb0 = *(const bf16x8*)&Vt[fm*72 + ks*32+kg];
    bf16x8 vb1 = *(const bf16x8*)&Vt[(16+fm)*72 + ks*32+kg];
    #pragma unroll
    for (int ni=0; ni<4; ++ni){
      bf16x8 pa = *(const bf16x8*)&Ps[(ni*16+fm)*72 + ks*32+kg];
      o2[ni][0] = __builtin_amdgcn_mfma_f32_16x16x32_bf16(pa, vb0, o2[ni][0], 0,0,0);
      o2[ni][1] = __builtin_amdgcn_mfma_f32_16x16x32_bf16(pa, vb1, o2[ni][1], 0,0,0);
    }
  }
  // normalized O (bf16) -> X_s region [64][136] (dead after QKV phase)
  #pragma unroll
  for (int ni=0; ni<4; ++ni){
    #pragma unroll
    for (int r=0;r<4;r++){
      int token = ni*16 + (lane>>4)*4 + r;
      float inv = 1.0f / rs_[ni][r];
      unsigned short* op = &shm[XS_OFF + token*136 + head*32];
      op[fm]    = f2bf(o2[ni][0][r]*inv);
      op[16+fm] = f2bf(o2[ni][1][r]*inv);
    }
  }
  __syncthreads();
  // proj: per-wave 64x32 slice, same fragment/k-order as the gemm2 proj (bitwise identical)
  {
    f32x4 pacc[4][2];
    #pragma unroll
    for (int tf=0; tf<4; ++tf){ pacc[tf][0] = (f32x4){}; pacc[tf][1] = (f32x4){}; }
    int wrow0 = wave*32;
    #pragma unroll
    for (int kk0=0; kk0<128; kk0+=32){
      bf16x8 bfr0 = *(const bf16x8*)(PROJW + (size_t)(wrow0 + fm)*128 + kk0 + kg);
      bf16x8 bfr1 = *(const bf16x8*)(PROJW + (size_t)(wrow0 + 16 + fm)*128 + kk0 + kg);
      #pragma unroll
      for (int tf=0; tf<4; ++tf){
        bf16x8 af = *(const bf16x8*)&shm[XS_OFF + (tf*16+fm)*136 + kk0 + kg];
        pacc[tf][0] = __builtin_amdgcn_mfma_f32_16x16x32_bf16(af, bfr0, pacc[tf][0], 0,0,0);
        pacc[tf][1] = __builtin_amdgcn_mfma_f32_16x16x32_bf16(af, bfr1, pacc[tf][1], 0,0,0);
      }
    }
    #pragma unroll
    for (int tf=0; tf<4; ++tf){
      #pragma unroll
      for (int cf=0; cf<2; ++cf){
        int n = wave*32 + cf*16 + fm;
        float bsv = projb[n];
        #pragma unroll
        for (int r=0;r<4;r++){
          size_t l = rowbase + (size_t)tf*WID + (lane>>4)*4 + r;
          XT[l*C_DIM + n] += pacc[tf][cf][r] + bsv;
        }
      }
    }
  }
}

// ---------------- LeFF dwconv strip v2: rolling window, weights in registers ----------------
__global__ __launch_bounds__(256) void dwconv_strip(const unsigned short* __restrict__ SB1,
                                                    const float* __restrict__ dw,
                                                    const float* __restrict__ db,
                                                    unsigned short* __restrict__ SB2,
                                                    int r0){
  int blk = blockIdx.x;
  int wt = blk % 12, hl = blk / 12;
  int tid = threadIdx.x;
  int c4 = tid & 127, ph = tid >> 7;
  int ch = c4*4;
  int w0 = wt*16 + ph*8;
  int h = r0 + hl;
  float wreg[9][4], bias[4];
  #pragma unroll
  for (int j=0;j<4;j++){
    bias[j] = db[ch+j];
    #pragma unroll
    for (int t9=0;t9<9;t9++) wreg[t9][j] = dw[(ch+j)*9+t9];
  }
  const unsigned short* rp[3];
  bool rv[3];
  #pragma unroll
  for (int ky=0;ky<3;ky++){
    int hh = h + ky - 1;
    rv[ky] = (hh >= 0) && (hh < HGT);
    rp[ky] = SB1 + ((size_t)(hl+ky)*WID)*512 + ch;
  }
  float win[3][3][4];
  #pragma unroll
  for (int ky=0;ky<3;ky++){
    #pragma unroll
    for (int j=0;j<4;j++){ win[ky][0][j]=0.f; win[ky][1][j]=0.f; }
    if (rv[ky]){
      if (w0 > 0){
        const unsigned int* p = (const unsigned int*)(rp[ky] + (size_t)(w0-1)*512);
        unsigned int u0=p[0], u1=p[1];
        win[ky][0][0]=bf2f((unsigned short)(u0&0xFFFF)); win[ky][0][1]=bf2f((unsigned short)(u0>>16));
        win[ky][0][2]=bf2f((unsigned short)(u1&0xFFFF)); win[ky][0][3]=bf2f((unsigned short)(u1>>16));
      }
      {
        const unsigned int* p = (const unsigned int*)(rp[ky] + (size_t)w0*512);
        unsigned int u0=p[0], u1=p[1];
        win[ky][1][0]=bf2f((unsigned short)(u0&0xFFFF)); win[ky][1][1]=bf2f((unsigned short)(u0>>16));
        win[ky][1][2]=bf2f((unsigned short)(u1&0xFFFF)); win[ky][1][3]=bf2f((unsigned short)(u1>>16));
      }
    }
  }
  #pragma unroll
  for (int px=0; px<8; ++px){
    int w = w0 + px;
    #pragma unroll
    for (int ky=0;ky<3;ky++){
      #pragma unroll
      for (int j=0;j<4;j++) win[ky][2][j]=0.f;
      if (rv[ky] && (w+1) < WID){
        const unsigned int* p = (const unsigned int*)(rp[ky] + (size_t)(w+1)*512);
        unsigned int u0=p[0], u1=p[1];
        win[ky][2][0]=bf2f((unsigned short)(u0&0xFFFF)); win[ky][2][1]=bf2f((unsigned short)(u0>>16));
        win[ky][2][2]=bf2f((unsigned short)(u1&0xFFFF)); win[ky][2][3]=bf2f((unsigned short)(u1>>16));
      }
    }
    float a[4];
    #pragma unroll
    for (int j=0;j<4;j++){
      float acc = bias[j];
      #pragma unroll
      for (int ky=0;ky<3;ky++)
        #pragma unroll
        for (int kx=0;kx<3;kx++)
          acc += wreg[ky*3+kx][j]*win[ky][kx][j];
      a[j] = gelu_f(acc);
    }
    unsigned int o0 = (unsigned int)f2bf(a[0]) | ((unsigned int)f2bf(a[1])<<16);
    unsigned int o1 = (unsigned int)f2bf(a[2]) | ((unsigned int)f2bf(a[3])<<16);
    unsigned int* op = (unsigned int*)&SB2[((size_t)hl*WID + w)*512 + ch];
    op[0] = o0; op[1] = o1;
    #pragma unroll
    for (int ky=0;ky<3;ky++)
      #pragma unroll
      for (int j=0;j<4;j++){ win[ky][0][j]=win[ky][1][j]; win[ky][1][j]=win[ky][2][j]; }
  }
}

// ---------------- per-batch BHWC -> BCHW transpose (fallback path only) ----------------
__global__ __launch_bounds__(256) void transpose_b_kernel(const float* __restrict__ src, float* __restrict__ dst,
                                                          size_t zstride){
  __shared__ float tile[128*65];
  int w0 = blockIdx.x*64, h = blockIdx.y;
  size_t zo = (size_t)blockIdx.z * zstride;
  int tid = threadIdx.x;
  for (int r=0; r<32; r++){
    int e = tid + 256*r; int c = e & 127, wl = e >> 7;
    tile[c*65 + wl] = src[zo + ((size_t)h*WID + w0 + wl)*C_DIM + c];
  }
  __syncthreads();
  for (int r=0; r<32; r++){
    int e = tid + 256*r; int wl = e & 63, c = e >> 6;
    dst[zo + ((size_t)c*HGT + h)*WID + w0 + wl] = tile[c*65 + wl];
  }
}

// ---------------- host ----------------
extern "C" void kernel_launch(void* const* d_in, const int* in_sizes, int n_in,
                              void* d_out, int out_size, void* d_ws, size_t ws_size,
                              hipStream_t stream) {
  const float* x      = (const float*)d_in[0];
  const float* pos_w  = (const float*)d_in[1];
  const float* pos_b  = (const float*)d_in[2];
  const float* ln1_g  = (const float*)d_in[3];
  const float* ln1_b  = (const float*)d_in[4];
  const float* q_w    = (const float*)d_in[5];
  const float* q_b    = (const float*)d_in[6];
  const float* kv_w   = (const float*)d_in[7];
  const float* kv_b   = (const float*)d_in[8];
  const float* rpb    = (const float*)d_in[9];
  const float* proj_w = (const float*)d_in[10];
  const float* proj_b = (const float*)d_in[11];
  const float* fft1_w = (const float*)d_in[12];
  const float* fft1_b = (const float*)d_in[13];
  const float* fft2_w = (const float*)d_in[14];
  const float* fft2_b = (const float*)d_in[15];
  const float* ln2_g  = (const float*)d_in[16];
  const float* ln2_b  = (const float*)d_in[17];
  const float* l1_w   = (const float*)d_in[18];
  const float* l1_b   = (const float*)d_in[19];
  const float* dw_w   = (const float*)d_in[20];
  const float* dw_b   = (const float*)d_in[21];
  const float* l2_w   = (const float*)d_in[22];
  const float* l2_b   = (const float*)d_in[23];

  const size_t S   = (size_t)NB*HGT*WID*C_DIM;   // 18,874,368
  const size_t Sb  = S/NB;                       //  4,718,592
  const size_t SZb = (size_t)HGT*WFD*C_DIM;      //  2,383,872 (u16 per spectrum half)
  const size_t GSZ = (size_t)HGT*WFD*256;        //  4,767,744 (u16)
  const int    P   = (int)(NB*HGT*WID);          // 147,456

  float* ws    = (float*)d_ws;
  float* TAB   = ws;
  float* STATS = ws + TAB_SZ;
  float* POOL  = ws + TAB_SZ + 2*(size_t)P;
  size_t head  = TAB_SZ + 2*(size_t)P;
  size_t pool  = (ws_size/4 > head) ? (ws_size/4 - head) : 0;

  // primary: XT in pool, d_out free as FFT scratch, direct BCHW l2 output
  bool xt_in_pool = (pool >= S + 5200000);
  float* XT     = xt_in_pool ? POOL : (float*)d_out;
  float* POOL2  = xt_in_pool ? POOL + S : POOL;
  size_t pool2  = xt_in_pool ? pool - S : pool;

  const float* biasT = TAB + T_BIAS;
  const float* QKVB  = TAB + T_QKVB;
  const unsigned short* UT = (const unsigned short*)(TAB + TF_SZ);
  const unsigned short* MW  = UT + UT_MW;
  const unsigned short* MHF = UT + UT_MHF;
  const unsigned short* MHI = UT + UT_MHI;
  const unsigned short* MWI = UT + UT_MWI;
  const unsigned short* QKVW  = UT + UT_QKVW;
  const unsigned short* PROJW = UT + UT_PROJW;
  const unsigned short* FFT1W = UT + UT_FFT1W;
  const unsigned short* FFT2W = UT + UT_FFT2W;
  const unsigned short* L1W   = UT + UT_L1W;
  const unsigned short* L2W   = UT + UT_L2W;

  build_tables<<<2858, 256, 0, stream>>>(TAB, rpb, q_b, kv_b, q_w, kv_w, proj_w,
                                         fft1_w, fft2_w, l1_w, l2_w);
  posconv3_kernel<<<dim3(6,24,32), 256, 0, stream>>>(x, pos_w, pos_b, XT);

  // ---- attention: LN1 stats -> fused(LN+QKV+attn+proj, RMW XT) ----
  ln_stats_kernel<<<P/4, 256, 0, stream>>>(XT, STATS);
  attn_fused3<<<2304, 256, 0, stream>>>(XT, STATS, ln1_g, ln1_b, QKVW, QKVB,
                                        biasT, PROJW, proj_b);

  // ---- FFT residual branch ----
  {
    unsigned short* FRu = (unsigned short*)POOL2;
    unsigned short* FIu = FRu + SZb;
    unsigned short* Gu  = FIu + SZb;
    size_t fixed = SZb + GSZ/2;                  // floats used by FR+FI+G
    int CK;
    unsigned short* FF0u;
    unsigned short* FF1u;
    if (xt_in_pool){
      // FF0/FF1 live in d_out (free scratch until LeFF writes it): single chunk always
      CK = WFD;
      FF0u = (unsigned short*)d_out;
      FF1u = FF0u + (size_t)WFD*49152;
    } else {
      int CKmax = 1;
      if (pool2 > fixed + 49152) CKmax = (int)((pool2 - fixed)/49152);
      if (CKmax < 1) CKmax = 1;
      if (CKmax > WFD) CKmax = WFD;
      int nch = (WFD + CKmax - 1)/CKmax;
      CK = (WFD + nch - 1)/nch;
      FF0u = (unsigned short*)(POOL2 + fixed);
      FF1u = FF0u + (size_t)CK*49152;
    }
    for (int b = 0; b < NB; ++b){
      float* XTb = XT + (size_t)b*Sb;
      dft_gemm<0><<<dim3(2, 192*4), 256, 0, stream>>>(MW, XTb, nullptr, FRu, FIu, 0);
      for (int k0 = 0; k0 < WFD; k0 += CK){
        int ck = (WFD - k0 < CK) ? (WFD - k0) : CK;
        int rows = ck*192;
        dft_gemm<1><<<dim3(2, ck*6), 256, 0, stream>>>(MHF, FRu, FIu, FF0u, nullptr, k0);
        gemm2<1,false,false,true,true,1><<<dim3(4, rows/64), 256, 0, stream>>>(
            FF0u, FFT1W, fft1_b, FF1u, 256, 256, 256, nullptr, nullptr, nullptr, 0, 0);
        gemm2<0,false,false,true,true,1><<<dim3(4, rows/64), 256, 0, stream>>>(
            FF1u, FFT2W, fft2_b, FF0u, 256, 256, 256, nullptr, nullptr, nullptr, 0, 0);
        dft_gemm<2><<<dim3(2, ck*6), 256, 0, stream>>>(MHI, FF0u, FF0u+128, Gu, nullptr, k0);
      }
      dft_gemm<3><<<dim3(2, 192*3), 256, 0, stream>>>(MWI, Gu, Gu+128, XTb, nullptr, 0);
    }
  }

  // ---- LN2 stats ----
  ln_stats_kernel<<<P/4, 256, 0, stream>>>(XT, STATS);

  // ---- LeFF: strip-mined l1 (gemm2 NT=2) -> dwconv -> l2 ----
  {
    int SH = 96;
    while ((size_t)(3*SH+4)*49152 > pool2 && SH > 24) SH >>= 1;
    const size_t SB1SZ = (size_t)(SH+2)*98304;   // u16
    unsigned short* SB1u[2] = { (unsigned short*)POOL2, (unsigned short*)POOL2 + SB1SZ };
    unsigned short* SB2u = (unsigned short*)POOL2 + 2*SB1SZ;
    int nStrips = HGT/SH;
    for (int b = 0; b < NB; ++b){
      auto launch_g = [&](int s){
        int r0 = s*SH;
        int prow0 = (b*HGT + r0 - 1)*WID;
        gemm2<2,false,true,false,true,2><<<dim3(4, (SH+2)*3), 256, 0, stream>>>(
            XT, L1W, l1_b, SB1u[s&1], 128, 512, 128,
            STATS, ln2_g, ln2_b, prow0, P-1);
      };
      launch_g(0);
      for (int s = 0; s < nStrips; ++s){
        if (s+1 < nStrips) launch_g(s+1);
        int r0 = s*SH;
        dwconv_strip<<<12*SH, 256, 0, stream>>>(SB1u[s&1], dw_w, dw_b, SB2u, r0);
        if (xt_in_pool){
          // direct BCHW output with fp32 residual from XT (no XT write, no transpose)
          gemm2<0,false,false,true,false,1,true><<<dim3(2, SH*3), 256, 0, stream>>>(
              SB2u, L2W, l2_b, d_out, 512, 128, 512,
              XT, nullptr, nullptr, (b*HGT + r0)*WID, 0);
        } else {
          gemm2<0,true,false,true,false,1><<<dim3(2, SH*3), 256, 0, stream>>>(
              SB2u, L2W, l2_b, XT + ((size_t)(b*HGT + r0)*WID)*C_DIM,
              512, 128, 512, nullptr, nullptr, nullptr, 0, 0);
        }
      }
    }
  }

  // ---- final transpose (fallback path only) ----
  if (!xt_in_pool){
    for (int b = 0; b < NB; ++b){
      transpose_b_kernel<<<dim3(3,192,1), 256, 0, stream>>>(XT + (size_t)b*Sb, POOL2, 0);
      hipMemcpyAsync((float*)d_out + (size_t)b*Sb, POOL2, Sb*sizeof(float),
                     hipMemcpyDeviceToDevice, stream);
    }
  }
}